// Round 3
// baseline (1955.634 us; speedup 1.0000x reference)
//
#include <hip/hip_runtime.h>

// ---------------- problem constants ----------------
#define N_FRAMES 2048          // T*B
#define T_STEPS  128
#define BATCH    16
#define UNITS    128
#define NORM_SCALE 11.313708498984760390f  // sqrt(128)

// ---------------- workspace layout (float elements) ----------------
static const size_t OFF_W1P   = 0;            // 6144   : conv1 w [ky][kx][ic][oc] * (1/255)
static const size_t OFF_W2P   = 6144;         // 32768  : conv2 w [kk][ic][oc]
static const size_t OFF_W3P   = 38912;        // 36864  : conv3 w [kk][ic][oc]
static const size_t OFF_FCWP  = 75776;        // 1605632: fc w permuted to k'=p*64+c
static const size_t OFF_HSR   = 1681408;      // 262144
static const size_t OFF_HSI   = 1943552;      // 262144
static const size_t OFF_PROJR = 2205696;      // 262144
static const size_t OFF_PROJI = 2467840;      // 262144
static const size_t OFF_H     = 2729984;      // 1048576 : fc output [2048][512]
static const size_t OFF_Y2    = 3778560;      // 10616832: [2048][9][9][64]
static const size_t OFF_Y1    = 14395392;     // 26214400: [2048][20][20][32]
static const size_t OFF_Y3    = OFF_Y1;       // 6422528 : [2048][7][7][64] (reuses y1 after conv2)

// ---------------- weight permutes ----------------
__global__ void permute_w1(const float* __restrict__ w, float* __restrict__ o) {
    int i = blockIdx.x * 256 + threadIdx.x;      // 6144
    if (i >= 32 * 3 * 64) return;
    int oc = i & 31; int r = i >> 5; int ic = r % 3; int kk = r / 3;
    int kx = kk & 7, ky = kk >> 3;
    o[i] = w[((oc * 3 + ic) * 8 + ky) * 8 + kx] * (1.0f / 255.0f);
}
__global__ void permute_w2(const float* __restrict__ w, float* __restrict__ o) {
    int i = blockIdx.x * 256 + threadIdx.x;      // 32768
    if (i >= 64 * 32 * 16) return;
    int oc = i & 63; int r = i >> 6; int ic = r & 31; int kk = r >> 5;
    int kx = kk & 3, ky = kk >> 2;
    o[i] = w[((oc * 32 + ic) * 4 + ky) * 4 + kx];
}
__global__ void permute_w3(const float* __restrict__ w, float* __restrict__ o) {
    int i = blockIdx.x * 256 + threadIdx.x;      // 36864
    if (i >= 64 * 64 * 9) return;
    int oc = i & 63; int r = i >> 6; int ic = r & 63; int kk = r >> 6;
    int kx = kk % 3, ky = kk / 3;
    o[i] = w[((oc * 64 + ic) * 3 + ky) * 3 + kx];
}
__global__ void permute_fcw(const float* __restrict__ w, float* __restrict__ o) {
    // o[(p*64+c)*512 + j] = w[(c*49+p)*512 + j]
    int i = blockIdx.x * 256 + threadIdx.x;      // 1605632
    if (i >= 3136 * 512) return;
    int j = i & 511; int kp = i >> 9; int c = kp & 63; int p = kp >> 6;
    o[i] = w[(size_t)(c * 49 + p) * 512 + j];
}

#define FMA16(xv)                                              \
    acc[j][0] = fmaf(xv.x, wv[0].x, acc[j][0]);                \
    acc[j][1] = fmaf(xv.x, wv[0].y, acc[j][1]);                \
    acc[j][2] = fmaf(xv.x, wv[0].z, acc[j][2]);                \
    acc[j][3] = fmaf(xv.x, wv[0].w, acc[j][3]);                \
    acc[j][0] = fmaf(xv.y, wv[1].x, acc[j][0]);                \
    acc[j][1] = fmaf(xv.y, wv[1].y, acc[j][1]);                \
    acc[j][2] = fmaf(xv.y, wv[1].z, acc[j][2]);                \
    acc[j][3] = fmaf(xv.y, wv[1].w, acc[j][3]);                \
    acc[j][0] = fmaf(xv.z, wv[2].x, acc[j][0]);                \
    acc[j][1] = fmaf(xv.z, wv[2].y, acc[j][1]);                \
    acc[j][2] = fmaf(xv.z, wv[2].z, acc[j][2]);                \
    acc[j][3] = fmaf(xv.z, wv[2].w, acc[j][3]);                \
    acc[j][0] = fmaf(xv.w, wv[3].x, acc[j][0]);                \
    acc[j][1] = fmaf(xv.w, wv[3].y, acc[j][1]);                \
    acc[j][2] = fmaf(xv.w, wv[3].z, acc[j][2]);                \
    acc[j][3] = fmaf(xv.w, wv[3].w, acc[j][3]);

// ---------------- conv1 v2: LDS-staged, register-blocked ----------------
__global__ __launch_bounds__(256) void conv1_kernel(const float* __restrict__ x,
                                                    const float* __restrict__ w,
                                                    const float* __restrict__ b,
                                                    float* __restrict__ y) {
    __shared__ float xs[44 * 252];    // 44352 B
    __shared__ float wsm[192 * 32];   // 24576 B
    int tid = threadIdx.x;
    int blk = blockIdx.x;
    int n = blk >> 1, hb = blk & 1;

    const float4* xb4 = reinterpret_cast<const float4*>(x + (size_t)n * 21168 + hb * 40 * 252);
    float4* xs4 = reinterpret_cast<float4*>(xs);
    for (int i = tid; i < 2772; i += 256) xs4[i] = xb4[i];
    const float4* w4 = reinterpret_cast<const float4*>(w);
    float4* ws4 = reinterpret_cast<float4*>(wsm);
    for (int i = tid; i < 1536; i += 256) ws4[i] = w4[i];
    __syncthreads();

    int ocg = tid & 7;
    int pg = tid >> 3;
    if (pg < 25) {
        int baseo[8];
        int pidx[8];
#pragma unroll
        for (int j = 0; j < 8; ++j) {
            int p = j * 25 + pg;
            pidx[j] = p;
            int oy = p / 20, ox = p % 20;
            baseo[j] = oy * 1008 + ox * 12;
        }
        float acc[8][4] = {};
#pragma unroll 2
        for (int ky = 0; ky < 8; ++ky) {
#pragma unroll
            for (int rq = 0; rq < 6; ++rq) {
                float4 wv[4];
#pragma unroll
                for (int m = 0; m < 4; ++m)
                    wv[m] = *reinterpret_cast<const float4*>(&wsm[(ky * 24 + rq * 4 + m) * 32 + ocg * 4]);
#pragma unroll
                for (int j = 0; j < 8; ++j) {
                    float4 xv = *reinterpret_cast<const float4*>(&xs[baseo[j] + ky * 252 + rq * 4]);
                    FMA16(xv)
                }
            }
        }
        float4 bv = reinterpret_cast<const float4*>(b)[ocg];
#pragma unroll
        for (int j = 0; j < 8; ++j) {
            float4 o;
            o.x = fmaxf(acc[j][0] + bv.x, 0.f);
            o.y = fmaxf(acc[j][1] + bv.y, 0.f);
            o.z = fmaxf(acc[j][2] + bv.z, 0.f);
            o.w = fmaxf(acc[j][3] + bv.w, 0.f);
            size_t off = ((size_t)(n * 400 + hb * 200 + pidx[j]) * 32) + ocg * 4;
            *reinterpret_cast<float4*>(&y[off]) = o;
        }
    }
}

// ---------------- conv2 v2: 1 image/block, LDS x + chunked LDS weights ----------------
// LDS: xs 51.2 KB + wsm 16.4 KB -> 2 blocks/CU. thread = 6 px x 4 oc.
__global__ __launch_bounds__(256) void conv2_kernel(const float* __restrict__ y1,
                                                    const float* __restrict__ w,
                                                    const float* __restrict__ b,
                                                    float* __restrict__ y2) {
    __shared__ float xs[12800];
    __shared__ float wsm[4096];
    int tid = threadIdx.x;
    int n = blockIdx.x;
    const float4* xg = reinterpret_cast<const float4*>(y1 + (size_t)n * 12800);
    float4* xs4 = reinterpret_cast<float4*>(xs);
#pragma unroll
    for (int q = 0; q < 13; ++q) {
        int i = q * 256 + tid;
        if (i < 3200) xs4[i] = xg[i];
    }
    const float4* wg = reinterpret_cast<const float4*>(w);
    float4* ws4 = reinterpret_cast<float4*>(wsm);
    float4 nreg[4];
#pragma unroll
    for (int q = 0; q < 4; ++q) nreg[q] = wg[q * 256 + tid];
#pragma unroll
    for (int q = 0; q < 4; ++q) ws4[q * 256 + tid] = nreg[q];
    __syncthreads();

    int ocg = tid & 15;
    int pg = tid >> 4;
    int baseo[6];
    bool valid[6];
#pragma unroll
    for (int j = 0; j < 6; ++j) {
        int p = pg + 16 * j;
        valid[j] = p < 81;
        int pp = valid[j] ? p : 0;
        baseo[j] = (pp / 9) * 1280 + (pp % 9) * 64;
    }
    float acc[6][4] = {};
#pragma unroll 1
    for (int kp = 0; kp < 8; ++kp) {
        if (kp < 7) {
#pragma unroll
            for (int q = 0; q < 4; ++q) nreg[q] = wg[(kp + 1) * 1024 + q * 256 + tid];
        }
#pragma unroll
        for (int kh = 0; kh < 2; ++kh) {
            int kk = kp * 2 + kh;
            int ky = kk >> 2, kx = kk & 3;
            int xoff = ky * 640 + kx * 32;
            const float* wk = wsm + kh * 2048 + ocg * 4;
#pragma unroll
            for (int icv = 0; icv < 8; ++icv) {
                float4 wv[4];
#pragma unroll
                for (int i = 0; i < 4; ++i)
                    wv[i] = *reinterpret_cast<const float4*>(wk + (icv * 4 + i) * 64);
#pragma unroll
                for (int j = 0; j < 6; ++j) {
                    float4 xv = *reinterpret_cast<const float4*>(&xs[baseo[j] + xoff + icv * 4]);
                    FMA16(xv)
                }
            }
        }
        if (kp < 7) {
            __syncthreads();
#pragma unroll
            for (int q = 0; q < 4; ++q) ws4[q * 256 + tid] = nreg[q];
            __syncthreads();
        }
    }
    float4 bv = reinterpret_cast<const float4*>(b)[ocg];
#pragma unroll
    for (int j = 0; j < 6; ++j) {
        if (valid[j]) {
            int p = pg + 16 * j;
            float4 o;
            o.x = fmaxf(acc[j][0] + bv.x, 0.f);
            o.y = fmaxf(acc[j][1] + bv.y, 0.f);
            o.z = fmaxf(acc[j][2] + bv.z, 0.f);
            o.w = fmaxf(acc[j][3] + bv.w, 0.f);
            *reinterpret_cast<float4*>(&y2[((size_t)n * 81 + p) * 64 + ocg * 4]) = o;
        }
    }
}

// ---------------- conv3 v2: 1 image/block, LDS x + chunked LDS weights ----------------
// LDS: xs 20.7 KB + wsm 16.4 KB -> 4 blocks/CU. thread = 4 px x 4 oc.
__global__ __launch_bounds__(256) void conv3_kernel(const float* __restrict__ y2,
                                                    const float* __restrict__ w,
                                                    const float* __restrict__ b,
                                                    float* __restrict__ y3) {
    __shared__ float xs[5184];
    __shared__ float wsm[4096];
    int tid = threadIdx.x;
    int n = blockIdx.x;
    const float4* xg = reinterpret_cast<const float4*>(y2 + (size_t)n * 5184);
    float4* xs4 = reinterpret_cast<float4*>(xs);
#pragma unroll
    for (int q = 0; q < 6; ++q) {
        int i = q * 256 + tid;
        if (i < 1296) xs4[i] = xg[i];
    }
    const float4* wg = reinterpret_cast<const float4*>(w);
    float4* ws4 = reinterpret_cast<float4*>(wsm);
    float4 nreg[4];
#pragma unroll
    for (int q = 0; q < 4; ++q) nreg[q] = wg[q * 256 + tid];
#pragma unroll
    for (int q = 0; q < 4; ++q) ws4[q * 256 + tid] = nreg[q];
    __syncthreads();

    int ocg = tid & 15;
    int pg = tid >> 4;
    int baseo[4];
    bool valid[4];
#pragma unroll
    for (int j = 0; j < 4; ++j) {
        int p = pg + 16 * j;
        valid[j] = p < 49;
        int pp = valid[j] ? p : 0;
        baseo[j] = (pp / 7) * 576 + (pp % 7) * 64;
    }
    float acc[4][4] = {};
#pragma unroll 1
    for (int kk = 0; kk < 9; ++kk) {
        if (kk < 8) {
#pragma unroll
            for (int q = 0; q < 4; ++q) nreg[q] = wg[(kk + 1) * 1024 + q * 256 + tid];
        }
        int ky = kk / 3, kx = kk % 3;
        int xoff = ky * 576 + kx * 64;
        const float* wk = wsm + ocg * 4;
#pragma unroll 4
        for (int icv = 0; icv < 16; ++icv) {
            float4 wv[4];
#pragma unroll
            for (int i = 0; i < 4; ++i)
                wv[i] = *reinterpret_cast<const float4*>(wk + (icv * 4 + i) * 64);
#pragma unroll
            for (int j = 0; j < 4; ++j) {
                float4 xv = *reinterpret_cast<const float4*>(&xs[baseo[j] + xoff + icv * 4]);
                FMA16(xv)
            }
        }
        if (kk < 8) {
            __syncthreads();
#pragma unroll
            for (int q = 0; q < 4; ++q) ws4[q * 256 + tid] = nreg[q];
            __syncthreads();
        }
    }
    float4 bv = reinterpret_cast<const float4*>(b)[ocg];
#pragma unroll
    for (int j = 0; j < 4; ++j) {
        if (valid[j]) {
            int p = pg + 16 * j;
            float4 o;
            o.x = fmaxf(acc[j][0] + bv.x, 0.f);
            o.y = fmaxf(acc[j][1] + bv.y, 0.f);
            o.z = fmaxf(acc[j][2] + bv.z, 0.f);
            o.w = fmaxf(acc[j][3] + bv.w, 0.f);
            *reinterpret_cast<float4*>(&y3[(size_t)n * 3136 + p * 64 + ocg * 4]) = o;
        }
    }
}

// ---------------- FC: h[2048][512] = relu(y3 @ fcwp + fc_b) ----------------
__global__ __launch_bounds__(256) void fc_kernel(const float* __restrict__ A,
                                                 const float* __restrict__ B,
                                                 const float* __restrict__ bias,
                                                 float* __restrict__ C) {
    __shared__ float As[16][64];
    __shared__ float Bs[16][64];
    int tid = threadIdx.x;
    int bm = blockIdx.x & 31;       // 32 M-tiles
    int bn = blockIdx.x >> 5;       // 8 N-tiles
    int row0 = bm * 64, col0 = bn * 64;
    int tr = tid >> 4, tc = tid & 15;
    float acc[4][4] = {};
    int am = tid >> 2, ak = (tid & 3) * 4;
    int bk = tid >> 4, bn4 = (tid & 15) * 4;
    for (int k0 = 0; k0 < 3136; k0 += 16) {
        float4 av = *reinterpret_cast<const float4*>(A + (size_t)(row0 + am) * 3136 + k0 + ak);
        As[ak][am] = av.x; As[ak + 1][am] = av.y; As[ak + 2][am] = av.z; As[ak + 3][am] = av.w;
        float4 bv = *reinterpret_cast<const float4*>(B + (size_t)(k0 + bk) * 512 + col0 + bn4);
        *reinterpret_cast<float4*>(&Bs[bk][bn4]) = bv;
        __syncthreads();
#pragma unroll
        for (int kk = 0; kk < 16; ++kk) {
            float4 a4 = *reinterpret_cast<const float4*>(&As[kk][tr * 4]);
            float4 b4 = *reinterpret_cast<const float4*>(&Bs[kk][tc * 4]);
            const float a[4] = {a4.x, a4.y, a4.z, a4.w};
            const float bb[4] = {b4.x, b4.y, b4.z, b4.w};
#pragma unroll
            for (int i = 0; i < 4; ++i)
#pragma unroll
                for (int j = 0; j < 4; ++j) acc[i][j] = fmaf(a[i], bb[j], acc[i][j]);
        }
        __syncthreads();
    }
#pragma unroll
    for (int i = 0; i < 4; ++i)
#pragma unroll
        for (int j = 0; j < 4; ++j) {
            int r = row0 + tr * 4 + i, c = col0 + tc * 4 + j;
            C[(size_t)r * 512 + c] = fmaxf(acc[i][j] + bias[c], 0.f);
        }
}

// ---------------- proj: h[2048][512] @ win -> proj_{r,i}[2048][128] ----------------
__global__ __launch_bounds__(256) void proj_kernel(const float* __restrict__ h,
                                                   const float* __restrict__ winr,
                                                   const float* __restrict__ wini,
                                                   float* __restrict__ pr,
                                                   float* __restrict__ pi) {
    int idx = blockIdx.x * 256 + threadIdx.x;    // (2048/8)*128 = 32768
    int u = idx & 127;
    int n0 = (idx >> 7) * 8;
    float ar[8] = {}, ai[8] = {};
    for (int k = 0; k < 512; ++k) {
        float wrv = winr[k * 128 + u], wiv = wini[k * 128 + u];
#pragma unroll
        for (int g = 0; g < 8; ++g) {
            float hv = h[(size_t)(n0 + g) * 512 + k];
            ar[g] = fmaf(hv, wrv, ar[g]);
            ai[g] = fmaf(hv, wiv, ai[g]);
        }
    }
#pragma unroll
    for (int g = 0; g < 8; ++g) {
        pr[(size_t)(n0 + g) * 128 + u] = ar[g];
        pi[(size_t)(n0 + g) * 128 + u] = ai[g];
    }
}

// ---------------- RNN scan: one block per batch lane, sequential over T ----------------
__global__ __launch_bounds__(512) void scan_kernel(const float* __restrict__ done,
                                                   const float* __restrict__ sr0,
                                                   const float* __restrict__ si0,
                                                   const float* __restrict__ wrecr,
                                                   const float* __restrict__ wreci,
                                                   const float* __restrict__ pr,
                                                   const float* __restrict__ pi,
                                                   float* __restrict__ hsr,
                                                   float* __restrict__ hsi) {
    int b = blockIdx.x;
    int tid = threadIdx.x;
    int u = tid & 127;
    int s = tid >> 7;                     // k-split 0..3
    float wr[32], wi[32];
#pragma unroll
    for (int j = 0; j < 32; ++j) {
        int k = s * 32 + j;
        wr[j] = wrecr[k * 128 + u];
        wi[j] = wreci[k * 128 + u];
    }
    __shared__ float stR[128], stI[128];
    __shared__ float parR[4][128], parI[4][128];
    __shared__ float red[128];
    __shared__ float normsh;
    if (s == 0) { stR[u] = sr0[b * 128 + u]; stI[u] = si0[b * 128 + u]; }
    __syncthreads();
    for (int t = 0; t < T_STEPS; ++t) {
        float d = done[t * BATCH + b];
        if (s == 0) {
            float r = 1.f - d;
            stR[u] = r * stR[u] + d;      // blend toward init (1 + 0i)
            stI[u] = r * stI[u];
        }
        __syncthreads();
        float ar = 0.f, ai = 0.f;
#pragma unroll
        for (int j = 0; j < 32; ++j) {
            int k = s * 32 + j;
            float srk = stR[k], sik = stI[k];
            ar = fmaf(srk, wr[j], ar); ar = fmaf(-sik, wi[j], ar);
            ai = fmaf(srk, wi[j], ai); ai = fmaf(sik, wr[j], ai);
        }
        parR[s][u] = ar; parI[s][u] = ai;
        __syncthreads();
        float pre_r = 0.f, pre_i = 0.f;
        if (s == 0) {
            int np = (t * BATCH + b) * 128 + u;
            pre_r = parR[0][u] + parR[1][u] + parR[2][u] + parR[3][u] + pr[np];
            pre_i = parI[0][u] + parI[1][u] + parI[2][u] + parI[3][u] + pi[np];
            red[u] = pre_r * pre_r + pre_i * pre_i;
        }
        __syncthreads();
        if (tid < 64) {
            float v = red[tid] + red[tid + 64];
#pragma unroll
            for (int off = 32; off; off >>= 1) v += __shfl_down(v, off);
            if (tid == 0) normsh = v;
        }
        __syncthreads();
        if (s == 0) {
            float scale = NORM_SCALE / sqrtf(normsh);
            float nr = pre_r * scale, ni = pre_i * scale;
            stR[u] = nr; stI[u] = ni;
            int np = (t * BATCH + b) * 128 + u;
            hsr[np] = nr; hsi[np] = ni;
        }
        __syncthreads();
    }
}

// ---------------- heads: out[2048][7] ----------------
__global__ void heads_kernel(const float* __restrict__ hsr, const float* __restrict__ hsi,
                             const float* __restrict__ aw, const float* __restrict__ ab,
                             const float* __restrict__ cw, const float* __restrict__ cb,
                             float* __restrict__ out) {
    int idx = blockIdx.x * 256 + threadIdx.x;    // 14336
    if (idx >= N_FRAMES * 7) return;
    int j = idx % 7;
    int n = idx / 7;
    float acc;
    if (j < 6) {
        acc = ab[j];
        for (int k = 0; k < 128; ++k) acc = fmaf(hsr[n * 128 + k], aw[k * 6 + j], acc);
        for (int k = 0; k < 128; ++k) acc = fmaf(hsi[n * 128 + k], aw[(128 + k) * 6 + j], acc);
    } else {
        acc = cb[0];
        for (int k = 0; k < 128; ++k) acc = fmaf(hsr[n * 128 + k], cw[k], acc);
        for (int k = 0; k < 128; ++k) acc = fmaf(hsi[n * 128 + k], cw[128 + k], acc);
    }
    out[idx] = acc;
}

// ---------------- launch ----------------
extern "C" void kernel_launch(void* const* d_in, const int* in_sizes, int n_in,
                              void* d_out, int out_size, void* d_ws, size_t ws_size,
                              hipStream_t stream) {
    const float* x        = (const float*)d_in[0];
    const float* done     = (const float*)d_in[1];
    const float* sr0      = (const float*)d_in[2];
    const float* si0      = (const float*)d_in[3];
    const float* conv1_w  = (const float*)d_in[4];
    const float* conv1_b  = (const float*)d_in[5];
    const float* conv2_w  = (const float*)d_in[6];
    const float* conv2_b  = (const float*)d_in[7];
    const float* conv3_w  = (const float*)d_in[8];
    const float* conv3_b  = (const float*)d_in[9];
    const float* fc_w     = (const float*)d_in[10];
    const float* fc_b     = (const float*)d_in[11];
    const float* win_r    = (const float*)d_in[12];
    const float* win_i    = (const float*)d_in[13];
    const float* wrec_r   = (const float*)d_in[14];
    const float* wrec_i   = (const float*)d_in[15];
    const float* actor_w  = (const float*)d_in[16];
    const float* actor_b  = (const float*)d_in[17];
    const float* critic_w = (const float*)d_in[18];
    const float* critic_b = (const float*)d_in[19];

    float* ws = (float*)d_ws;
    float* w1p  = ws + OFF_W1P;
    float* w2p  = ws + OFF_W2P;
    float* w3p  = ws + OFF_W3P;
    float* fcwp = ws + OFF_FCWP;
    float* hsr  = ws + OFF_HSR;
    float* hsi  = ws + OFF_HSI;
    float* prj  = ws + OFF_PROJR;
    float* pij  = ws + OFF_PROJI;
    float* h    = ws + OFF_H;
    float* y2   = ws + OFF_Y2;
    float* y1   = ws + OFF_Y1;
    float* y3   = ws + OFF_Y3;
    float* outp = (float*)d_out;

    hipLaunchKernelGGL(permute_w1, dim3(24), dim3(256), 0, stream, conv1_w, w1p);
    hipLaunchKernelGGL(permute_w2, dim3(128), dim3(256), 0, stream, conv2_w, w2p);
    hipLaunchKernelGGL(permute_w3, dim3(144), dim3(256), 0, stream, conv3_w, w3p);
    hipLaunchKernelGGL(permute_fcw, dim3(6272), dim3(256), 0, stream, fc_w, fcwp);

    hipLaunchKernelGGL(conv1_kernel, dim3(4096), dim3(256), 0, stream, x, w1p, conv1_b, y1);
    hipLaunchKernelGGL(conv2_kernel, dim3(2048), dim3(256), 0, stream, y1, w2p, conv2_b, y2);
    hipLaunchKernelGGL(conv3_kernel, dim3(2048), dim3(256), 0, stream, y2, w3p, conv3_b, y3);
    hipLaunchKernelGGL(fc_kernel, dim3(256), dim3(256), 0, stream, y3, fcwp, fc_b, h);
    hipLaunchKernelGGL(proj_kernel, dim3(128), dim3(256), 0, stream, h, win_r, win_i, prj, pij);
    hipLaunchKernelGGL(scan_kernel, dim3(16), dim3(512), 0, stream,
                       done, sr0, si0, wrec_r, wrec_i, prj, pij, hsr, hsi);
    hipLaunchKernelGGL(heads_kernel, dim3(56), dim3(256), 0, stream,
                       hsr, hsi, actor_w, actor_b, critic_w, critic_b, outp);
}

// Round 4
// 1098.625 us; speedup vs baseline: 1.7801x; 1.7801x over previous
//
#include <hip/hip_runtime.h>

// ---------------- problem constants ----------------
#define N_FRAMES 2048          // T*B
#define T_STEPS  128
#define BATCH    16
#define UNITS    128
#define NORM_SCALE 11.313708498984760390f  // sqrt(128)

// ---------------- workspace layout (float elements) ----------------
static const size_t OFF_W1P   = 0;            // 6144   : conv1 w [ky][kx][ic][oc] * (1/255)
static const size_t OFF_W2P   = 6144;         // 32768  : conv2 w [kk][ic][oc]
static const size_t OFF_W3P   = 38912;        // 36864  : conv3 w [kk][ic][oc]
static const size_t OFF_FCWP  = 75776;        // 1605632: fc w permuted to k'=p*64+c
static const size_t OFF_HSR   = 1681408;      // 262144
static const size_t OFF_HSI   = 1943552;      // 262144
static const size_t OFF_PROJR = 2205696;      // 262144
static const size_t OFF_PROJI = 2467840;      // 262144
static const size_t OFF_H     = 2729984;      // 1048576 : fc output [2048][512]
static const size_t OFF_Y2    = 3778560;      // 10616832: [2048][9][9][64]
static const size_t OFF_Y1    = 14395392;     // 26214400: [2048][20][20][32]
static const size_t OFF_Y3    = OFF_Y1;       // 6422528 : [2048][7][7][64] (reuses y1 after conv2)

// ---------------- weight permutes ----------------
__global__ void permute_w1(const float* __restrict__ w, float* __restrict__ o) {
    int i = blockIdx.x * 256 + threadIdx.x;      // 6144
    if (i >= 32 * 3 * 64) return;
    int oc = i & 31; int r = i >> 5; int ic = r % 3; int kk = r / 3;
    int kx = kk & 7, ky = kk >> 3;
    o[i] = w[((oc * 3 + ic) * 8 + ky) * 8 + kx] * (1.0f / 255.0f);
}
__global__ void permute_w2(const float* __restrict__ w, float* __restrict__ o) {
    int i = blockIdx.x * 256 + threadIdx.x;      // 32768
    if (i >= 64 * 32 * 16) return;
    int oc = i & 63; int r = i >> 6; int ic = r & 31; int kk = r >> 5;
    int kx = kk & 3, ky = kk >> 2;
    o[i] = w[((oc * 32 + ic) * 4 + ky) * 4 + kx];
}
__global__ void permute_w3(const float* __restrict__ w, float* __restrict__ o) {
    int i = blockIdx.x * 256 + threadIdx.x;      // 36864
    if (i >= 64 * 64 * 9) return;
    int oc = i & 63; int r = i >> 6; int ic = r & 63; int kk = r >> 6;
    int kx = kk % 3, ky = kk / 3;
    o[i] = w[((oc * 64 + ic) * 3 + ky) * 3 + kx];
}
__global__ void permute_fcw(const float* __restrict__ w, float* __restrict__ o) {
    // o[(p*64+c)*512 + j] = w[(c*49+p)*512 + j]
    int i = blockIdx.x * 256 + threadIdx.x;      // 1605632
    if (i >= 3136 * 512) return;
    int j = i & 511; int kp = i >> 9; int c = kp & 63; int p = kp >> 6;
    o[i] = w[(size_t)(c * 49 + p) * 512 + j];
}

#define FMA16(xv)                                              \
    acc[j][0] = fmaf(xv.x, wv[0].x, acc[j][0]);                \
    acc[j][1] = fmaf(xv.x, wv[0].y, acc[j][1]);                \
    acc[j][2] = fmaf(xv.x, wv[0].z, acc[j][2]);                \
    acc[j][3] = fmaf(xv.x, wv[0].w, acc[j][3]);                \
    acc[j][0] = fmaf(xv.y, wv[1].x, acc[j][0]);                \
    acc[j][1] = fmaf(xv.y, wv[1].y, acc[j][1]);                \
    acc[j][2] = fmaf(xv.y, wv[1].z, acc[j][2]);                \
    acc[j][3] = fmaf(xv.y, wv[1].w, acc[j][3]);                \
    acc[j][0] = fmaf(xv.z, wv[2].x, acc[j][0]);                \
    acc[j][1] = fmaf(xv.z, wv[2].y, acc[j][1]);                \
    acc[j][2] = fmaf(xv.z, wv[2].z, acc[j][2]);                \
    acc[j][3] = fmaf(xv.z, wv[2].w, acc[j][3]);                \
    acc[j][0] = fmaf(xv.w, wv[3].x, acc[j][0]);                \
    acc[j][1] = fmaf(xv.w, wv[3].y, acc[j][1]);                \
    acc[j][2] = fmaf(xv.w, wv[3].z, acc[j][2]);                \
    acc[j][3] = fmaf(xv.w, wv[3].w, acc[j][3]);

// ---------------- conv1 v2: LDS-staged, register-blocked (unchanged) ----------------
__global__ __launch_bounds__(256) void conv1_kernel(const float* __restrict__ x,
                                                    const float* __restrict__ w,
                                                    const float* __restrict__ b,
                                                    float* __restrict__ y) {
    __shared__ float xs[44 * 252];    // 44352 B
    __shared__ float wsm[192 * 32];   // 24576 B
    int tid = threadIdx.x;
    int blk = blockIdx.x;
    int n = blk >> 1, hb = blk & 1;

    const float4* xb4 = reinterpret_cast<const float4*>(x + (size_t)n * 21168 + hb * 40 * 252);
    float4* xs4 = reinterpret_cast<float4*>(xs);
    for (int i = tid; i < 2772; i += 256) xs4[i] = xb4[i];
    const float4* w4 = reinterpret_cast<const float4*>(w);
    float4* ws4 = reinterpret_cast<float4*>(wsm);
    for (int i = tid; i < 1536; i += 256) ws4[i] = w4[i];
    __syncthreads();

    int ocg = tid & 7;
    int pg = tid >> 3;
    if (pg < 25) {
        int baseo[8];
        int pidx[8];
#pragma unroll
        for (int j = 0; j < 8; ++j) {
            int p = j * 25 + pg;
            pidx[j] = p;
            int oy = p / 20, ox = p % 20;
            baseo[j] = oy * 1008 + ox * 12;
        }
        float acc[8][4] = {};
#pragma unroll 2
        for (int ky = 0; ky < 8; ++ky) {
#pragma unroll
            for (int rq = 0; rq < 6; ++rq) {
                float4 wv[4];
#pragma unroll
                for (int m = 0; m < 4; ++m)
                    wv[m] = *reinterpret_cast<const float4*>(&wsm[(ky * 24 + rq * 4 + m) * 32 + ocg * 4]);
#pragma unroll
                for (int j = 0; j < 8; ++j) {
                    float4 xv = *reinterpret_cast<const float4*>(&xs[baseo[j] + ky * 252 + rq * 4]);
                    FMA16(xv)
                }
            }
        }
        float4 bv = reinterpret_cast<const float4*>(b)[ocg];
#pragma unroll
        for (int j = 0; j < 8; ++j) {
            float4 o;
            o.x = fmaxf(acc[j][0] + bv.x, 0.f);
            o.y = fmaxf(acc[j][1] + bv.y, 0.f);
            o.z = fmaxf(acc[j][2] + bv.z, 0.f);
            o.w = fmaxf(acc[j][3] + bv.w, 0.f);
            size_t off = ((size_t)(n * 400 + hb * 200 + pidx[j]) * 32) + ocg * 4;
            *reinterpret_cast<float4*>(&y[off]) = o;
        }
    }
}

// ---------------- conv2 v3: 1 image/block, swizzled LDS x, weights from global ----------------
// LDS: xs 51.2 KB (3 blocks/CU). thread = 6 px x 4 oc. No syncthreads in main loop.
// swizzle: word addr = px*32 + (ic ^ ((px&3)<<3)) -> within-wave dpx=1..3 hits banks +-8/16/24.
__global__ __launch_bounds__(256, 3) void conv2_kernel(const float* __restrict__ y1,
                                                       const float* __restrict__ w,
                                                       const float* __restrict__ b,
                                                       float* __restrict__ y2) {
    __shared__ float xs[12800];
    int tid = threadIdx.x;
    int n = blockIdx.x;
    const float4* xg = reinterpret_cast<const float4*>(y1 + (size_t)n * 12800);
#pragma unroll
    for (int q = 0; q < 13; ++q) {
        int i = q * 256 + tid;
        if (i < 3200) {
            int px = i >> 3, qq = i & 7;
            float4 v = xg[i];
            *reinterpret_cast<float4*>(&xs[px * 32 + ((qq * 4) ^ ((px & 3) << 3))]) = v;
        }
    }
    __syncthreads();

    int ocg = tid & 15;
    int pg = tid >> 4;
    int ibase[6];          // input base pixel index (iy0*20+ix0)
    bool valid[6];
#pragma unroll
    for (int j = 0; j < 6; ++j) {
        int p = pg + 16 * j;
        valid[j] = p < 81;
        int pp = valid[j] ? p : 0;
        ibase[j] = (pp / 9) * 40 + (pp % 9) * 2;   // (oy*2)*20 + ox*2
    }
    const float4* wg4 = reinterpret_cast<const float4*>(w);
    float acc[6][4] = {};
#pragma unroll 1
    for (int kk = 0; kk < 16; ++kk) {
        int ky = kk >> 2, kx = kk & 3;
        int koff = ky * 20 + kx;
        int ib[6], sz[6];
#pragma unroll
        for (int j = 0; j < 6; ++j) {
            int ipx = ibase[j] + koff;
            ib[j] = ipx * 32;
            sz[j] = (ipx & 3) << 3;
        }
        const float4* wkk = wg4 + kk * 512 + ocg;
#pragma unroll 2
        for (int icv = 0; icv < 8; ++icv) {
            float4 wv[4];
#pragma unroll
            for (int i = 0; i < 4; ++i) wv[i] = wkk[(icv * 4 + i) * 16];
#pragma unroll
            for (int j = 0; j < 6; ++j) {
                float4 xv = *reinterpret_cast<const float4*>(&xs[ib[j] + ((icv * 4) ^ sz[j])]);
                FMA16(xv)
            }
        }
    }
    float4 bv = reinterpret_cast<const float4*>(b)[ocg];
#pragma unroll
    for (int j = 0; j < 6; ++j) {
        if (valid[j]) {
            int p = pg + 16 * j;
            float4 o;
            o.x = fmaxf(acc[j][0] + bv.x, 0.f);
            o.y = fmaxf(acc[j][1] + bv.y, 0.f);
            o.z = fmaxf(acc[j][2] + bv.z, 0.f);
            o.w = fmaxf(acc[j][3] + bv.w, 0.f);
            *reinterpret_cast<float4*>(&y2[((size_t)n * 81 + p) * 64 + ocg * 4]) = o;
        }
    }
}

// ---------------- conv3 v3: 1 image/block, swizzled LDS x, weights from global ----------------
// LDS: xs 20.7 KB (7 blocks/CU). thread = 4 px x 4 oc.
// swizzle: word addr = px*64 + (ic ^ ((px&7)<<3)).
__global__ __launch_bounds__(256, 4) void conv3_kernel(const float* __restrict__ y2,
                                                       const float* __restrict__ w,
                                                       const float* __restrict__ b,
                                                       float* __restrict__ y3) {
    __shared__ float xs[5184];
    int tid = threadIdx.x;
    int n = blockIdx.x;
    const float4* xg = reinterpret_cast<const float4*>(y2 + (size_t)n * 5184);
#pragma unroll
    for (int q = 0; q < 6; ++q) {
        int i = q * 256 + tid;
        if (i < 1296) {
            int px = i >> 4, qq = i & 15;
            float4 v = xg[i];
            *reinterpret_cast<float4*>(&xs[px * 64 + ((qq * 4) ^ ((px & 7) << 3))]) = v;
        }
    }
    __syncthreads();

    int ocg = tid & 15;
    int pg = tid >> 4;
    int ibase[4];
    bool valid[4];
#pragma unroll
    for (int j = 0; j < 4; ++j) {
        int p = pg + 16 * j;
        valid[j] = p < 49;
        int pp = valid[j] ? p : 0;
        ibase[j] = (pp / 7) * 9 + (pp % 7);   // oy*9 + ox
    }
    const float4* wg4 = reinterpret_cast<const float4*>(w);
    float acc[4][4] = {};
#pragma unroll 1
    for (int kk = 0; kk < 9; ++kk) {
        int ky = kk / 3, kx = kk % 3;
        int koff = ky * 9 + kx;
        int ib[4], sz[4];
#pragma unroll
        for (int j = 0; j < 4; ++j) {
            int ipx = ibase[j] + koff;
            ib[j] = ipx * 64;
            sz[j] = (ipx & 7) << 3;
        }
        const float4* wkk = wg4 + kk * 1024 + ocg;
#pragma unroll 2
        for (int icv = 0; icv < 16; ++icv) {
            float4 wv[4];
#pragma unroll
            for (int i = 0; i < 4; ++i) wv[i] = wkk[(icv * 4 + i) * 16];
#pragma unroll
            for (int j = 0; j < 4; ++j) {
                float4 xv = *reinterpret_cast<const float4*>(&xs[ib[j] + ((icv * 4) ^ sz[j])]);
                FMA16(xv)
            }
        }
    }
    float4 bv = reinterpret_cast<const float4*>(b)[ocg];
#pragma unroll
    for (int j = 0; j < 4; ++j) {
        if (valid[j]) {
            int p = pg + 16 * j;
            float4 o;
            o.x = fmaxf(acc[j][0] + bv.x, 0.f);
            o.y = fmaxf(acc[j][1] + bv.y, 0.f);
            o.z = fmaxf(acc[j][2] + bv.z, 0.f);
            o.w = fmaxf(acc[j][3] + bv.w, 0.f);
            *reinterpret_cast<float4*>(&y3[(size_t)n * 3136 + p * 64 + ocg * 4]) = o;
        }
    }
}

// ---------------- FC: h[2048][512] = relu(y3 @ fcwp + fc_b) ----------------
__global__ __launch_bounds__(256) void fc_kernel(const float* __restrict__ A,
                                                 const float* __restrict__ B,
                                                 const float* __restrict__ bias,
                                                 float* __restrict__ C) {
    __shared__ float As[16][64];
    __shared__ float Bs[16][64];
    int tid = threadIdx.x;
    int bm = blockIdx.x & 31;       // 32 M-tiles
    int bn = blockIdx.x >> 5;       // 8 N-tiles
    int row0 = bm * 64, col0 = bn * 64;
    int tr = tid >> 4, tc = tid & 15;
    float acc[4][4] = {};
    int am = tid >> 2, ak = (tid & 3) * 4;
    int bk = tid >> 4, bn4 = (tid & 15) * 4;
    for (int k0 = 0; k0 < 3136; k0 += 16) {
        float4 av = *reinterpret_cast<const float4*>(A + (size_t)(row0 + am) * 3136 + k0 + ak);
        As[ak][am] = av.x; As[ak + 1][am] = av.y; As[ak + 2][am] = av.z; As[ak + 3][am] = av.w;
        float4 bv = *reinterpret_cast<const float4*>(B + (size_t)(k0 + bk) * 512 + col0 + bn4);
        *reinterpret_cast<float4*>(&Bs[bk][bn4]) = bv;
        __syncthreads();
#pragma unroll
        for (int kk = 0; kk < 16; ++kk) {
            float4 a4 = *reinterpret_cast<const float4*>(&As[kk][tr * 4]);
            float4 b4 = *reinterpret_cast<const float4*>(&Bs[kk][tc * 4]);
            const float a[4] = {a4.x, a4.y, a4.z, a4.w};
            const float bb[4] = {b4.x, b4.y, b4.z, b4.w};
#pragma unroll
            for (int i = 0; i < 4; ++i)
#pragma unroll
                for (int j = 0; j < 4; ++j) acc[i][j] = fmaf(a[i], bb[j], acc[i][j]);
        }
        __syncthreads();
    }
#pragma unroll
    for (int i = 0; i < 4; ++i)
#pragma unroll
        for (int j = 0; j < 4; ++j) {
            int r = row0 + tr * 4 + i, c = col0 + tc * 4 + j;
            C[(size_t)r * 512 + c] = fmaxf(acc[i][j] + bias[c], 0.f);
        }
}

// ---------------- proj: h[2048][512] @ win -> proj_{r,i}[2048][128] ----------------
__global__ __launch_bounds__(256) void proj_kernel(const float* __restrict__ h,
                                                   const float* __restrict__ winr,
                                                   const float* __restrict__ wini,
                                                   float* __restrict__ pr,
                                                   float* __restrict__ pi) {
    int idx = blockIdx.x * 256 + threadIdx.x;    // (2048/8)*128 = 32768
    int u = idx & 127;
    int n0 = (idx >> 7) * 8;
    float ar[8] = {}, ai[8] = {};
    for (int k = 0; k < 512; ++k) {
        float wrv = winr[k * 128 + u], wiv = wini[k * 128 + u];
#pragma unroll
        for (int g = 0; g < 8; ++g) {
            float hv = h[(size_t)(n0 + g) * 512 + k];
            ar[g] = fmaf(hv, wrv, ar[g]);
            ai[g] = fmaf(hv, wiv, ai[g]);
        }
    }
#pragma unroll
    for (int g = 0; g < 8; ++g) {
        pr[(size_t)(n0 + g) * 128 + u] = ar[g];
        pi[(size_t)(n0 + g) * 128 + u] = ai[g];
    }
}

// ---------------- RNN scan: one block per batch lane, sequential over T ----------------
__global__ __launch_bounds__(512) void scan_kernel(const float* __restrict__ done,
                                                   const float* __restrict__ sr0,
                                                   const float* __restrict__ si0,
                                                   const float* __restrict__ wrecr,
                                                   const float* __restrict__ wreci,
                                                   const float* __restrict__ pr,
                                                   const float* __restrict__ pi,
                                                   float* __restrict__ hsr,
                                                   float* __restrict__ hsi) {
    int b = blockIdx.x;
    int tid = threadIdx.x;
    int u = tid & 127;
    int s = tid >> 7;                     // k-split 0..3
    float wr[32], wi[32];
#pragma unroll
    for (int j = 0; j < 32; ++j) {
        int k = s * 32 + j;
        wr[j] = wrecr[k * 128 + u];
        wi[j] = wreci[k * 128 + u];
    }
    __shared__ float stR[128], stI[128];
    __shared__ float parR[4][128], parI[4][128];
    __shared__ float red[128];
    __shared__ float normsh;
    if (s == 0) { stR[u] = sr0[b * 128 + u]; stI[u] = si0[b * 128 + u]; }
    __syncthreads();
    for (int t = 0; t < T_STEPS; ++t) {
        float d = done[t * BATCH + b];
        if (s == 0) {
            float r = 1.f - d;
            stR[u] = r * stR[u] + d;      // blend toward init (1 + 0i)
            stI[u] = r * stI[u];
        }
        __syncthreads();
        float ar = 0.f, ai = 0.f;
#pragma unroll
        for (int j = 0; j < 32; ++j) {
            int k = s * 32 + j;
            float srk = stR[k], sik = stI[k];
            ar = fmaf(srk, wr[j], ar); ar = fmaf(-sik, wi[j], ar);
            ai = fmaf(srk, wi[j], ai); ai = fmaf(sik, wr[j], ai);
        }
        parR[s][u] = ar; parI[s][u] = ai;
        __syncthreads();
        float pre_r = 0.f, pre_i = 0.f;
        if (s == 0) {
            int np = (t * BATCH + b) * 128 + u;
            pre_r = parR[0][u] + parR[1][u] + parR[2][u] + parR[3][u] + pr[np];
            pre_i = parI[0][u] + parI[1][u] + parI[2][u] + parI[3][u] + pi[np];
            red[u] = pre_r * pre_r + pre_i * pre_i;
        }
        __syncthreads();
        if (tid < 64) {
            float v = red[tid] + red[tid + 64];
#pragma unroll
            for (int off = 32; off; off >>= 1) v += __shfl_down(v, off);
            if (tid == 0) normsh = v;
        }
        __syncthreads();
        if (s == 0) {
            float scale = NORM_SCALE / sqrtf(normsh);
            float nr = pre_r * scale, ni = pre_i * scale;
            stR[u] = nr; stI[u] = ni;
            int np = (t * BATCH + b) * 128 + u;
            hsr[np] = nr; hsi[np] = ni;
        }
        __syncthreads();
    }
}

// ---------------- heads: out[2048][7] ----------------
__global__ void heads_kernel(const float* __restrict__ hsr, const float* __restrict__ hsi,
                             const float* __restrict__ aw, const float* __restrict__ ab,
                             const float* __restrict__ cw, const float* __restrict__ cb,
                             float* __restrict__ out) {
    int idx = blockIdx.x * 256 + threadIdx.x;    // 14336
    if (idx >= N_FRAMES * 7) return;
    int j = idx % 7;
    int n = idx / 7;
    float acc;
    if (j < 6) {
        acc = ab[j];
        for (int k = 0; k < 128; ++k) acc = fmaf(hsr[n * 128 + k], aw[k * 6 + j], acc);
        for (int k = 0; k < 128; ++k) acc = fmaf(hsi[n * 128 + k], aw[(128 + k) * 6 + j], acc);
    } else {
        acc = cb[0];
        for (int k = 0; k < 128; ++k) acc = fmaf(hsr[n * 128 + k], cw[k], acc);
        for (int k = 0; k < 128; ++k) acc = fmaf(hsi[n * 128 + k], cw[128 + k], acc);
    }
    out[idx] = acc;
}

// ---------------- launch ----------------
extern "C" void kernel_launch(void* const* d_in, const int* in_sizes, int n_in,
                              void* d_out, int out_size, void* d_ws, size_t ws_size,
                              hipStream_t stream) {
    const float* x        = (const float*)d_in[0];
    const float* done     = (const float*)d_in[1];
    const float* sr0      = (const float*)d_in[2];
    const float* si0      = (const float*)d_in[3];
    const float* conv1_w  = (const float*)d_in[4];
    const float* conv1_b  = (const float*)d_in[5];
    const float* conv2_w  = (const float*)d_in[6];
    const float* conv2_b  = (const float*)d_in[7];
    const float* conv3_w  = (const float*)d_in[8];
    const float* conv3_b  = (const float*)d_in[9];
    const float* fc_w     = (const float*)d_in[10];
    const float* fc_b     = (const float*)d_in[11];
    const float* win_r    = (const float*)d_in[12];
    const float* win_i    = (const float*)d_in[13];
    const float* wrec_r   = (const float*)d_in[14];
    const float* wrec_i   = (const float*)d_in[15];
    const float* actor_w  = (const float*)d_in[16];
    const float* actor_b  = (const float*)d_in[17];
    const float* critic_w = (const float*)d_in[18];
    const float* critic_b = (const float*)d_in[19];

    float* ws = (float*)d_ws;
    float* w1p  = ws + OFF_W1P;
    float* w2p  = ws + OFF_W2P;
    float* w3p  = ws + OFF_W3P;
    float* fcwp = ws + OFF_FCWP;
    float* hsr  = ws + OFF_HSR;
    float* hsi  = ws + OFF_HSI;
    float* prj  = ws + OFF_PROJR;
    float* pij  = ws + OFF_PROJI;
    float* h    = ws + OFF_H;
    float* y2   = ws + OFF_Y2;
    float* y1   = ws + OFF_Y1;
    float* y3   = ws + OFF_Y3;
    float* outp = (float*)d_out;

    hipLaunchKernelGGL(permute_w1, dim3(24), dim3(256), 0, stream, conv1_w, w1p);
    hipLaunchKernelGGL(permute_w2, dim3(128), dim3(256), 0, stream, conv2_w, w2p);
    hipLaunchKernelGGL(permute_w3, dim3(144), dim3(256), 0, stream, conv3_w, w3p);
    hipLaunchKernelGGL(permute_fcw, dim3(6272), dim3(256), 0, stream, fc_w, fcwp);

    hipLaunchKernelGGL(conv1_kernel, dim3(4096), dim3(256), 0, stream, x, w1p, conv1_b, y1);
    hipLaunchKernelGGL(conv2_kernel, dim3(2048), dim3(256), 0, stream, y1, w2p, conv2_b, y2);
    hipLaunchKernelGGL(conv3_kernel, dim3(2048), dim3(256), 0, stream, y2, w3p, conv3_b, y3);
    hipLaunchKernelGGL(fc_kernel, dim3(256), dim3(256), 0, stream, y3, fcwp, fc_b, h);
    hipLaunchKernelGGL(proj_kernel, dim3(128), dim3(256), 0, stream, h, win_r, win_i, prj, pij);
    hipLaunchKernelGGL(scan_kernel, dim3(16), dim3(512), 0, stream,
                       done, sr0, si0, wrec_r, wrec_i, prj, pij, hsr, hsi);
    hipLaunchKernelGGL(heads_kernel, dim3(56), dim3(256), 0, stream,
                       hsr, hsi, actor_w, actor_b, critic_w, critic_b, outp);
}

// Round 5
// 1057.104 us; speedup vs baseline: 1.8500x; 1.0393x over previous
//
#include <hip/hip_runtime.h>

// ---------------- problem constants ----------------
#define N_FRAMES 2048          // T*B
#define T_STEPS  128
#define BATCH    16
#define UNITS    128
#define NORM_SCALE 11.313708498984760390f  // sqrt(128)

// ---------------- workspace layout (float elements) ----------------
static const size_t OFF_W1P   = 0;            // 6144   : conv1 w [ky][kx][ic][oc] * (1/255)
static const size_t OFF_W2P   = 6144;         // 32768  : conv2 w [kk][ic][oc]
static const size_t OFF_W3P   = 38912;        // 36864  : conv3 w [kk][ic][oc]
static const size_t OFF_FCWP  = 75776;        // 1605632: fc w permuted to k'=p*64+c
static const size_t OFF_HSR   = 1681408;      // 262144
static const size_t OFF_HSI   = 1943552;      // 262144
static const size_t OFF_PROJR = 2205696;      // 262144
static const size_t OFF_PROJI = 2467840;      // 262144
static const size_t OFF_H     = 2729984;      // 1048576 : fc output [2048][512]
static const size_t OFF_Y2    = 3778560;      // 10616832: [2048][9][9][64]
static const size_t OFF_Y1    = 14395392;     // 26214400: [2048][20][20][32]
static const size_t OFF_Y3    = OFF_Y1;       // 6422528 : [2048][7][7][64] (reuses y1 after conv2)

// ---------------- weight permutes ----------------
__global__ void permute_w1(const float* __restrict__ w, float* __restrict__ o) {
    int i = blockIdx.x * 256 + threadIdx.x;      // 6144
    if (i >= 32 * 3 * 64) return;
    int oc = i & 31; int r = i >> 5; int ic = r % 3; int kk = r / 3;
    int kx = kk & 7, ky = kk >> 3;
    o[i] = w[((oc * 3 + ic) * 8 + ky) * 8 + kx] * (1.0f / 255.0f);
}
__global__ void permute_w2(const float* __restrict__ w, float* __restrict__ o) {
    int i = blockIdx.x * 256 + threadIdx.x;      // 32768
    if (i >= 64 * 32 * 16) return;
    int oc = i & 63; int r = i >> 6; int ic = r & 31; int kk = r >> 5;
    int kx = kk & 3, ky = kk >> 2;
    o[i] = w[((oc * 32 + ic) * 4 + ky) * 4 + kx];
}
__global__ void permute_w3(const float* __restrict__ w, float* __restrict__ o) {
    int i = blockIdx.x * 256 + threadIdx.x;      // 36864
    if (i >= 64 * 64 * 9) return;
    int oc = i & 63; int r = i >> 6; int ic = r & 63; int kk = r >> 6;
    int kx = kk % 3, ky = kk / 3;
    o[i] = w[((oc * 64 + ic) * 3 + ky) * 3 + kx];
}
__global__ void permute_fcw(const float* __restrict__ w, float* __restrict__ o) {
    // o[(p*64+c)*512 + j] = w[(c*49+p)*512 + j]
    int i = blockIdx.x * 256 + threadIdx.x;      // 1605632
    if (i >= 3136 * 512) return;
    int j = i & 511; int kp = i >> 9; int c = kp & 63; int p = kp >> 6;
    o[i] = w[(size_t)(c * 49 + p) * 512 + j];
}

#define FMA16(xv)                                              \
    acc[j][0] = fmaf(xv.x, wv[0].x, acc[j][0]);                \
    acc[j][1] = fmaf(xv.x, wv[0].y, acc[j][1]);                \
    acc[j][2] = fmaf(xv.x, wv[0].z, acc[j][2]);                \
    acc[j][3] = fmaf(xv.x, wv[0].w, acc[j][3]);                \
    acc[j][0] = fmaf(xv.y, wv[1].x, acc[j][0]);                \
    acc[j][1] = fmaf(xv.y, wv[1].y, acc[j][1]);                \
    acc[j][2] = fmaf(xv.y, wv[1].z, acc[j][2]);                \
    acc[j][3] = fmaf(xv.y, wv[1].w, acc[j][3]);                \
    acc[j][0] = fmaf(xv.z, wv[2].x, acc[j][0]);                \
    acc[j][1] = fmaf(xv.z, wv[2].y, acc[j][1]);                \
    acc[j][2] = fmaf(xv.z, wv[2].z, acc[j][2]);                \
    acc[j][3] = fmaf(xv.z, wv[2].w, acc[j][3]);                \
    acc[j][0] = fmaf(xv.w, wv[3].x, acc[j][0]);                \
    acc[j][1] = fmaf(xv.w, wv[3].y, acc[j][1]);                \
    acc[j][2] = fmaf(xv.w, wv[3].z, acc[j][2]);                \
    acc[j][3] = fmaf(xv.w, wv[3].w, acc[j][3]);

// ---------------- conv1 v3: quarter-strips, x-only LDS, weights from global ----------------
// block = (n, q): 5 output rows, 24 input rows (24.2 KB LDS). 8192 blocks.
// thread = 4 px x 4 oc (ocg=tid&7, pg=tid>>3 < 25; p = j*25+pg).
__global__ __launch_bounds__(256, 5) void conv1_kernel(const float* __restrict__ x,
                                                       const float* __restrict__ w,
                                                       const float* __restrict__ b,
                                                       float* __restrict__ y) {
    __shared__ float xs[24 * 252];    // 24192 B
    int tid = threadIdx.x;
    int blk = blockIdx.x;
    int n = blk >> 2, q = blk & 3;

    const float4* xb4 = reinterpret_cast<const float4*>(x + (size_t)n * 21168 + q * 20 * 252);
    float4* xs4 = reinterpret_cast<float4*>(xs);
#pragma unroll
    for (int it = 0; it < 6; ++it) {
        int i = it * 256 + tid;
        if (i < 1512) xs4[i] = xb4[i];
    }
    __syncthreads();

    int ocg = tid & 7;
    int pg = tid >> 3;
    if (pg < 25) {
        int baseo[4];
        int pidx[4];
#pragma unroll
        for (int j = 0; j < 4; ++j) {
            int p = j * 25 + pg;          // local pixel in [0,100)
            pidx[j] = p;
            int oy = p / 20, ox = p % 20;
            baseo[j] = oy * 1008 + ox * 12;   // (oy*4)*252 + ox*12
        }
        const float4* wg4 = reinterpret_cast<const float4*>(w);
        float acc[4][4] = {};
#pragma unroll 2
        for (int ky = 0; ky < 8; ++ky) {
#pragma unroll
            for (int rq = 0; rq < 6; ++rq) {
                float4 wv[4];
#pragma unroll
                for (int m = 0; m < 4; ++m)
                    wv[m] = wg4[(ky * 24 + rq * 4 + m) * 8 + ocg];
#pragma unroll
                for (int j = 0; j < 4; ++j) {
                    float4 xv = *reinterpret_cast<const float4*>(&xs[baseo[j] + ky * 252 + rq * 4]);
                    FMA16(xv)
                }
            }
        }
        float4 bv = reinterpret_cast<const float4*>(b)[ocg];
#pragma unroll
        for (int j = 0; j < 4; ++j) {
            float4 o;
            o.x = fmaxf(acc[j][0] + bv.x, 0.f);
            o.y = fmaxf(acc[j][1] + bv.y, 0.f);
            o.z = fmaxf(acc[j][2] + bv.z, 0.f);
            o.w = fmaxf(acc[j][3] + bv.w, 0.f);
            size_t off = ((size_t)(n * 400 + q * 100 + pidx[j]) * 32) + ocg * 4;
            *reinterpret_cast<float4*>(&y[off]) = o;
        }
    }
}

// ---------------- conv2 v3: 1 image/block, swizzled LDS x, weights from global ----------------
__global__ __launch_bounds__(256, 3) void conv2_kernel(const float* __restrict__ y1,
                                                       const float* __restrict__ w,
                                                       const float* __restrict__ b,
                                                       float* __restrict__ y2) {
    __shared__ float xs[12800];
    int tid = threadIdx.x;
    int n = blockIdx.x;
    const float4* xg = reinterpret_cast<const float4*>(y1 + (size_t)n * 12800);
#pragma unroll
    for (int q = 0; q < 13; ++q) {
        int i = q * 256 + tid;
        if (i < 3200) {
            int px = i >> 3, qq = i & 7;
            float4 v = xg[i];
            *reinterpret_cast<float4*>(&xs[px * 32 + ((qq * 4) ^ ((px & 3) << 3))]) = v;
        }
    }
    __syncthreads();

    int ocg = tid & 15;
    int pg = tid >> 4;
    int ibase[6];
    bool valid[6];
#pragma unroll
    for (int j = 0; j < 6; ++j) {
        int p = pg + 16 * j;
        valid[j] = p < 81;
        int pp = valid[j] ? p : 0;
        ibase[j] = (pp / 9) * 40 + (pp % 9) * 2;
    }
    const float4* wg4 = reinterpret_cast<const float4*>(w);
    float acc[6][4] = {};
#pragma unroll 1
    for (int kk = 0; kk < 16; ++kk) {
        int ky = kk >> 2, kx = kk & 3;
        int koff = ky * 20 + kx;
        int ib[6], sz[6];
#pragma unroll
        for (int j = 0; j < 6; ++j) {
            int ipx = ibase[j] + koff;
            ib[j] = ipx * 32;
            sz[j] = (ipx & 3) << 3;
        }
        const float4* wkk = wg4 + kk * 512 + ocg;
#pragma unroll 2
        for (int icv = 0; icv < 8; ++icv) {
            float4 wv[4];
#pragma unroll
            for (int i = 0; i < 4; ++i) wv[i] = wkk[(icv * 4 + i) * 16];
#pragma unroll
            for (int j = 0; j < 6; ++j) {
                float4 xv = *reinterpret_cast<const float4*>(&xs[ib[j] + ((icv * 4) ^ sz[j])]);
                FMA16(xv)
            }
        }
    }
    float4 bv = reinterpret_cast<const float4*>(b)[ocg];
#pragma unroll
    for (int j = 0; j < 6; ++j) {
        if (valid[j]) {
            int p = pg + 16 * j;
            float4 o;
            o.x = fmaxf(acc[j][0] + bv.x, 0.f);
            o.y = fmaxf(acc[j][1] + bv.y, 0.f);
            o.z = fmaxf(acc[j][2] + bv.z, 0.f);
            o.w = fmaxf(acc[j][3] + bv.w, 0.f);
            *reinterpret_cast<float4*>(&y2[((size_t)n * 81 + p) * 64 + ocg * 4]) = o;
        }
    }
}

// ---------------- conv3 v3: 1 image/block, swizzled LDS x, weights from global ----------------
__global__ __launch_bounds__(256, 4) void conv3_kernel(const float* __restrict__ y2,
                                                       const float* __restrict__ w,
                                                       const float* __restrict__ b,
                                                       float* __restrict__ y3) {
    __shared__ float xs[5184];
    int tid = threadIdx.x;
    int n = blockIdx.x;
    const float4* xg = reinterpret_cast<const float4*>(y2 + (size_t)n * 5184);
#pragma unroll
    for (int q = 0; q < 6; ++q) {
        int i = q * 256 + tid;
        if (i < 1296) {
            int px = i >> 4, qq = i & 15;
            float4 v = xg[i];
            *reinterpret_cast<float4*>(&xs[px * 64 + ((qq * 4) ^ ((px & 7) << 3))]) = v;
        }
    }
    __syncthreads();

    int ocg = tid & 15;
    int pg = tid >> 4;
    int ibase[4];
    bool valid[4];
#pragma unroll
    for (int j = 0; j < 4; ++j) {
        int p = pg + 16 * j;
        valid[j] = p < 49;
        int pp = valid[j] ? p : 0;
        ibase[j] = (pp / 7) * 9 + (pp % 7);
    }
    const float4* wg4 = reinterpret_cast<const float4*>(w);
    float acc[4][4] = {};
#pragma unroll 1
    for (int kk = 0; kk < 9; ++kk) {
        int ky = kk / 3, kx = kk % 3;
        int koff = ky * 9 + kx;
        int ib[4], sz[4];
#pragma unroll
        for (int j = 0; j < 4; ++j) {
            int ipx = ibase[j] + koff;
            ib[j] = ipx * 64;
            sz[j] = (ipx & 7) << 3;
        }
        const float4* wkk = wg4 + kk * 1024 + ocg;
#pragma unroll 2
        for (int icv = 0; icv < 16; ++icv) {
            float4 wv[4];
#pragma unroll
            for (int i = 0; i < 4; ++i) wv[i] = wkk[(icv * 4 + i) * 16];
#pragma unroll
            for (int j = 0; j < 4; ++j) {
                float4 xv = *reinterpret_cast<const float4*>(&xs[ib[j] + ((icv * 4) ^ sz[j])]);
                FMA16(xv)
            }
        }
    }
    float4 bv = reinterpret_cast<const float4*>(b)[ocg];
#pragma unroll
    for (int j = 0; j < 4; ++j) {
        if (valid[j]) {
            int p = pg + 16 * j;
            float4 o;
            o.x = fmaxf(acc[j][0] + bv.x, 0.f);
            o.y = fmaxf(acc[j][1] + bv.y, 0.f);
            o.z = fmaxf(acc[j][2] + bv.z, 0.f);
            o.w = fmaxf(acc[j][3] + bv.w, 0.f);
            *reinterpret_cast<float4*>(&y3[(size_t)n * 3136 + p * 64 + ocg * 4]) = o;
        }
    }
}

// ---------------- FC: h[2048][512] = relu(y3 @ fcwp + fc_b) ----------------
__global__ __launch_bounds__(256) void fc_kernel(const float* __restrict__ A,
                                                 const float* __restrict__ B,
                                                 const float* __restrict__ bias,
                                                 float* __restrict__ C) {
    __shared__ float As[16][64];
    __shared__ float Bs[16][64];
    int tid = threadIdx.x;
    int bm = blockIdx.x & 31;       // 32 M-tiles
    int bn = blockIdx.x >> 5;       // 8 N-tiles
    int row0 = bm * 64, col0 = bn * 64;
    int tr = tid >> 4, tc = tid & 15;
    float acc[4][4] = {};
    int am = tid >> 2, ak = (tid & 3) * 4;
    int bk = tid >> 4, bn4 = (tid & 15) * 4;
    for (int k0 = 0; k0 < 3136; k0 += 16) {
        float4 av = *reinterpret_cast<const float4*>(A + (size_t)(row0 + am) * 3136 + k0 + ak);
        As[ak][am] = av.x; As[ak + 1][am] = av.y; As[ak + 2][am] = av.z; As[ak + 3][am] = av.w;
        float4 bv = *reinterpret_cast<const float4*>(B + (size_t)(k0 + bk) * 512 + col0 + bn4);
        *reinterpret_cast<float4*>(&Bs[bk][bn4]) = bv;
        __syncthreads();
#pragma unroll
        for (int kk = 0; kk < 16; ++kk) {
            float4 a4 = *reinterpret_cast<const float4*>(&As[kk][tr * 4]);
            float4 b4 = *reinterpret_cast<const float4*>(&Bs[kk][tc * 4]);
            const float a[4] = {a4.x, a4.y, a4.z, a4.w};
            const float bb[4] = {b4.x, b4.y, b4.z, b4.w};
#pragma unroll
            for (int i = 0; i < 4; ++i)
#pragma unroll
                for (int j = 0; j < 4; ++j) acc[i][j] = fmaf(a[i], bb[j], acc[i][j]);
        }
        __syncthreads();
    }
#pragma unroll
    for (int i = 0; i < 4; ++i)
#pragma unroll
        for (int j = 0; j < 4; ++j) {
            int r = row0 + tr * 4 + i, c = col0 + tc * 4 + j;
            C[(size_t)r * 512 + c] = fmaxf(acc[i][j] + bias[c], 0.f);
        }
}

// ---------------- proj: h[2048][512] @ win -> proj_{r,i}[2048][128] ----------------
__global__ __launch_bounds__(256) void proj_kernel(const float* __restrict__ h,
                                                   const float* __restrict__ winr,
                                                   const float* __restrict__ wini,
                                                   float* __restrict__ pr,
                                                   float* __restrict__ pi) {
    int idx = blockIdx.x * 256 + threadIdx.x;    // (2048/8)*128 = 32768
    int u = idx & 127;
    int n0 = (idx >> 7) * 8;
    float ar[8] = {}, ai[8] = {};
    for (int k = 0; k < 512; ++k) {
        float wrv = winr[k * 128 + u], wiv = wini[k * 128 + u];
#pragma unroll
        for (int g = 0; g < 8; ++g) {
            float hv = h[(size_t)(n0 + g) * 512 + k];
            ar[g] = fmaf(hv, wrv, ar[g]);
            ai[g] = fmaf(hv, wiv, ai[g]);
        }
    }
#pragma unroll
    for (int g = 0; g < 8; ++g) {
        pr[(size_t)(n0 + g) * 128 + u] = ar[g];
        pi[(size_t)(n0 + g) * 128 + u] = ai[g];
    }
}

// ---------------- RNN scan: one block per batch lane, sequential over T ----------------
__global__ __launch_bounds__(512) void scan_kernel(const float* __restrict__ done,
                                                   const float* __restrict__ sr0,
                                                   const float* __restrict__ si0,
                                                   const float* __restrict__ wrecr,
                                                   const float* __restrict__ wreci,
                                                   const float* __restrict__ pr,
                                                   const float* __restrict__ pi,
                                                   float* __restrict__ hsr,
                                                   float* __restrict__ hsi) {
    int b = blockIdx.x;
    int tid = threadIdx.x;
    int u = tid & 127;
    int s = tid >> 7;                     // k-split 0..3
    float wr[32], wi[32];
#pragma unroll
    for (int j = 0; j < 32; ++j) {
        int k = s * 32 + j;
        wr[j] = wrecr[k * 128 + u];
        wi[j] = wreci[k * 128 + u];
    }
    __shared__ float stR[128], stI[128];
    __shared__ float parR[4][128], parI[4][128];
    __shared__ float red[128];
    __shared__ float normsh;
    if (s == 0) { stR[u] = sr0[b * 128 + u]; stI[u] = si0[b * 128 + u]; }
    __syncthreads();
    for (int t = 0; t < T_STEPS; ++t) {
        float d = done[t * BATCH + b];
        if (s == 0) {
            float r = 1.f - d;
            stR[u] = r * stR[u] + d;      // blend toward init (1 + 0i)
            stI[u] = r * stI[u];
        }
        __syncthreads();
        float ar = 0.f, ai = 0.f;
#pragma unroll
        for (int j = 0; j < 32; ++j) {
            int k = s * 32 + j;
            float srk = stR[k], sik = stI[k];
            ar = fmaf(srk, wr[j], ar); ar = fmaf(-sik, wi[j], ar);
            ai = fmaf(srk, wi[j], ai); ai = fmaf(sik, wr[j], ai);
        }
        parR[s][u] = ar; parI[s][u] = ai;
        __syncthreads();
        float pre_r = 0.f, pre_i = 0.f;
        if (s == 0) {
            int np = (t * BATCH + b) * 128 + u;
            pre_r = parR[0][u] + parR[1][u] + parR[2][u] + parR[3][u] + pr[np];
            pre_i = parI[0][u] + parI[1][u] + parI[2][u] + parI[3][u] + pi[np];
            red[u] = pre_r * pre_r + pre_i * pre_i;
        }
        __syncthreads();
        if (tid < 64) {
            float v = red[tid] + red[tid + 64];
#pragma unroll
            for (int off = 32; off; off >>= 1) v += __shfl_down(v, off);
            if (tid == 0) normsh = v;
        }
        __syncthreads();
        if (s == 0) {
            float scale = NORM_SCALE / sqrtf(normsh);
            float nr = pre_r * scale, ni = pre_i * scale;
            stR[u] = nr; stI[u] = ni;
            int np = (t * BATCH + b) * 128 + u;
            hsr[np] = nr; hsi[np] = ni;
        }
        __syncthreads();
    }
}

// ---------------- heads: out[2048][7] ----------------
__global__ void heads_kernel(const float* __restrict__ hsr, const float* __restrict__ hsi,
                             const float* __restrict__ aw, const float* __restrict__ ab,
                             const float* __restrict__ cw, const float* __restrict__ cb,
                             float* __restrict__ out) {
    int idx = blockIdx.x * 256 + threadIdx.x;    // 14336
    if (idx >= N_FRAMES * 7) return;
    int j = idx % 7;
    int n = idx / 7;
    float acc;
    if (j < 6) {
        acc = ab[j];
        for (int k = 0; k < 128; ++k) acc = fmaf(hsr[n * 128 + k], aw[k * 6 + j], acc);
        for (int k = 0; k < 128; ++k) acc = fmaf(hsi[n * 128 + k], aw[(128 + k) * 6 + j], acc);
    } else {
        acc = cb[0];
        for (int k = 0; k < 128; ++k) acc = fmaf(hsr[n * 128 + k], cw[k], acc);
        for (int k = 0; k < 128; ++k) acc = fmaf(hsi[n * 128 + k], cw[128 + k], acc);
    }
    out[idx] = acc;
}

// ---------------- launch ----------------
extern "C" void kernel_launch(void* const* d_in, const int* in_sizes, int n_in,
                              void* d_out, int out_size, void* d_ws, size_t ws_size,
                              hipStream_t stream) {
    const float* x        = (const float*)d_in[0];
    const float* done     = (const float*)d_in[1];
    const float* sr0      = (const float*)d_in[2];
    const float* si0      = (const float*)d_in[3];
    const float* conv1_w  = (const float*)d_in[4];
    const float* conv1_b  = (const float*)d_in[5];
    const float* conv2_w  = (const float*)d_in[6];
    const float* conv2_b  = (const float*)d_in[7];
    const float* conv3_w  = (const float*)d_in[8];
    const float* conv3_b  = (const float*)d_in[9];
    const float* fc_w     = (const float*)d_in[10];
    const float* fc_b     = (const float*)d_in[11];
    const float* win_r    = (const float*)d_in[12];
    const float* win_i    = (const float*)d_in[13];
    const float* wrec_r   = (const float*)d_in[14];
    const float* wrec_i   = (const float*)d_in[15];
    const float* actor_w  = (const float*)d_in[16];
    const float* actor_b  = (const float*)d_in[17];
    const float* critic_w = (const float*)d_in[18];
    const float* critic_b = (const float*)d_in[19];

    float* ws = (float*)d_ws;
    float* w1p  = ws + OFF_W1P;
    float* w2p  = ws + OFF_W2P;
    float* w3p  = ws + OFF_W3P;
    float* fcwp = ws + OFF_FCWP;
    float* hsr  = ws + OFF_HSR;
    float* hsi  = ws + OFF_HSI;
    float* prj  = ws + OFF_PROJR;
    float* pij  = ws + OFF_PROJI;
    float* h    = ws + OFF_H;
    float* y2   = ws + OFF_Y2;
    float* y1   = ws + OFF_Y1;
    float* y3   = ws + OFF_Y3;
    float* outp = (float*)d_out;

    hipLaunchKernelGGL(permute_w1, dim3(24), dim3(256), 0, stream, conv1_w, w1p);
    hipLaunchKernelGGL(permute_w2, dim3(128), dim3(256), 0, stream, conv2_w, w2p);
    hipLaunchKernelGGL(permute_w3, dim3(144), dim3(256), 0, stream, conv3_w, w3p);
    hipLaunchKernelGGL(permute_fcw, dim3(6272), dim3(256), 0, stream, fc_w, fcwp);

    hipLaunchKernelGGL(conv1_kernel, dim3(8192), dim3(256), 0, stream, x, w1p, conv1_b, y1);
    hipLaunchKernelGGL(conv2_kernel, dim3(2048), dim3(256), 0, stream, y1, w2p, conv2_b, y2);
    hipLaunchKernelGGL(conv3_kernel, dim3(2048), dim3(256), 0, stream, y2, w3p, conv3_b, y3);
    hipLaunchKernelGGL(fc_kernel, dim3(256), dim3(256), 0, stream, y3, fcwp, fc_b, h);
    hipLaunchKernelGGL(proj_kernel, dim3(128), dim3(256), 0, stream, h, win_r, win_i, prj, pij);
    hipLaunchKernelGGL(scan_kernel, dim3(16), dim3(512), 0, stream,
                       done, sr0, si0, wrec_r, wrec_i, prj, pij, hsr, hsi);
    hipLaunchKernelGGL(heads_kernel, dim3(56), dim3(256), 0, stream,
                       hsr, hsi, actor_w, actor_b, critic_w, critic_b, outp);
}

// Round 6
// 1047.385 us; speedup vs baseline: 1.8672x; 1.0093x over previous
//
#include <hip/hip_runtime.h>

// ---------------- problem constants ----------------
#define N_FRAMES 2048          // T*B
#define T_STEPS  128
#define BATCH    16
#define UNITS    128
#define NORM_SCALE 11.313708498984760390f  // sqrt(128)

// ---------------- workspace layout (float elements) ----------------
static const size_t OFF_W1P   = 0;            // 6144   : conv1 w [ky][kx][ic][oc] * (1/255)
static const size_t OFF_W2P   = 6144;         // 32768  : conv2 w [kk][ic][oc]
static const size_t OFF_W3P   = 38912;        // 36864  : conv3 w [kk][ic][oc]
static const size_t OFF_FCWP  = 75776;        // 1605632: fc w permuted to k'=p*64+c
static const size_t OFF_HSR   = 1681408;      // 262144
static const size_t OFF_HSI   = 1943552;      // 262144
static const size_t OFF_PROJR = 2205696;      // 262144
static const size_t OFF_PROJI = 2467840;      // 262144
static const size_t OFF_H     = 2729984;      // 1048576 : fc output [2048][512]
static const size_t OFF_Y2    = 3778560;      // 10616832: [2048][9][9][64]
static const size_t OFF_Y1    = 14395392;     // 26214400: [2048][20][20][32]
static const size_t OFF_Y3    = OFF_Y1;       // 6422528 : [2048][7][7][64] (reuses y1 after conv2)

// ---------------- weight permutes ----------------
__global__ void permute_w1(const float* __restrict__ w, float* __restrict__ o) {
    int i = blockIdx.x * 256 + threadIdx.x;      // 6144
    if (i >= 32 * 3 * 64) return;
    int oc = i & 31; int r = i >> 5; int ic = r % 3; int kk = r / 3;
    int kx = kk & 7, ky = kk >> 3;
    o[i] = w[((oc * 3 + ic) * 8 + ky) * 8 + kx] * (1.0f / 255.0f);
}
__global__ void permute_w2(const float* __restrict__ w, float* __restrict__ o) {
    int i = blockIdx.x * 256 + threadIdx.x;      // 32768
    if (i >= 64 * 32 * 16) return;
    int oc = i & 63; int r = i >> 6; int ic = r & 31; int kk = r >> 5;
    int kx = kk & 3, ky = kk >> 2;
    o[i] = w[((oc * 32 + ic) * 4 + ky) * 4 + kx];
}
__global__ void permute_w3(const float* __restrict__ w, float* __restrict__ o) {
    int i = blockIdx.x * 256 + threadIdx.x;      // 36864
    if (i >= 64 * 64 * 9) return;
    int oc = i & 63; int r = i >> 6; int ic = r & 63; int kk = r >> 6;
    int kx = kk % 3, ky = kk / 3;
    o[i] = w[((oc * 64 + ic) * 3 + ky) * 3 + kx];
}
__global__ void permute_fcw(const float* __restrict__ w, float* __restrict__ o) {
    // o[(p*64+c)*512 + j] = w[(c*49+p)*512 + j]
    int i = blockIdx.x * 256 + threadIdx.x;      // 1605632
    if (i >= 3136 * 512) return;
    int j = i & 511; int kp = i >> 9; int c = kp & 63; int p = kp >> 6;
    o[i] = w[(size_t)(c * 49 + p) * 512 + j];
}

#define FMA16(xv)                                              \
    acc[j][0] = fmaf(xv.x, wv[0].x, acc[j][0]);                \
    acc[j][1] = fmaf(xv.x, wv[0].y, acc[j][1]);                \
    acc[j][2] = fmaf(xv.x, wv[0].z, acc[j][2]);                \
    acc[j][3] = fmaf(xv.x, wv[0].w, acc[j][3]);                \
    acc[j][0] = fmaf(xv.y, wv[1].x, acc[j][0]);                \
    acc[j][1] = fmaf(xv.y, wv[1].y, acc[j][1]);                \
    acc[j][2] = fmaf(xv.y, wv[1].z, acc[j][2]);                \
    acc[j][3] = fmaf(xv.y, wv[1].w, acc[j][3]);                \
    acc[j][0] = fmaf(xv.z, wv[2].x, acc[j][0]);                \
    acc[j][1] = fmaf(xv.z, wv[2].y, acc[j][1]);                \
    acc[j][2] = fmaf(xv.z, wv[2].z, acc[j][2]);                \
    acc[j][3] = fmaf(xv.z, wv[2].w, acc[j][3]);                \
    acc[j][0] = fmaf(xv.w, wv[3].x, acc[j][0]);                \
    acc[j][1] = fmaf(xv.w, wv[3].y, acc[j][1]);                \
    acc[j][2] = fmaf(xv.w, wv[3].z, acc[j][2]);                \
    acc[j][3] = fmaf(xv.w, wv[3].w, acc[j][3]);

// ---------------- conv1 v4: half-image strips, x-only LDS, weights from global,
// 8 px x 4 oc per thread (128 FMA per 4-load weight group). ----------------
__global__ __launch_bounds__(256, 3) void conv1_kernel(const float* __restrict__ x,
                                                       const float* __restrict__ w,
                                                       const float* __restrict__ b,
                                                       float* __restrict__ y) {
    __shared__ float xs[44 * 252];    // 44352 B
    int tid = threadIdx.x;
    int blk = blockIdx.x;
    int n = blk >> 1, hb = blk & 1;

    const float4* xb4 = reinterpret_cast<const float4*>(x + (size_t)n * 21168 + hb * 40 * 252);
    float4* xs4 = reinterpret_cast<float4*>(xs);
#pragma unroll
    for (int it = 0; it < 11; ++it) {
        int i = it * 256 + tid;
        if (i < 2772) xs4[i] = xb4[i];
    }
    __syncthreads();

    int ocg = tid & 7;
    int pg = tid >> 3;
    if (pg < 25) {
        int baseo[8];
        int pidx[8];
#pragma unroll
        for (int j = 0; j < 8; ++j) {
            int p = j * 25 + pg;          // local pixel in [0,200)
            pidx[j] = p;
            int oy = p / 20, ox = p % 20;
            baseo[j] = oy * 1008 + ox * 12;   // (oy*4)*252 + ox*12
        }
        const float4* wg4 = reinterpret_cast<const float4*>(w);
        float acc[8][4] = {};
#pragma unroll 2
        for (int ky = 0; ky < 8; ++ky) {
#pragma unroll
            for (int rq = 0; rq < 6; ++rq) {
                float4 wv[4];
#pragma unroll
                for (int m = 0; m < 4; ++m)
                    wv[m] = wg4[(ky * 24 + rq * 4 + m) * 8 + ocg];
#pragma unroll
                for (int j = 0; j < 8; ++j) {
                    float4 xv = *reinterpret_cast<const float4*>(&xs[baseo[j] + ky * 252 + rq * 4]);
                    FMA16(xv)
                }
            }
        }
        float4 bv = reinterpret_cast<const float4*>(b)[ocg];
#pragma unroll
        for (int j = 0; j < 8; ++j) {
            float4 o;
            o.x = fmaxf(acc[j][0] + bv.x, 0.f);
            o.y = fmaxf(acc[j][1] + bv.y, 0.f);
            o.z = fmaxf(acc[j][2] + bv.z, 0.f);
            o.w = fmaxf(acc[j][3] + bv.w, 0.f);
            size_t off = ((size_t)(n * 400 + hb * 200 + pidx[j]) * 32) + ocg * 4;
            *reinterpret_cast<float4*>(&y[off]) = o;
        }
    }
}

// ---------------- conv2 v3: 1 image/block, swizzled LDS x, weights from global ----------------
__global__ __launch_bounds__(256, 3) void conv2_kernel(const float* __restrict__ y1,
                                                       const float* __restrict__ w,
                                                       const float* __restrict__ b,
                                                       float* __restrict__ y2) {
    __shared__ float xs[12800];
    int tid = threadIdx.x;
    int n = blockIdx.x;
    const float4* xg = reinterpret_cast<const float4*>(y1 + (size_t)n * 12800);
#pragma unroll
    for (int q = 0; q < 13; ++q) {
        int i = q * 256 + tid;
        if (i < 3200) {
            int px = i >> 3, qq = i & 7;
            float4 v = xg[i];
            *reinterpret_cast<float4*>(&xs[px * 32 + ((qq * 4) ^ ((px & 3) << 3))]) = v;
        }
    }
    __syncthreads();

    int ocg = tid & 15;
    int pg = tid >> 4;
    int ibase[6];
    bool valid[6];
#pragma unroll
    for (int j = 0; j < 6; ++j) {
        int p = pg + 16 * j;
        valid[j] = p < 81;
        int pp = valid[j] ? p : 0;
        ibase[j] = (pp / 9) * 40 + (pp % 9) * 2;
    }
    const float4* wg4 = reinterpret_cast<const float4*>(w);
    float acc[6][4] = {};
#pragma unroll 1
    for (int kk = 0; kk < 16; ++kk) {
        int ky = kk >> 2, kx = kk & 3;
        int koff = ky * 20 + kx;
        int ib[6], sz[6];
#pragma unroll
        for (int j = 0; j < 6; ++j) {
            int ipx = ibase[j] + koff;
            ib[j] = ipx * 32;
            sz[j] = (ipx & 3) << 3;
        }
        const float4* wkk = wg4 + kk * 512 + ocg;
#pragma unroll 2
        for (int icv = 0; icv < 8; ++icv) {
            float4 wv[4];
#pragma unroll
            for (int i = 0; i < 4; ++i) wv[i] = wkk[(icv * 4 + i) * 16];
#pragma unroll
            for (int j = 0; j < 6; ++j) {
                float4 xv = *reinterpret_cast<const float4*>(&xs[ib[j] + ((icv * 4) ^ sz[j])]);
                FMA16(xv)
            }
        }
    }
    float4 bv = reinterpret_cast<const float4*>(b)[ocg];
#pragma unroll
    for (int j = 0; j < 6; ++j) {
        if (valid[j]) {
            int p = pg + 16 * j;
            float4 o;
            o.x = fmaxf(acc[j][0] + bv.x, 0.f);
            o.y = fmaxf(acc[j][1] + bv.y, 0.f);
            o.z = fmaxf(acc[j][2] + bv.z, 0.f);
            o.w = fmaxf(acc[j][3] + bv.w, 0.f);
            *reinterpret_cast<float4*>(&y2[((size_t)n * 81 + p) * 64 + ocg * 4]) = o;
        }
    }
}

// ---------------- conv3 v3: 1 image/block, swizzled LDS x, weights from global ----------------
__global__ __launch_bounds__(256, 4) void conv3_kernel(const float* __restrict__ y2,
                                                       const float* __restrict__ w,
                                                       const float* __restrict__ b,
                                                       float* __restrict__ y3) {
    __shared__ float xs[5184];
    int tid = threadIdx.x;
    int n = blockIdx.x;
    const float4* xg = reinterpret_cast<const float4*>(y2 + (size_t)n * 5184);
#pragma unroll
    for (int q = 0; q < 6; ++q) {
        int i = q * 256 + tid;
        if (i < 1296) {
            int px = i >> 4, qq = i & 15;
            float4 v = xg[i];
            *reinterpret_cast<float4*>(&xs[px * 64 + ((qq * 4) ^ ((px & 7) << 3))]) = v;
        }
    }
    __syncthreads();

    int ocg = tid & 15;
    int pg = tid >> 4;
    int ibase[4];
    bool valid[4];
#pragma unroll
    for (int j = 0; j < 4; ++j) {
        int p = pg + 16 * j;
        valid[j] = p < 49;
        int pp = valid[j] ? p : 0;
        ibase[j] = (pp / 7) * 9 + (pp % 7);
    }
    const float4* wg4 = reinterpret_cast<const float4*>(w);
    float acc[4][4] = {};
#pragma unroll 1
    for (int kk = 0; kk < 9; ++kk) {
        int ky = kk / 3, kx = kk % 3;
        int koff = ky * 9 + kx;
        int ib[4], sz[4];
#pragma unroll
        for (int j = 0; j < 4; ++j) {
            int ipx = ibase[j] + koff;
            ib[j] = ipx * 64;
            sz[j] = (ipx & 7) << 3;
        }
        const float4* wkk = wg4 + kk * 1024 + ocg;
#pragma unroll 2
        for (int icv = 0; icv < 16; ++icv) {
            float4 wv[4];
#pragma unroll
            for (int i = 0; i < 4; ++i) wv[i] = wkk[(icv * 4 + i) * 16];
#pragma unroll
            for (int j = 0; j < 4; ++j) {
                float4 xv = *reinterpret_cast<const float4*>(&xs[ib[j] + ((icv * 4) ^ sz[j])]);
                FMA16(xv)
            }
        }
    }
    float4 bv = reinterpret_cast<const float4*>(b)[ocg];
#pragma unroll
    for (int j = 0; j < 4; ++j) {
        if (valid[j]) {
            int p = pg + 16 * j;
            float4 o;
            o.x = fmaxf(acc[j][0] + bv.x, 0.f);
            o.y = fmaxf(acc[j][1] + bv.y, 0.f);
            o.z = fmaxf(acc[j][2] + bv.z, 0.f);
            o.w = fmaxf(acc[j][3] + bv.w, 0.f);
            *reinterpret_cast<float4*>(&y3[(size_t)n * 3136 + p * 64 + ocg * 4]) = o;
        }
    }
}

// ---------------- FC: h[2048][512] = relu(y3 @ fcwp + fc_b) ----------------
__global__ __launch_bounds__(256) void fc_kernel(const float* __restrict__ A,
                                                 const float* __restrict__ B,
                                                 const float* __restrict__ bias,
                                                 float* __restrict__ C) {
    __shared__ float As[16][64];
    __shared__ float Bs[16][64];
    int tid = threadIdx.x;
    int bm = blockIdx.x & 31;       // 32 M-tiles
    int bn = blockIdx.x >> 5;       // 8 N-tiles
    int row0 = bm * 64, col0 = bn * 64;
    int tr = tid >> 4, tc = tid & 15;
    float acc[4][4] = {};
    int am = tid >> 2, ak = (tid & 3) * 4;
    int bk = tid >> 4, bn4 = (tid & 15) * 4;
    for (int k0 = 0; k0 < 3136; k0 += 16) {
        float4 av = *reinterpret_cast<const float4*>(A + (size_t)(row0 + am) * 3136 + k0 + ak);
        As[ak][am] = av.x; As[ak + 1][am] = av.y; As[ak + 2][am] = av.z; As[ak + 3][am] = av.w;
        float4 bv = *reinterpret_cast<const float4*>(B + (size_t)(k0 + bk) * 512 + col0 + bn4);
        *reinterpret_cast<float4*>(&Bs[bk][bn4]) = bv;
        __syncthreads();
#pragma unroll
        for (int kk = 0; kk < 16; ++kk) {
            float4 a4 = *reinterpret_cast<const float4*>(&As[kk][tr * 4]);
            float4 b4 = *reinterpret_cast<const float4*>(&Bs[kk][tc * 4]);
            const float a[4] = {a4.x, a4.y, a4.z, a4.w};
            const float bb[4] = {b4.x, b4.y, b4.z, b4.w};
#pragma unroll
            for (int i = 0; i < 4; ++i)
#pragma unroll
                for (int j = 0; j < 4; ++j) acc[i][j] = fmaf(a[i], bb[j], acc[i][j]);
        }
        __syncthreads();
    }
#pragma unroll
    for (int i = 0; i < 4; ++i)
#pragma unroll
        for (int j = 0; j < 4; ++j) {
            int r = row0 + tr * 4 + i, c = col0 + tc * 4 + j;
            C[(size_t)r * 512 + c] = fmaxf(acc[i][j] + bias[c], 0.f);
        }
}

// ---------------- proj: h[2048][512] @ win -> proj_{r,i}[2048][128] ----------------
__global__ __launch_bounds__(256) void proj_kernel(const float* __restrict__ h,
                                                   const float* __restrict__ winr,
                                                   const float* __restrict__ wini,
                                                   float* __restrict__ pr,
                                                   float* __restrict__ pi) {
    int idx = blockIdx.x * 256 + threadIdx.x;    // (2048/8)*128 = 32768
    int u = idx & 127;
    int n0 = (idx >> 7) * 8;
    float ar[8] = {}, ai[8] = {};
    for (int k = 0; k < 512; ++k) {
        float wrv = winr[k * 128 + u], wiv = wini[k * 128 + u];
#pragma unroll
        for (int g = 0; g < 8; ++g) {
            float hv = h[(size_t)(n0 + g) * 512 + k];
            ar[g] = fmaf(hv, wrv, ar[g]);
            ai[g] = fmaf(hv, wiv, ai[g]);
        }
    }
#pragma unroll
    for (int g = 0; g < 8; ++g) {
        pr[(size_t)(n0 + g) * 128 + u] = ar[g];
        pi[(size_t)(n0 + g) * 128 + u] = ai[g];
    }
}

// ---------------- RNN scan: one block per batch lane, sequential over T ----------------
__global__ __launch_bounds__(512) void scan_kernel(const float* __restrict__ done,
                                                   const float* __restrict__ sr0,
                                                   const float* __restrict__ si0,
                                                   const float* __restrict__ wrecr,
                                                   const float* __restrict__ wreci,
                                                   const float* __restrict__ pr,
                                                   const float* __restrict__ pi,
                                                   float* __restrict__ hsr,
                                                   float* __restrict__ hsi) {
    int b = blockIdx.x;
    int tid = threadIdx.x;
    int u = tid & 127;
    int s = tid >> 7;                     // k-split 0..3
    float wr[32], wi[32];
#pragma unroll
    for (int j = 0; j < 32; ++j) {
        int k = s * 32 + j;
        wr[j] = wrecr[k * 128 + u];
        wi[j] = wreci[k * 128 + u];
    }
    __shared__ float stR[128], stI[128];
    __shared__ float parR[4][128], parI[4][128];
    __shared__ float red[128];
    __shared__ float normsh;
    if (s == 0) { stR[u] = sr0[b * 128 + u]; stI[u] = si0[b * 128 + u]; }
    __syncthreads();
    for (int t = 0; t < T_STEPS; ++t) {
        float d = done[t * BATCH + b];
        if (s == 0) {
            float r = 1.f - d;
            stR[u] = r * stR[u] + d;      // blend toward init (1 + 0i)
            stI[u] = r * stI[u];
        }
        __syncthreads();
        float ar = 0.f, ai = 0.f;
#pragma unroll
        for (int j = 0; j < 32; ++j) {
            int k = s * 32 + j;
            float srk = stR[k], sik = stI[k];
            ar = fmaf(srk, wr[j], ar); ar = fmaf(-sik, wi[j], ar);
            ai = fmaf(srk, wi[j], ai); ai = fmaf(sik, wr[j], ai);
        }
        parR[s][u] = ar; parI[s][u] = ai;
        __syncthreads();
        float pre_r = 0.f, pre_i = 0.f;
        if (s == 0) {
            int np = (t * BATCH + b) * 128 + u;
            pre_r = parR[0][u] + parR[1][u] + parR[2][u] + parR[3][u] + pr[np];
            pre_i = parI[0][u] + parI[1][u] + parI[2][u] + parI[3][u] + pi[np];
            red[u] = pre_r * pre_r + pre_i * pre_i;
        }
        __syncthreads();
        if (tid < 64) {
            float v = red[tid] + red[tid + 64];
#pragma unroll
            for (int off = 32; off; off >>= 1) v += __shfl_down(v, off);
            if (tid == 0) normsh = v;
        }
        __syncthreads();
        if (s == 0) {
            float scale = NORM_SCALE / sqrtf(normsh);
            float nr = pre_r * scale, ni = pre_i * scale;
            stR[u] = nr; stI[u] = ni;
            int np = (t * BATCH + b) * 128 + u;
            hsr[np] = nr; hsi[np] = ni;
        }
        __syncthreads();
    }
}

// ---------------- heads: out[2048][7] ----------------
__global__ void heads_kernel(const float* __restrict__ hsr, const float* __restrict__ hsi,
                             const float* __restrict__ aw, const float* __restrict__ ab,
                             const float* __restrict__ cw, const float* __restrict__ cb,
                             float* __restrict__ out) {
    int idx = blockIdx.x * 256 + threadIdx.x;    // 14336
    if (idx >= N_FRAMES * 7) return;
    int j = idx % 7;
    int n = idx / 7;
    float acc;
    if (j < 6) {
        acc = ab[j];
        for (int k = 0; k < 128; ++k) acc = fmaf(hsr[n * 128 + k], aw[k * 6 + j], acc);
        for (int k = 0; k < 128; ++k) acc = fmaf(hsi[n * 128 + k], aw[(128 + k) * 6 + j], acc);
    } else {
        acc = cb[0];
        for (int k = 0; k < 128; ++k) acc = fmaf(hsr[n * 128 + k], cw[k], acc);
        for (int k = 0; k < 128; ++k) acc = fmaf(hsi[n * 128 + k], cw[128 + k], acc);
    }
    out[idx] = acc;
}

// ---------------- launch ----------------
extern "C" void kernel_launch(void* const* d_in, const int* in_sizes, int n_in,
                              void* d_out, int out_size, void* d_ws, size_t ws_size,
                              hipStream_t stream) {
    const float* x        = (const float*)d_in[0];
    const float* done     = (const float*)d_in[1];
    const float* sr0      = (const float*)d_in[2];
    const float* si0      = (const float*)d_in[3];
    const float* conv1_w  = (const float*)d_in[4];
    const float* conv1_b  = (const float*)d_in[5];
    const float* conv2_w  = (const float*)d_in[6];
    const float* conv2_b  = (const float*)d_in[7];
    const float* conv3_w  = (const float*)d_in[8];
    const float* conv3_b  = (const float*)d_in[9];
    const float* fc_w     = (const float*)d_in[10];
    const float* fc_b     = (const float*)d_in[11];
    const float* win_r    = (const float*)d_in[12];
    const float* win_i    = (const float*)d_in[13];
    const float* wrec_r   = (const float*)d_in[14];
    const float* wrec_i   = (const float*)d_in[15];
    const float* actor_w  = (const float*)d_in[16];
    const float* actor_b  = (const float*)d_in[17];
    const float* critic_w = (const float*)d_in[18];
    const float* critic_b = (const float*)d_in[19];

    float* ws = (float*)d_ws;
    float* w1p  = ws + OFF_W1P;
    float* w2p  = ws + OFF_W2P;
    float* w3p  = ws + OFF_W3P;
    float* fcwp = ws + OFF_FCWP;
    float* hsr  = ws + OFF_HSR;
    float* hsi  = ws + OFF_HSI;
    float* prj  = ws + OFF_PROJR;
    float* pij  = ws + OFF_PROJI;
    float* h    = ws + OFF_H;
    float* y2   = ws + OFF_Y2;
    float* y1   = ws + OFF_Y1;
    float* y3   = ws + OFF_Y3;
    float* outp = (float*)d_out;

    hipLaunchKernelGGL(permute_w1, dim3(24), dim3(256), 0, stream, conv1_w, w1p);
    hipLaunchKernelGGL(permute_w2, dim3(128), dim3(256), 0, stream, conv2_w, w2p);
    hipLaunchKernelGGL(permute_w3, dim3(144), dim3(256), 0, stream, conv3_w, w3p);
    hipLaunchKernelGGL(permute_fcw, dim3(6272), dim3(256), 0, stream, fc_w, fcwp);

    hipLaunchKernelGGL(conv1_kernel, dim3(4096), dim3(256), 0, stream, x, w1p, conv1_b, y1);
    hipLaunchKernelGGL(conv2_kernel, dim3(2048), dim3(256), 0, stream, y1, w2p, conv2_b, y2);
    hipLaunchKernelGGL(conv3_kernel, dim3(2048), dim3(256), 0, stream, y2, w3p, conv3_b, y3);
    hipLaunchKernelGGL(fc_kernel, dim3(256), dim3(256), 0, stream, y3, fcwp, fc_b, h);
    hipLaunchKernelGGL(proj_kernel, dim3(128), dim3(256), 0, stream, h, win_r, win_i, prj, pij);
    hipLaunchKernelGGL(scan_kernel, dim3(16), dim3(512), 0, stream,
                       done, sr0, si0, wrec_r, wrec_i, prj, pij, hsr, hsi);
    hipLaunchKernelGGL(heads_kernel, dim3(56), dim3(256), 0, stream,
                       hsr, hsi, actor_w, actor_b, critic_w, critic_b, outp);
}

// Round 7
// 896.575 us; speedup vs baseline: 2.1812x; 1.1682x over previous
//
#include <hip/hip_runtime.h>
#include <hip/hip_bf16.h>

// ---------------- problem constants ----------------
#define N_FRAMES 2048          // T*B
#define T_STEPS  128
#define BATCH    16
#define UNITS    128
#define NORM_SCALE 11.313708498984760390f  // sqrt(128)

typedef short bf16x8 __attribute__((ext_vector_type(8)));
typedef float f32x4 __attribute__((ext_vector_type(4)));

static __device__ inline unsigned short f2bf(float f) {
    __hip_bfloat16 h = __float2bfloat16(f);
    return __builtin_bit_cast(unsigned short, h);
}

// ---------------- workspace layout (float elements) ----------------
static const size_t OFF_W1P   = 0;            // 16KB as ushort: conv1 MFMA weights [ky][nt][lane][8]
static const size_t OFF_W2P   = 6144;         // 32768  : conv2 w [kk][ic][oc]
static const size_t OFF_W3P   = 38912;        // 36864  : conv3 w [kk][ic][oc]
static const size_t OFF_FCWP  = 75776;        // 1605632: fc w permuted to k'=p*64+c
static const size_t OFF_HSR   = 1681408;      // 262144
static const size_t OFF_HSI   = 1943552;      // 262144
static const size_t OFF_PROJR = 2205696;      // 262144
static const size_t OFF_PROJI = 2467840;      // 262144
static const size_t OFF_H     = 2729984;      // 1048576 : fc output [2048][512]
static const size_t OFF_Y2    = 3778560;      // 10616832: [2048][9][9][64]
static const size_t OFF_Y1    = 14395392;     // 26214400: [2048][20][20][32]
static const size_t OFF_Y3    = OFF_Y1;       // 6422528 : [2048][7][7][64] (reuses y1 after conv2)

// ---------------- weight permutes ----------------
// conv1 MFMA weight: o[ky][nt][lane][j] (bf16) = w[oc=nt*16+(lane&15)][ic][ky][kx]*(1/255)
// where t=(lane>>4)*8+j in [0,32): t<24 -> kx=t/3, ic=t%3 ; t>=24 -> 0 (K padding)
__global__ void permute_w1mf(const float* __restrict__ w, unsigned short* __restrict__ o) {
    int i = blockIdx.x * 256 + threadIdx.x;      // 8192 = 8ky * 2nt * 64lane * 8j
    if (i >= 8192) return;
    int j = i & 7; int lane = (i >> 3) & 63; int nt = (i >> 9) & 1; int ky = i >> 10;
    int t = (lane >> 4) * 8 + j;
    int oc = nt * 16 + (lane & 15);
    float v = 0.f;
    if (t < 24) {
        int kx = t / 3, ic = t % 3;
        v = w[((oc * 3 + ic) * 8 + ky) * 8 + kx] * (1.0f / 255.0f);
    }
    o[i] = f2bf(v);
}
__global__ void permute_w2(const float* __restrict__ w, float* __restrict__ o) {
    int i = blockIdx.x * 256 + threadIdx.x;      // 32768
    if (i >= 64 * 32 * 16) return;
    int oc = i & 63; int r = i >> 6; int ic = r & 31; int kk = r >> 5;
    int kx = kk & 3, ky = kk >> 2;
    o[i] = w[((oc * 32 + ic) * 4 + ky) * 4 + kx];
}
__global__ void permute_w3(const float* __restrict__ w, float* __restrict__ o) {
    int i = blockIdx.x * 256 + threadIdx.x;      // 36864
    if (i >= 64 * 64 * 9) return;
    int oc = i & 63; int r = i >> 6; int ic = r & 63; int kk = r >> 6;
    int kx = kk % 3, ky = kk / 3;
    o[i] = w[((oc * 64 + ic) * 3 + ky) * 3 + kx];
}
__global__ void permute_fcw(const float* __restrict__ w, float* __restrict__ o) {
    // o[(p*64+c)*512 + j] = w[(c*49+p)*512 + j]
    int i = blockIdx.x * 256 + threadIdx.x;      // 1605632
    if (i >= 3136 * 512) return;
    int j = i & 511; int kp = i >> 9; int c = kp & 63; int p = kp >> 6;
    o[i] = w[(size_t)(c * 49 + p) * 512 + j];
}

#define FMA16(xv)                                              \
    acc[j][0] = fmaf(xv.x, wv[0].x, acc[j][0]);                \
    acc[j][1] = fmaf(xv.x, wv[0].y, acc[j][1]);                \
    acc[j][2] = fmaf(xv.x, wv[0].z, acc[j][2]);                \
    acc[j][3] = fmaf(xv.x, wv[0].w, acc[j][3]);                \
    acc[j][0] = fmaf(xv.y, wv[1].x, acc[j][0]);                \
    acc[j][1] = fmaf(xv.y, wv[1].y, acc[j][1]);                \
    acc[j][2] = fmaf(xv.y, wv[1].z, acc[j][2]);                \
    acc[j][3] = fmaf(xv.y, wv[1].w, acc[j][3]);                \
    acc[j][0] = fmaf(xv.z, wv[2].x, acc[j][0]);                \
    acc[j][1] = fmaf(xv.z, wv[2].y, acc[j][1]);                \
    acc[j][2] = fmaf(xv.z, wv[2].z, acc[j][2]);                \
    acc[j][3] = fmaf(xv.z, wv[2].w, acc[j][3]);                \
    acc[j][0] = fmaf(xv.w, wv[3].x, acc[j][0]);                \
    acc[j][1] = fmaf(xv.w, wv[3].y, acc[j][1]);                \
    acc[j][2] = fmaf(xv.w, wv[3].z, acc[j][2]);                \
    acc[j][3] = fmaf(xv.w, wv[3].w, acc[j][3]);

// ---------------- conv1 v5: MFMA implicit GEMM ----------------
// block = half image (200 px). LDS: x as bf16, 44 rows * 252 + 8 pad = 22.2 KB.
// M-tiles of 16 px (13 tiles, last masked), N = 2 tiles of 16 oc, K = 8 ky-steps of 32
// (patch row padded 24->32 with zero WEIGHTS so padded A reads are annihilated).
__global__ __launch_bounds__(256) void conv1_kernel(const float* __restrict__ x,
                                                    const unsigned short* __restrict__ wmf,
                                                    const float* __restrict__ b,
                                                    float* __restrict__ y) {
    __shared__ unsigned short xs[11096];
    int tid = threadIdx.x;
    int blk = blockIdx.x;
    int n = blk >> 1, hb = blk & 1;

    // stage x rows hb*40 .. +43 as bf16 (convert in flight)
    const float4* xb4 = reinterpret_cast<const float4*>(x + (size_t)n * 21168 + hb * 40 * 252);
#pragma unroll
    for (int it = 0; it < 11; ++it) {
        int i = it * 256 + tid;
        if (i < 2772) {
            float4 v = xb4[i];
            ushort4 h;
            h.x = f2bf(v.x); h.y = f2bf(v.y); h.z = f2bf(v.z); h.w = f2bf(v.w);
            *reinterpret_cast<ushort4*>(&xs[i * 4]) = h;
        }
    }
    if (tid < 8) xs[11088 + tid] = 0;   // zero the overrun pad (NaN safety)
    __syncthreads();

    int lane = tid & 63;
    int wv = tid >> 6;
    int row = lane & 15;     // A: pixel row ; B/D: oc col
    int seg = lane >> 4;     // k-segment (A/B), row-group (D)
    const uint4* wm = reinterpret_cast<const uint4*>(wmf);
    float b0 = b[row];
    float b1 = b[16 + row];
    int pbase = n * 400 + hb * 200;

    for (int tile = wv; tile < 13; tile += 4) {
        int p = tile * 16 + row; if (p > 199) p = 199;   // clamp A-reads for masked rows
        int eb = (p / 20) * 1008 + (p % 20) * 12 + seg * 8;
        f32x4 acc0 = {0.f, 0.f, 0.f, 0.f};
        f32x4 acc1 = {0.f, 0.f, 0.f, 0.f};
#pragma unroll
        for (int ky = 0; ky < 8; ++ky) {
            int ea = eb + ky * 252;
            ushort4 lo = *reinterpret_cast<const ushort4*>(&xs[ea]);
            ushort4 hi = *reinterpret_cast<const ushort4*>(&xs[ea + 4]);
            bf16x8 a = {(short)lo.x, (short)lo.y, (short)lo.z, (short)lo.w,
                        (short)hi.x, (short)hi.y, (short)hi.z, (short)hi.w};
            bf16x8 w0 = __builtin_bit_cast(bf16x8, wm[(ky * 2 + 0) * 64 + lane]);
            bf16x8 w1 = __builtin_bit_cast(bf16x8, wm[(ky * 2 + 1) * 64 + lane]);
            acc0 = __builtin_amdgcn_mfma_f32_16x16x32_bf16(a, w0, acc0, 0, 0, 0);
            acc1 = __builtin_amdgcn_mfma_f32_16x16x32_bf16(a, w1, acc1, 0, 0, 0);
        }
#pragma unroll
        for (int r = 0; r < 4; ++r) {
            int pl = tile * 16 + seg * 4 + r;            // D row = (lane>>4)*4 + r
            if (pl < 200) {
                float* yp = y + ((size_t)(pbase + pl)) * 32 + row;
                yp[0]  = fmaxf(acc0[r] + b0, 0.f);
                yp[16] = fmaxf(acc1[r] + b1, 0.f);
            }
        }
    }
}

// ---------------- conv2 v3: 1 image/block, swizzled LDS x, weights from global ----------------
__global__ __launch_bounds__(256, 3) void conv2_kernel(const float* __restrict__ y1,
                                                       const float* __restrict__ w,
                                                       const float* __restrict__ b,
                                                       float* __restrict__ y2) {
    __shared__ float xs[12800];
    int tid = threadIdx.x;
    int n = blockIdx.x;
    const float4* xg = reinterpret_cast<const float4*>(y1 + (size_t)n * 12800);
#pragma unroll
    for (int q = 0; q < 13; ++q) {
        int i = q * 256 + tid;
        if (i < 3200) {
            int px = i >> 3, qq = i & 7;
            float4 v = xg[i];
            *reinterpret_cast<float4*>(&xs[px * 32 + ((qq * 4) ^ ((px & 3) << 3))]) = v;
        }
    }
    __syncthreads();

    int ocg = tid & 15;
    int pg = tid >> 4;
    int ibase[6];
    bool valid[6];
#pragma unroll
    for (int j = 0; j < 6; ++j) {
        int p = pg + 16 * j;
        valid[j] = p < 81;
        int pp = valid[j] ? p : 0;
        ibase[j] = (pp / 9) * 40 + (pp % 9) * 2;
    }
    const float4* wg4 = reinterpret_cast<const float4*>(w);
    float acc[6][4] = {};
#pragma unroll 1
    for (int kk = 0; kk < 16; ++kk) {
        int ky = kk >> 2, kx = kk & 3;
        int koff = ky * 20 + kx;
        int ib[6], sz[6];
#pragma unroll
        for (int j = 0; j < 6; ++j) {
            int ipx = ibase[j] + koff;
            ib[j] = ipx * 32;
            sz[j] = (ipx & 3) << 3;
        }
        const float4* wkk = wg4 + kk * 512 + ocg;
#pragma unroll 2
        for (int icv = 0; icv < 8; ++icv) {
            float4 wv[4];
#pragma unroll
            for (int i = 0; i < 4; ++i) wv[i] = wkk[(icv * 4 + i) * 16];
#pragma unroll
            for (int j = 0; j < 6; ++j) {
                float4 xv = *reinterpret_cast<const float4*>(&xs[ib[j] + ((icv * 4) ^ sz[j])]);
                FMA16(xv)
            }
        }
    }
    float4 bv = reinterpret_cast<const float4*>(b)[ocg];
#pragma unroll
    for (int j = 0; j < 6; ++j) {
        if (valid[j]) {
            int p = pg + 16 * j;
            float4 o;
            o.x = fmaxf(acc[j][0] + bv.x, 0.f);
            o.y = fmaxf(acc[j][1] + bv.y, 0.f);
            o.z = fmaxf(acc[j][2] + bv.z, 0.f);
            o.w = fmaxf(acc[j][3] + bv.w, 0.f);
            *reinterpret_cast<float4*>(&y2[((size_t)n * 81 + p) * 64 + ocg * 4]) = o;
        }
    }
}

// ---------------- conv3 v3: 1 image/block, swizzled LDS x, weights from global ----------------
__global__ __launch_bounds__(256, 4) void conv3_kernel(const float* __restrict__ y2,
                                                       const float* __restrict__ w,
                                                       const float* __restrict__ b,
                                                       float* __restrict__ y3) {
    __shared__ float xs[5184];
    int tid = threadIdx.x;
    int n = blockIdx.x;
    const float4* xg = reinterpret_cast<const float4*>(y2 + (size_t)n * 5184);
#pragma unroll
    for (int q = 0; q < 6; ++q) {
        int i = q * 256 + tid;
        if (i < 1296) {
            int px = i >> 4, qq = i & 15;
            float4 v = xg[i];
            *reinterpret_cast<float4*>(&xs[px * 64 + ((qq * 4) ^ ((px & 7) << 3))]) = v;
        }
    }
    __syncthreads();

    int ocg = tid & 15;
    int pg = tid >> 4;
    int ibase[4];
    bool valid[4];
#pragma unroll
    for (int j = 0; j < 4; ++j) {
        int p = pg + 16 * j;
        valid[j] = p < 49;
        int pp = valid[j] ? p : 0;
        ibase[j] = (pp / 7) * 9 + (pp % 7);
    }
    const float4* wg4 = reinterpret_cast<const float4*>(w);
    float acc[4][4] = {};
#pragma unroll 1
    for (int kk = 0; kk < 9; ++kk) {
        int ky = kk / 3, kx = kk % 3;
        int koff = ky * 9 + kx;
        int ib[4], sz[4];
#pragma unroll
        for (int j = 0; j < 4; ++j) {
            int ipx = ibase[j] + koff;
            ib[j] = ipx * 64;
            sz[j] = (ipx & 7) << 3;
        }
        const float4* wkk = wg4 + kk * 1024 + ocg;
#pragma unroll 2
        for (int icv = 0; icv < 16; ++icv) {
            float4 wv[4];
#pragma unroll
            for (int i = 0; i < 4; ++i) wv[i] = wkk[(icv * 4 + i) * 16];
#pragma unroll
            for (int j = 0; j < 4; ++j) {
                float4 xv = *reinterpret_cast<const float4*>(&xs[ib[j] + ((icv * 4) ^ sz[j])]);
                FMA16(xv)
            }
        }
    }
    float4 bv = reinterpret_cast<const float4*>(b)[ocg];
#pragma unroll
    for (int j = 0; j < 4; ++j) {
        if (valid[j]) {
            int p = pg + 16 * j;
            float4 o;
            o.x = fmaxf(acc[j][0] + bv.x, 0.f);
            o.y = fmaxf(acc[j][1] + bv.y, 0.f);
            o.z = fmaxf(acc[j][2] + bv.z, 0.f);
            o.w = fmaxf(acc[j][3] + bv.w, 0.f);
            *reinterpret_cast<float4*>(&y3[(size_t)n * 3136 + p * 64 + ocg * 4]) = o;
        }
    }
}

// ---------------- FC: h[2048][512] = relu(y3 @ fcwp + fc_b) ----------------
__global__ __launch_bounds__(256) void fc_kernel(const float* __restrict__ A,
                                                 const float* __restrict__ B,
                                                 const float* __restrict__ bias,
                                                 float* __restrict__ C) {
    __shared__ float As[16][64];
    __shared__ float Bs[16][64];
    int tid = threadIdx.x;
    int bm = blockIdx.x & 31;       // 32 M-tiles
    int bn = blockIdx.x >> 5;       // 8 N-tiles
    int row0 = bm * 64, col0 = bn * 64;
    int tr = tid >> 4, tc = tid & 15;
    float acc[4][4] = {};
    int am = tid >> 2, ak = (tid & 3) * 4;
    int bk = tid >> 4, bn4 = (tid & 15) * 4;
    for (int k0 = 0; k0 < 3136; k0 += 16) {
        float4 av = *reinterpret_cast<const float4*>(A + (size_t)(row0 + am) * 3136 + k0 + ak);
        As[ak][am] = av.x; As[ak + 1][am] = av.y; As[ak + 2][am] = av.z; As[ak + 3][am] = av.w;
        float4 bv = *reinterpret_cast<const float4*>(B + (size_t)(k0 + bk) * 512 + col0 + bn4);
        *reinterpret_cast<float4*>(&Bs[bk][bn4]) = bv;
        __syncthreads();
#pragma unroll
        for (int kk = 0; kk < 16; ++kk) {
            float4 a4 = *reinterpret_cast<const float4*>(&As[kk][tr * 4]);
            float4 b4 = *reinterpret_cast<const float4*>(&Bs[kk][tc * 4]);
            const float a[4] = {a4.x, a4.y, a4.z, a4.w};
            const float bb[4] = {b4.x, b4.y, b4.z, b4.w};
#pragma unroll
            for (int i = 0; i < 4; ++i)
#pragma unroll
                for (int j = 0; j < 4; ++j) acc[i][j] = fmaf(a[i], bb[j], acc[i][j]);
        }
        __syncthreads();
    }
#pragma unroll
    for (int i = 0; i < 4; ++i)
#pragma unroll
        for (int j = 0; j < 4; ++j) {
            int r = row0 + tr * 4 + i, c = col0 + tc * 4 + j;
            C[(size_t)r * 512 + c] = fmaxf(acc[i][j] + bias[c], 0.f);
        }
}

// ---------------- proj: h[2048][512] @ win -> proj_{r,i}[2048][128] ----------------
__global__ __launch_bounds__(256) void proj_kernel(const float* __restrict__ h,
                                                   const float* __restrict__ winr,
                                                   const float* __restrict__ wini,
                                                   float* __restrict__ pr,
                                                   float* __restrict__ pi) {
    int idx = blockIdx.x * 256 + threadIdx.x;    // (2048/8)*128 = 32768
    int u = idx & 127;
    int n0 = (idx >> 7) * 8;
    float ar[8] = {}, ai[8] = {};
    for (int k = 0; k < 512; ++k) {
        float wrv = winr[k * 128 + u], wiv = wini[k * 128 + u];
#pragma unroll
        for (int g = 0; g < 8; ++g) {
            float hv = h[(size_t)(n0 + g) * 512 + k];
            ar[g] = fmaf(hv, wrv, ar[g]);
            ai[g] = fmaf(hv, wiv, ai[g]);
        }
    }
#pragma unroll
    for (int g = 0; g < 8; ++g) {
        pr[(size_t)(n0 + g) * 128 + u] = ar[g];
        pi[(size_t)(n0 + g) * 128 + u] = ai[g];
    }
}

// ---------------- RNN scan: one block per batch lane, sequential over T ----------------
__global__ __launch_bounds__(512) void scan_kernel(const float* __restrict__ done,
                                                   const float* __restrict__ sr0,
                                                   const float* __restrict__ si0,
                                                   const float* __restrict__ wrecr,
                                                   const float* __restrict__ wreci,
                                                   const float* __restrict__ pr,
                                                   const float* __restrict__ pi,
                                                   float* __restrict__ hsr,
                                                   float* __restrict__ hsi) {
    int b = blockIdx.x;
    int tid = threadIdx.x;
    int u = tid & 127;
    int s = tid >> 7;                     // k-split 0..3
    float wr[32], wi[32];
#pragma unroll
    for (int j = 0; j < 32; ++j) {
        int k = s * 32 + j;
        wr[j] = wrecr[k * 128 + u];
        wi[j] = wreci[k * 128 + u];
    }
    __shared__ float stR[128], stI[128];
    __shared__ float parR[4][128], parI[4][128];
    __shared__ float red[128];
    __shared__ float normsh;
    if (s == 0) { stR[u] = sr0[b * 128 + u]; stI[u] = si0[b * 128 + u]; }
    __syncthreads();
    for (int t = 0; t < T_STEPS; ++t) {
        float d = done[t * BATCH + b];
        if (s == 0) {
            float r = 1.f - d;
            stR[u] = r * stR[u] + d;      // blend toward init (1 + 0i)
            stI[u] = r * stI[u];
        }
        __syncthreads();
        float ar = 0.f, ai = 0.f;
#pragma unroll
        for (int j = 0; j < 32; ++j) {
            int k = s * 32 + j;
            float srk = stR[k], sik = stI[k];
            ar = fmaf(srk, wr[j], ar); ar = fmaf(-sik, wi[j], ar);
            ai = fmaf(srk, wi[j], ai); ai = fmaf(sik, wr[j], ai);
        }
        parR[s][u] = ar; parI[s][u] = ai;
        __syncthreads();
        float pre_r = 0.f, pre_i = 0.f;
        if (s == 0) {
            int np = (t * BATCH + b) * 128 + u;
            pre_r = parR[0][u] + parR[1][u] + parR[2][u] + parR[3][u] + pr[np];
            pre_i = parI[0][u] + parI[1][u] + parI[2][u] + parI[3][u] + pi[np];
            red[u] = pre_r * pre_r + pre_i * pre_i;
        }
        __syncthreads();
        if (tid < 64) {
            float v = red[tid] + red[tid + 64];
#pragma unroll
            for (int off = 32; off; off >>= 1) v += __shfl_down(v, off);
            if (tid == 0) normsh = v;
        }
        __syncthreads();
        if (s == 0) {
            float scale = NORM_SCALE / sqrtf(normsh);
            float nr = pre_r * scale, ni = pre_i * scale;
            stR[u] = nr; stI[u] = ni;
            int np = (t * BATCH + b) * 128 + u;
            hsr[np] = nr; hsi[np] = ni;
        }
        __syncthreads();
    }
}

// ---------------- heads: out[2048][7] ----------------
__global__ void heads_kernel(const float* __restrict__ hsr, const float* __restrict__ hsi,
                             const float* __restrict__ aw, const float* __restrict__ ab,
                             const float* __restrict__ cw, const float* __restrict__ cb,
                             float* __restrict__ out) {
    int idx = blockIdx.x * 256 + threadIdx.x;    // 14336
    if (idx >= N_FRAMES * 7) return;
    int j = idx % 7;
    int n = idx / 7;
    float acc;
    if (j < 6) {
        acc = ab[j];
        for (int k = 0; k < 128; ++k) acc = fmaf(hsr[n * 128 + k], aw[k * 6 + j], acc);
        for (int k = 0; k < 128; ++k) acc = fmaf(hsi[n * 128 + k], aw[(128 + k) * 6 + j], acc);
    } else {
        acc = cb[0];
        for (int k = 0; k < 128; ++k) acc = fmaf(hsr[n * 128 + k], cw[k], acc);
        for (int k = 0; k < 128; ++k) acc = fmaf(hsi[n * 128 + k], cw[128 + k], acc);
    }
    out[idx] = acc;
}

// ---------------- launch ----------------
extern "C" void kernel_launch(void* const* d_in, const int* in_sizes, int n_in,
                              void* d_out, int out_size, void* d_ws, size_t ws_size,
                              hipStream_t stream) {
    const float* x        = (const float*)d_in[0];
    const float* done     = (const float*)d_in[1];
    const float* sr0      = (const float*)d_in[2];
    const float* si0      = (const float*)d_in[3];
    const float* conv1_w  = (const float*)d_in[4];
    const float* conv1_b  = (const float*)d_in[5];
    const float* conv2_w  = (const float*)d_in[6];
    const float* conv2_b  = (const float*)d_in[7];
    const float* conv3_w  = (const float*)d_in[8];
    const float* conv3_b  = (const float*)d_in[9];
    const float* fc_w     = (const float*)d_in[10];
    const float* fc_b     = (const float*)d_in[11];
    const float* win_r    = (const float*)d_in[12];
    const float* win_i    = (const float*)d_in[13];
    const float* wrec_r   = (const float*)d_in[14];
    const float* wrec_i   = (const float*)d_in[15];
    const float* actor_w  = (const float*)d_in[16];
    const float* actor_b  = (const float*)d_in[17];
    const float* critic_w = (const float*)d_in[18];
    const float* critic_b = (const float*)d_in[19];

    float* ws = (float*)d_ws;
    unsigned short* w1mf = (unsigned short*)(ws + OFF_W1P);
    float* w2p  = ws + OFF_W2P;
    float* w3p  = ws + OFF_W3P;
    float* fcwp = ws + OFF_FCWP;
    float* hsr  = ws + OFF_HSR;
    float* hsi  = ws + OFF_HSI;
    float* prj  = ws + OFF_PROJR;
    float* pij  = ws + OFF_PROJI;
    float* h    = ws + OFF_H;
    float* y2   = ws + OFF_Y2;
    float* y1   = ws + OFF_Y1;
    float* y3   = ws + OFF_Y3;
    float* outp = (float*)d_out;

    hipLaunchKernelGGL(permute_w1mf, dim3(32), dim3(256), 0, stream, conv1_w, w1mf);
    hipLaunchKernelGGL(permute_w2, dim3(128), dim3(256), 0, stream, conv2_w, w2p);
    hipLaunchKernelGGL(permute_w3, dim3(144), dim3(256), 0, stream, conv3_w, w3p);
    hipLaunchKernelGGL(permute_fcw, dim3(6272), dim3(256), 0, stream, fc_w, fcwp);

    hipLaunchKernelGGL(conv1_kernel, dim3(4096), dim3(256), 0, stream, x, w1mf, conv1_b, y1);
    hipLaunchKernelGGL(conv2_kernel, dim3(2048), dim3(256), 0, stream, y1, w2p, conv2_b, y2);
    hipLaunchKernelGGL(conv3_kernel, dim3(2048), dim3(256), 0, stream, y2, w3p, conv3_b, y3);
    hipLaunchKernelGGL(fc_kernel, dim3(256), dim3(256), 0, stream, y3, fcwp, fc_b, h);
    hipLaunchKernelGGL(proj_kernel, dim3(128), dim3(256), 0, stream, h, win_r, win_i, prj, pij);
    hipLaunchKernelGGL(scan_kernel, dim3(16), dim3(512), 0, stream,
                       done, sr0, si0, wrec_r, wrec_i, prj, pij, hsr, hsi);
    hipLaunchKernelGGL(heads_kernel, dim3(56), dim3(256), 0, stream,
                       hsr, hsi, actor_w, actor_b, critic_w, critic_b, outp);
}

// Round 8
// 848.619 us; speedup vs baseline: 2.3045x; 1.0565x over previous
//
#include <hip/hip_runtime.h>
#include <hip/hip_bf16.h>

// ---------------- problem constants ----------------
#define N_FRAMES 2048          // T*B
#define T_STEPS  128
#define BATCH    16
#define UNITS    128
#define NORM_SCALE 11.313708498984760390f  // sqrt(128)

typedef short bf16x8 __attribute__((ext_vector_type(8)));
typedef float f32x4 __attribute__((ext_vector_type(4)));

static __device__ inline unsigned short f2bf(float f) {
    __hip_bfloat16 h = __float2bfloat16(f);
    return __builtin_bit_cast(unsigned short, h);
}

// ---------------- workspace layout (float elements) ----------------
static const size_t OFF_W1P   = 0;            // 16KB as ushort: conv1 MFMA weights [ky][nt][lane][8]
static const size_t OFF_W2P   = 6144;         // 32768  : conv2 w [kk][ic][oc]
static const size_t OFF_W3P   = 38912;        // 36864  : conv3 w [kk][ic][oc]
static const size_t OFF_FCWP  = 75776;        // 1605632: fc w permuted to k'=p*64+c
static const size_t OFF_HSR   = 1681408;      // 262144
static const size_t OFF_HSI   = 1943552;      // 262144
static const size_t OFF_PROJR = 2205696;      // 262144
static const size_t OFF_PROJI = 2467840;      // 262144
static const size_t OFF_H     = 2729984;      // 1048576 : fc output [2048][512]
static const size_t OFF_Y2    = 3778560;      // 10616832: [2048][9][9][64]
static const size_t OFF_WRTR  = OFF_Y2;       // 16384 : wrec_r transposed [u][k] (after conv3 consumed y2)
static const size_t OFF_WRTI  = OFF_Y2 + 16384; // 16384 : wrec_i transposed
static const size_t OFF_Y1    = 14395392;     // 26214400: [2048][20][20][32]
static const size_t OFF_Y3    = OFF_Y1;       // 6422528 : [2048][7][7][64] (reuses y1 after conv2)

// ---------------- weight permutes ----------------
__global__ void permute_w1mf(const float* __restrict__ w, unsigned short* __restrict__ o) {
    int i = blockIdx.x * 256 + threadIdx.x;      // 8192 = 8ky * 2nt * 64lane * 8j
    if (i >= 8192) return;
    int j = i & 7; int lane = (i >> 3) & 63; int nt = (i >> 9) & 1; int ky = i >> 10;
    int t = (lane >> 4) * 8 + j;
    int oc = nt * 16 + (lane & 15);
    float v = 0.f;
    if (t < 24) {
        int kx = t / 3, ic = t % 3;
        v = w[((oc * 3 + ic) * 8 + ky) * 8 + kx] * (1.0f / 255.0f);
    }
    o[i] = f2bf(v);
}
__global__ void permute_w2(const float* __restrict__ w, float* __restrict__ o) {
    int i = blockIdx.x * 256 + threadIdx.x;      // 32768
    if (i >= 64 * 32 * 16) return;
    int oc = i & 63; int r = i >> 6; int ic = r & 31; int kk = r >> 5;
    int kx = kk & 3, ky = kk >> 2;
    o[i] = w[((oc * 32 + ic) * 4 + ky) * 4 + kx];
}
__global__ void permute_w3(const float* __restrict__ w, float* __restrict__ o) {
    int i = blockIdx.x * 256 + threadIdx.x;      // 36864
    if (i >= 64 * 64 * 9) return;
    int oc = i & 63; int r = i >> 6; int ic = r & 63; int kk = r >> 6;
    int kx = kk % 3, ky = kk / 3;
    o[i] = w[((oc * 64 + ic) * 3 + ky) * 3 + kx];
}
__global__ void permute_fcw(const float* __restrict__ w, float* __restrict__ o) {
    int i = blockIdx.x * 256 + threadIdx.x;      // 1605632
    if (i >= 3136 * 512) return;
    int j = i & 511; int kp = i >> 9; int c = kp & 63; int p = kp >> 6;
    o[i] = w[(size_t)(c * 49 + p) * 512 + j];
}
__global__ void permute_wrt(const float* __restrict__ wr, const float* __restrict__ wi,
                            float* __restrict__ otr, float* __restrict__ oti) {
    int i = blockIdx.x * 256 + threadIdx.x;      // 16384
    if (i >= 16384) return;
    int k = i & 127, u = i >> 7;
    otr[i] = wr[k * 128 + u];
    oti[i] = wi[k * 128 + u];
}

#define FMA16(xv)                                              \
    acc[j][0] = fmaf(xv.x, wv[0].x, acc[j][0]);                \
    acc[j][1] = fmaf(xv.x, wv[0].y, acc[j][1]);                \
    acc[j][2] = fmaf(xv.x, wv[0].z, acc[j][2]);                \
    acc[j][3] = fmaf(xv.x, wv[0].w, acc[j][3]);                \
    acc[j][0] = fmaf(xv.y, wv[1].x, acc[j][0]);                \
    acc[j][1] = fmaf(xv.y, wv[1].y, acc[j][1]);                \
    acc[j][2] = fmaf(xv.y, wv[1].z, acc[j][2]);                \
    acc[j][3] = fmaf(xv.y, wv[1].w, acc[j][3]);                \
    acc[j][0] = fmaf(xv.z, wv[2].x, acc[j][0]);                \
    acc[j][1] = fmaf(xv.z, wv[2].y, acc[j][1]);                \
    acc[j][2] = fmaf(xv.z, wv[2].z, acc[j][2]);                \
    acc[j][3] = fmaf(xv.z, wv[2].w, acc[j][3]);                \
    acc[j][0] = fmaf(xv.w, wv[3].x, acc[j][0]);                \
    acc[j][1] = fmaf(xv.w, wv[3].y, acc[j][1]);                \
    acc[j][2] = fmaf(xv.w, wv[3].z, acc[j][2]);                \
    acc[j][3] = fmaf(xv.w, wv[3].w, acc[j][3]);

// ---------------- conv1 v5: MFMA implicit GEMM (unchanged) ----------------
__global__ __launch_bounds__(256) void conv1_kernel(const float* __restrict__ x,
                                                    const unsigned short* __restrict__ wmf,
                                                    const float* __restrict__ b,
                                                    float* __restrict__ y) {
    __shared__ unsigned short xs[11096];
    int tid = threadIdx.x;
    int blk = blockIdx.x;
    int n = blk >> 1, hb = blk & 1;

    const float4* xb4 = reinterpret_cast<const float4*>(x + (size_t)n * 21168 + hb * 40 * 252);
#pragma unroll
    for (int it = 0; it < 11; ++it) {
        int i = it * 256 + tid;
        if (i < 2772) {
            float4 v = xb4[i];
            ushort4 h;
            h.x = f2bf(v.x); h.y = f2bf(v.y); h.z = f2bf(v.z); h.w = f2bf(v.w);
            *reinterpret_cast<ushort4*>(&xs[i * 4]) = h;
        }
    }
    if (tid < 8) xs[11088 + tid] = 0;
    __syncthreads();

    int lane = tid & 63;
    int wv = tid >> 6;
    int row = lane & 15;
    int seg = lane >> 4;
    const uint4* wm = reinterpret_cast<const uint4*>(wmf);
    float b0 = b[row];
    float b1 = b[16 + row];
    int pbase = n * 400 + hb * 200;

    for (int tile = wv; tile < 13; tile += 4) {
        int p = tile * 16 + row; if (p > 199) p = 199;
        int eb = (p / 20) * 1008 + (p % 20) * 12 + seg * 8;
        f32x4 acc0 = {0.f, 0.f, 0.f, 0.f};
        f32x4 acc1 = {0.f, 0.f, 0.f, 0.f};
#pragma unroll
        for (int ky = 0; ky < 8; ++ky) {
            int ea = eb + ky * 252;
            ushort4 lo = *reinterpret_cast<const ushort4*>(&xs[ea]);
            ushort4 hi = *reinterpret_cast<const ushort4*>(&xs[ea + 4]);
            bf16x8 a = {(short)lo.x, (short)lo.y, (short)lo.z, (short)lo.w,
                        (short)hi.x, (short)hi.y, (short)hi.z, (short)hi.w};
            bf16x8 w0 = __builtin_bit_cast(bf16x8, wm[(ky * 2 + 0) * 64 + lane]);
            bf16x8 w1 = __builtin_bit_cast(bf16x8, wm[(ky * 2 + 1) * 64 + lane]);
            acc0 = __builtin_amdgcn_mfma_f32_16x16x32_bf16(a, w0, acc0, 0, 0, 0);
            acc1 = __builtin_amdgcn_mfma_f32_16x16x32_bf16(a, w1, acc1, 0, 0, 0);
        }
#pragma unroll
        for (int r = 0; r < 4; ++r) {
            int pl = tile * 16 + seg * 4 + r;
            if (pl < 200) {
                float* yp = y + ((size_t)(pbase + pl)) * 32 + row;
                yp[0]  = fmaxf(acc0[r] + b0, 0.f);
                yp[16] = fmaxf(acc1[r] + b1, 0.f);
            }
        }
    }
}

// ---------------- conv2 v3 (unchanged) ----------------
__global__ __launch_bounds__(256, 3) void conv2_kernel(const float* __restrict__ y1,
                                                       const float* __restrict__ w,
                                                       const float* __restrict__ b,
                                                       float* __restrict__ y2) {
    __shared__ float xs[12800];
    int tid = threadIdx.x;
    int n = blockIdx.x;
    const float4* xg = reinterpret_cast<const float4*>(y1 + (size_t)n * 12800);
#pragma unroll
    for (int q = 0; q < 13; ++q) {
        int i = q * 256 + tid;
        if (i < 3200) {
            int px = i >> 3, qq = i & 7;
            float4 v = xg[i];
            *reinterpret_cast<float4*>(&xs[px * 32 + ((qq * 4) ^ ((px & 3) << 3))]) = v;
        }
    }
    __syncthreads();

    int ocg = tid & 15;
    int pg = tid >> 4;
    int ibase[6];
    bool valid[6];
#pragma unroll
    for (int j = 0; j < 6; ++j) {
        int p = pg + 16 * j;
        valid[j] = p < 81;
        int pp = valid[j] ? p : 0;
        ibase[j] = (pp / 9) * 40 + (pp % 9) * 2;
    }
    const float4* wg4 = reinterpret_cast<const float4*>(w);
    float acc[6][4] = {};
#pragma unroll 1
    for (int kk = 0; kk < 16; ++kk) {
        int ky = kk >> 2, kx = kk & 3;
        int koff = ky * 20 + kx;
        int ib[6], sz[6];
#pragma unroll
        for (int j = 0; j < 6; ++j) {
            int ipx = ibase[j] + koff;
            ib[j] = ipx * 32;
            sz[j] = (ipx & 3) << 3;
        }
        const float4* wkk = wg4 + kk * 512 + ocg;
#pragma unroll 2
        for (int icv = 0; icv < 8; ++icv) {
            float4 wv[4];
#pragma unroll
            for (int i = 0; i < 4; ++i) wv[i] = wkk[(icv * 4 + i) * 16];
#pragma unroll
            for (int j = 0; j < 6; ++j) {
                float4 xv = *reinterpret_cast<const float4*>(&xs[ib[j] + ((icv * 4) ^ sz[j])]);
                FMA16(xv)
            }
        }
    }
    float4 bv = reinterpret_cast<const float4*>(b)[ocg];
#pragma unroll
    for (int j = 0; j < 6; ++j) {
        if (valid[j]) {
            int p = pg + 16 * j;
            float4 o;
            o.x = fmaxf(acc[j][0] + bv.x, 0.f);
            o.y = fmaxf(acc[j][1] + bv.y, 0.f);
            o.z = fmaxf(acc[j][2] + bv.z, 0.f);
            o.w = fmaxf(acc[j][3] + bv.w, 0.f);
            *reinterpret_cast<float4*>(&y2[((size_t)n * 81 + p) * 64 + ocg * 4]) = o;
        }
    }
}

// ---------------- conv3 v3 (unchanged) ----------------
__global__ __launch_bounds__(256, 4) void conv3_kernel(const float* __restrict__ y2,
                                                       const float* __restrict__ w,
                                                       const float* __restrict__ b,
                                                       float* __restrict__ y3) {
    __shared__ float xs[5184];
    int tid = threadIdx.x;
    int n = blockIdx.x;
    const float4* xg = reinterpret_cast<const float4*>(y2 + (size_t)n * 5184);
#pragma unroll
    for (int q = 0; q < 6; ++q) {
        int i = q * 256 + tid;
        if (i < 1296) {
            int px = i >> 4, qq = i & 15;
            float4 v = xg[i];
            *reinterpret_cast<float4*>(&xs[px * 64 + ((qq * 4) ^ ((px & 7) << 3))]) = v;
        }
    }
    __syncthreads();

    int ocg = tid & 15;
    int pg = tid >> 4;
    int ibase[4];
    bool valid[4];
#pragma unroll
    for (int j = 0; j < 4; ++j) {
        int p = pg + 16 * j;
        valid[j] = p < 49;
        int pp = valid[j] ? p : 0;
        ibase[j] = (pp / 7) * 9 + (pp % 7);
    }
    const float4* wg4 = reinterpret_cast<const float4*>(w);
    float acc[4][4] = {};
#pragma unroll 1
    for (int kk = 0; kk < 9; ++kk) {
        int ky = kk / 3, kx = kk % 3;
        int koff = ky * 9 + kx;
        int ib[4], sz[4];
#pragma unroll
        for (int j = 0; j < 4; ++j) {
            int ipx = ibase[j] + koff;
            ib[j] = ipx * 64;
            sz[j] = (ipx & 7) << 3;
        }
        const float4* wkk = wg4 + kk * 1024 + ocg;
#pragma unroll 2
        for (int icv = 0; icv < 16; ++icv) {
            float4 wv[4];
#pragma unroll
            for (int i = 0; i < 4; ++i) wv[i] = wkk[(icv * 4 + i) * 16];
#pragma unroll
            for (int j = 0; j < 4; ++j) {
                float4 xv = *reinterpret_cast<const float4*>(&xs[ib[j] + ((icv * 4) ^ sz[j])]);
                FMA16(xv)
            }
        }
    }
    float4 bv = reinterpret_cast<const float4*>(b)[ocg];
#pragma unroll
    for (int j = 0; j < 4; ++j) {
        if (valid[j]) {
            int p = pg + 16 * j;
            float4 o;
            o.x = fmaxf(acc[j][0] + bv.x, 0.f);
            o.y = fmaxf(acc[j][1] + bv.y, 0.f);
            o.z = fmaxf(acc[j][2] + bv.z, 0.f);
            o.w = fmaxf(acc[j][3] + bv.w, 0.f);
            *reinterpret_cast<float4*>(&y3[(size_t)n * 3136 + p * 64 + ocg * 4]) = o;
        }
    }
}

// ---------------- FC (unchanged) ----------------
__global__ __launch_bounds__(256) void fc_kernel(const float* __restrict__ A,
                                                 const float* __restrict__ B,
                                                 const float* __restrict__ bias,
                                                 float* __restrict__ C) {
    __shared__ float As[16][64];
    __shared__ float Bs[16][64];
    int tid = threadIdx.x;
    int bm = blockIdx.x & 31;
    int bn = blockIdx.x >> 5;
    int row0 = bm * 64, col0 = bn * 64;
    int tr = tid >> 4, tc = tid & 15;
    float acc[4][4] = {};
    int am = tid >> 2, ak = (tid & 3) * 4;
    int bk = tid >> 4, bn4 = (tid & 15) * 4;
    for (int k0 = 0; k0 < 3136; k0 += 16) {
        float4 av = *reinterpret_cast<const float4*>(A + (size_t)(row0 + am) * 3136 + k0 + ak);
        As[ak][am] = av.x; As[ak + 1][am] = av.y; As[ak + 2][am] = av.z; As[ak + 3][am] = av.w;
        float4 bv = *reinterpret_cast<const float4*>(B + (size_t)(k0 + bk) * 512 + col0 + bn4);
        *reinterpret_cast<float4*>(&Bs[bk][bn4]) = bv;
        __syncthreads();
#pragma unroll
        for (int kk = 0; kk < 16; ++kk) {
            float4 a4 = *reinterpret_cast<const float4*>(&As[kk][tr * 4]);
            float4 b4 = *reinterpret_cast<const float4*>(&Bs[kk][tc * 4]);
            const float a[4] = {a4.x, a4.y, a4.z, a4.w};
            const float bb[4] = {b4.x, b4.y, b4.z, b4.w};
#pragma unroll
            for (int i = 0; i < 4; ++i)
#pragma unroll
                for (int j = 0; j < 4; ++j) acc[i][j] = fmaf(a[i], bb[j], acc[i][j]);
        }
        __syncthreads();
    }
#pragma unroll
    for (int i = 0; i < 4; ++i)
#pragma unroll
        for (int j = 0; j < 4; ++j) {
            int r = row0 + tr * 4 + i, c = col0 + tc * 4 + j;
            C[(size_t)r * 512 + c] = fmaxf(acc[i][j] + bias[c], 0.f);
        }
}

// ---------------- proj (unchanged) ----------------
__global__ __launch_bounds__(256) void proj_kernel(const float* __restrict__ h,
                                                   const float* __restrict__ winr,
                                                   const float* __restrict__ wini,
                                                   float* __restrict__ pr,
                                                   float* __restrict__ pi) {
    int idx = blockIdx.x * 256 + threadIdx.x;
    int u = idx & 127;
    int n0 = (idx >> 7) * 8;
    float ar[8] = {}, ai[8] = {};
    for (int k = 0; k < 512; ++k) {
        float wrv = winr[k * 128 + u], wiv = wini[k * 128 + u];
#pragma unroll
        for (int g = 0; g < 8; ++g) {
            float hv = h[(size_t)(n0 + g) * 512 + k];
            ar[g] = fmaf(hv, wrv, ar[g]);
            ai[g] = fmaf(hv, wiv, ai[g]);
        }
    }
#pragma unroll
    for (int g = 0; g < 8; ++g) {
        pr[(size_t)(n0 + g) * 128 + u] = ar[g];
        pi[(size_t)(n0 + g) * 128 + u] = ai[g];
    }
}

// ---------------- RNN scan v2: reg-resident wrecT, linear done-fold, 3 barriers/step ----------------
__global__ __launch_bounds__(512) void scan_kernel(const float* __restrict__ done,
                                                   const float* __restrict__ sr0,
                                                   const float* __restrict__ si0,
                                                   const float* __restrict__ wrtR,
                                                   const float* __restrict__ wrtI,
                                                   const float* __restrict__ pr,
                                                   const float* __restrict__ pi,
                                                   float* __restrict__ hsr,
                                                   float* __restrict__ hsi) {
    int b = blockIdx.x;
    int tid = threadIdx.x;
    int u = tid & 127;
    int s = tid >> 7;                 // k-split 0..3 (32 k each)
    int w = tid >> 6;                 // wave id 0..7

    // weights in registers: 8 float4 pairs (contiguous k thanks to transpose)
    const float4* wr4 = reinterpret_cast<const float4*>(wrtR + u * 128 + s * 32);
    const float4* wi4 = reinterpret_cast<const float4*>(wrtI + u * 128 + s * 32);
    float4 WR[8], WI[8];
#pragma unroll
    for (int q = 0; q < 8; ++q) { WR[q] = wr4[q]; WI[q] = wi4[q]; }

    __shared__ __align__(16) float stR[128], stI[128];
    __shared__ float parR[4][128], parI[4][128];
    __shared__ float redw[8];

    // prologue: state init + wrec column sums (for the done-blend linear fold)
    if (s == 0) { stR[u] = sr0[b * 128 + u]; stI[u] = si0[b * 128 + u]; }
    float cr = 0.f, ci = 0.f;
#pragma unroll
    for (int q = 0; q < 8; ++q) {
        cr += WR[q].x + WR[q].y + WR[q].z + WR[q].w;
        ci += WI[q].x + WI[q].y + WI[q].z + WI[q].w;
    }
    parR[s][u] = cr; parI[s][u] = ci;
    __syncthreads();
    float SWr = parR[0][u] + parR[1][u] + parR[2][u] + parR[3][u];
    float SWi = parI[0][u] + parI[1][u] + parI[2][u] + parI[3][u];
    __syncthreads();

    for (int t = 0; t < T_STEPS; ++t) {
        int np = (t * BATCH + b) * 128 + u;
        float prr = pr[np];
        float pri = pi[np];
        float d = done[t * BATCH + b];
        float r = 1.f - d;

        // matvec partial on RAW state (blend folded in linearly afterwards)
        const float4* sR4 = reinterpret_cast<const float4*>(&stR[s * 32]);
        const float4* sI4 = reinterpret_cast<const float4*>(&stI[s * 32]);
        float ar0 = 0.f, ar1 = 0.f, ai0 = 0.f, ai1 = 0.f;
#pragma unroll
        for (int q = 0; q < 8; ++q) {
            float4 sr = sR4[q], si = sI4[q];
            float4 wrv = WR[q], wiv = WI[q];
            if (q & 1) {
                ar1 = fmaf(sr.x, wrv.x, ar1); ar1 = fmaf(-si.x, wiv.x, ar1);
                ai1 = fmaf(sr.x, wiv.x, ai1); ai1 = fmaf(si.x, wrv.x, ai1);
                ar1 = fmaf(sr.y, wrv.y, ar1); ar1 = fmaf(-si.y, wiv.y, ar1);
                ai1 = fmaf(sr.y, wiv.y, ai1); ai1 = fmaf(si.y, wrv.y, ai1);
                ar1 = fmaf(sr.z, wrv.z, ar1); ar1 = fmaf(-si.z, wiv.z, ar1);
                ai1 = fmaf(sr.z, wiv.z, ai1); ai1 = fmaf(si.z, wrv.z, ai1);
                ar1 = fmaf(sr.w, wrv.w, ar1); ar1 = fmaf(-si.w, wiv.w, ar1);
                ai1 = fmaf(sr.w, wiv.w, ai1); ai1 = fmaf(si.w, wrv.w, ai1);
            } else {
                ar0 = fmaf(sr.x, wrv.x, ar0); ar0 = fmaf(-si.x, wiv.x, ar0);
                ai0 = fmaf(sr.x, wiv.x, ai0); ai0 = fmaf(si.x, wrv.x, ai0);
                ar0 = fmaf(sr.y, wrv.y, ar0); ar0 = fmaf(-si.y, wiv.y, ar0);
                ai0 = fmaf(sr.y, wiv.y, ai0); ai0 = fmaf(si.y, wrv.y, ai0);
                ar0 = fmaf(sr.z, wrv.z, ar0); ar0 = fmaf(-si.z, wiv.z, ar0);
                ai0 = fmaf(sr.z, wiv.z, ai0); ai0 = fmaf(si.z, wrv.z, ai0);
                ar0 = fmaf(sr.w, wrv.w, ar0); ar0 = fmaf(-si.w, wiv.w, ar0);
                ai0 = fmaf(sr.w, wiv.w, ai0); ai0 = fmaf(si.w, wrv.w, ai0);
            }
        }
        parR[s][u] = ar0 + ar1;
        parI[s][u] = ai0 + ai1;
        __syncthreads();                                 // bar 1

        float tr_ = (parR[0][u] + parR[1][u]) + (parR[2][u] + parR[3][u]);
        float ti_ = (parI[0][u] + parI[1][u]) + (parI[2][u] + parI[3][u]);
        float pre_r = fmaf(r, tr_, fmaf(d, SWr, prr));
        float pre_i = fmaf(r, ti_, fmaf(d, SWi, pri));
        float sq = fmaf(pre_r, pre_r, pre_i * pre_i);
#pragma unroll
        for (int off = 32; off; off >>= 1) sq += __shfl_xor(sq, off);
        if ((tid & 63) == 0) redw[w] = sq;
        __syncthreads();                                 // bar 2

        float norm = redw[s * 2] + redw[s * 2 + 1];
        float scale = NORM_SCALE / sqrtf(norm);
        float nr = pre_r * scale, ni = pre_i * scale;
        if (s == 0) {                                    // waves 0,1 (uniform per wave)
            stR[u] = nr; stI[u] = ni;
            hsr[np] = nr; hsi[np] = ni;
        }
        __syncthreads();                                 // bar 3
    }
}

// ---------------- heads (unchanged) ----------------
__global__ void heads_kernel(const float* __restrict__ hsr, const float* __restrict__ hsi,
                             const float* __restrict__ aw, const float* __restrict__ ab,
                             const float* __restrict__ cw, const float* __restrict__ cb,
                             float* __restrict__ out) {
    int idx = blockIdx.x * 256 + threadIdx.x;
    if (idx >= N_FRAMES * 7) return;
    int j = idx % 7;
    int n = idx / 7;
    float acc;
    if (j < 6) {
        acc = ab[j];
        for (int k = 0; k < 128; ++k) acc = fmaf(hsr[n * 128 + k], aw[k * 6 + j], acc);
        for (int k = 0; k < 128; ++k) acc = fmaf(hsi[n * 128 + k], aw[(128 + k) * 6 + j], acc);
    } else {
        acc = cb[0];
        for (int k = 0; k < 128; ++k) acc = fmaf(hsr[n * 128 + k], cw[k], acc);
        for (int k = 0; k < 128; ++k) acc = fmaf(hsi[n * 128 + k], cw[128 + k], acc);
    }
    out[idx] = acc;
}

// ---------------- launch ----------------
extern "C" void kernel_launch(void* const* d_in, const int* in_sizes, int n_in,
                              void* d_out, int out_size, void* d_ws, size_t ws_size,
                              hipStream_t stream) {
    const float* x        = (const float*)d_in[0];
    const float* done     = (const float*)d_in[1];
    const float* sr0      = (const float*)d_in[2];
    const float* si0      = (const float*)d_in[3];
    const float* conv1_w  = (const float*)d_in[4];
    const float* conv1_b  = (const float*)d_in[5];
    const float* conv2_w  = (const float*)d_in[6];
    const float* conv2_b  = (const float*)d_in[7];
    const float* conv3_w  = (const float*)d_in[8];
    const float* conv3_b  = (const float*)d_in[9];
    const float* fc_w     = (const float*)d_in[10];
    const float* fc_b     = (const float*)d_in[11];
    const float* win_r    = (const float*)d_in[12];
    const float* win_i    = (const float*)d_in[13];
    const float* wrec_r   = (const float*)d_in[14];
    const float* wrec_i   = (const float*)d_in[15];
    const float* actor_w  = (const float*)d_in[16];
    const float* actor_b  = (const float*)d_in[17];
    const float* critic_w = (const float*)d_in[18];
    const float* critic_b = (const float*)d_in[19];

    float* ws = (float*)d_ws;
    unsigned short* w1mf = (unsigned short*)(ws + OFF_W1P);
    float* w2p  = ws + OFF_W2P;
    float* w3p  = ws + OFF_W3P;
    float* fcwp = ws + OFF_FCWP;
    float* hsr  = ws + OFF_HSR;
    float* hsi  = ws + OFF_HSI;
    float* prj  = ws + OFF_PROJR;
    float* pij  = ws + OFF_PROJI;
    float* h    = ws + OFF_H;
    float* y2   = ws + OFF_Y2;
    float* wrtR = ws + OFF_WRTR;
    float* wrtI = ws + OFF_WRTI;
    float* y1   = ws + OFF_Y1;
    float* y3   = ws + OFF_Y3;
    float* outp = (float*)d_out;

    hipLaunchKernelGGL(permute_w1mf, dim3(32), dim3(256), 0, stream, conv1_w, w1mf);
    hipLaunchKernelGGL(permute_w2, dim3(128), dim3(256), 0, stream, conv2_w, w2p);
    hipLaunchKernelGGL(permute_w3, dim3(144), dim3(256), 0, stream, conv3_w, w3p);
    hipLaunchKernelGGL(permute_fcw, dim3(6272), dim3(256), 0, stream, fc_w, fcwp);

    hipLaunchKernelGGL(conv1_kernel, dim3(4096), dim3(256), 0, stream, x, w1mf, conv1_b, y1);
    hipLaunchKernelGGL(conv2_kernel, dim3(2048), dim3(256), 0, stream, y1, w2p, conv2_b, y2);
    hipLaunchKernelGGL(conv3_kernel, dim3(2048), dim3(256), 0, stream, y2, w3p, conv3_b, y3);
    // y2 is consumed; its space now holds the transposed recurrent weights
    hipLaunchKernelGGL(permute_wrt, dim3(64), dim3(256), 0, stream, wrec_r, wrec_i, wrtR, wrtI);
    hipLaunchKernelGGL(fc_kernel, dim3(256), dim3(256), 0, stream, y3, fcwp, fc_b, h);
    hipLaunchKernelGGL(proj_kernel, dim3(128), dim3(256), 0, stream, h, win_r, win_i, prj, pij);
    hipLaunchKernelGGL(scan_kernel, dim3(16), dim3(512), 0, stream,
                       done, sr0, si0, wrtR, wrtI, prj, pij, hsr, hsi);
    hipLaunchKernelGGL(heads_kernel, dim3(56), dim3(256), 0, stream,
                       hsr, hsi, actor_w, actor_b, critic_w, critic_b, outp);
}

// Round 9
// 696.033 us; speedup vs baseline: 2.8097x; 1.2192x over previous
//
#include <hip/hip_runtime.h>
#include <hip/hip_bf16.h>

// ---------------- problem constants ----------------
#define N_FRAMES 2048          // T*B
#define T_STEPS  128
#define BATCH    16
#define UNITS    128
#define NORM_SCALE 11.313708498984760390f  // sqrt(128)

typedef short bf16x8 __attribute__((ext_vector_type(8)));
typedef float f32x4 __attribute__((ext_vector_type(4)));

static __device__ inline unsigned short f2bf(float f) {
    __hip_bfloat16 h = __float2bfloat16(f);
    return __builtin_bit_cast(unsigned short, h);
}

// ---------------- workspace layout (float elements) ----------------
static const size_t OFF_W1P   = 0;            // 16KB as ushort: conv1 MFMA weights [ky][nt][lane][8]
static const size_t OFF_W2P   = 6144;         // 32768  : conv2 w [kk][ic][oc]
static const size_t OFF_W3P   = 38912;        // 36864  : conv3 w [kk][ic][oc]
static const size_t OFF_FCWP  = 75776;        // as ushort: fc MFMA B-frags [100][32][64][8] = 1.6M ush (3.2MB)
static const size_t OFF_HSR   = 1681408;      // 262144
static const size_t OFF_HSI   = 1943552;      // 262144
static const size_t OFF_PROJR = 2205696;      // 262144
static const size_t OFF_PROJI = 2467840;      // 262144
static const size_t OFF_H     = 2729984;      // 1048576 : fc output [2048][512] f32
static const size_t OFF_Y2    = 3778560;      // 10616832: [2048][9][9][64]
static const size_t OFF_WRTR  = OFF_Y2;       // 16384 : wrec_r transposed (after conv3 consumed y2)
static const size_t OFF_WRTI  = OFF_Y2 + 16384; // 16384 : wrec_i transposed
static const size_t OFF_Y1    = 14395392;     // 26214400: [2048][20][20][32]
static const size_t OFF_Y3    = OFF_Y1;       // as ushort: y3 bf16 [2048][3136] (reuses y1 after conv2)

// ---------------- weight permutes ----------------
__global__ void permute_w1mf(const float* __restrict__ w, unsigned short* __restrict__ o) {
    int i = blockIdx.x * 256 + threadIdx.x;      // 8192 = 8ky * 2nt * 64lane * 8j
    if (i >= 8192) return;
    int j = i & 7; int lane = (i >> 3) & 63; int nt = (i >> 9) & 1; int ky = i >> 10;
    int t = (lane >> 4) * 8 + j;
    int oc = nt * 16 + (lane & 15);
    float v = 0.f;
    if (t < 24) {
        int kx = t / 3, ic = t % 3;
        v = w[((oc * 3 + ic) * 8 + ky) * 8 + kx] * (1.0f / 255.0f);
    }
    o[i] = f2bf(v);
}
__global__ void permute_w2(const float* __restrict__ w, float* __restrict__ o) {
    int i = blockIdx.x * 256 + threadIdx.x;      // 32768
    if (i >= 64 * 32 * 16) return;
    int oc = i & 63; int r = i >> 6; int ic = r & 31; int kk = r >> 5;
    int kx = kk & 3, ky = kk >> 2;
    o[i] = w[((oc * 32 + ic) * 4 + ky) * 4 + kx];
}
__global__ void permute_w3(const float* __restrict__ w, float* __restrict__ o) {
    int i = blockIdx.x * 256 + threadIdx.x;      // 36864
    if (i >= 64 * 64 * 9) return;
    int oc = i & 63; int r = i >> 6; int ic = r & 63; int kk = r >> 6;
    int kx = kk % 3, ky = kk / 3;
    o[i] = w[((oc * 64 + ic) * 3 + ky) * 3 + kx];
}
// fc MFMA B-frag table: o[(kk*32+ntg)*512 + lane*8 + jj] = fcw[k' = kk*32+(lane>>4)*8+jj][n = ntg*16+(lane&15)]
// where k' = p*64+c maps to fc_w[(c*49+p)*512 + n]; k' >= 3136 -> 0 (K padding).
__global__ void permute_fcwmf(const float* __restrict__ w, unsigned short* __restrict__ o) {
    int i = blockIdx.x * 256 + threadIdx.x;      // 100*32*64*8 = 1638400
    if (i >= 1638400) return;
    int jj = i & 7; int lane = (i >> 3) & 63; int ntg = (i >> 9) & 31; int kk = i >> 14;
    int k = kk * 32 + (lane >> 4) * 8 + jj;
    int n = ntg * 16 + (lane & 15);
    float v = 0.f;
    if (k < 3136) {
        int p = k >> 6, c = k & 63;
        v = w[(size_t)(c * 49 + p) * 512 + n];
    }
    o[i] = f2bf(v);
}
__global__ void permute_wrt(const float* __restrict__ wr, const float* __restrict__ wi,
                            float* __restrict__ otr, float* __restrict__ oti) {
    int i = blockIdx.x * 256 + threadIdx.x;      // 16384
    if (i >= 16384) return;
    int k = i & 127, u = i >> 7;
    otr[i] = wr[k * 128 + u];
    oti[i] = wi[k * 128 + u];
}

#define FMA16(xv)                                              \
    acc[j][0] = fmaf(xv.x, wv[0].x, acc[j][0]);                \
    acc[j][1] = fmaf(xv.x, wv[0].y, acc[j][1]);                \
    acc[j][2] = fmaf(xv.x, wv[0].z, acc[j][2]);                \
    acc[j][3] = fmaf(xv.x, wv[0].w, acc[j][3]);                \
    acc[j][0] = fmaf(xv.y, wv[1].x, acc[j][0]);                \
    acc[j][1] = fmaf(xv.y, wv[1].y, acc[j][1]);                \
    acc[j][2] = fmaf(xv.y, wv[1].z, acc[j][2]);                \
    acc[j][3] = fmaf(xv.y, wv[1].w, acc[j][3]);                \
    acc[j][0] = fmaf(xv.z, wv[2].x, acc[j][0]);                \
    acc[j][1] = fmaf(xv.z, wv[2].y, acc[j][1]);                \
    acc[j][2] = fmaf(xv.z, wv[2].z, acc[j][2]);                \
    acc[j][3] = fmaf(xv.z, wv[2].w, acc[j][3]);                \
    acc[j][0] = fmaf(xv.w, wv[3].x, acc[j][0]);                \
    acc[j][1] = fmaf(xv.w, wv[3].y, acc[j][1]);                \
    acc[j][2] = fmaf(xv.w, wv[3].z, acc[j][2]);                \
    acc[j][3] = fmaf(xv.w, wv[3].w, acc[j][3]);

// ---------------- conv1 v5: MFMA implicit GEMM (unchanged) ----------------
__global__ __launch_bounds__(256) void conv1_kernel(const float* __restrict__ x,
                                                    const unsigned short* __restrict__ wmf,
                                                    const float* __restrict__ b,
                                                    float* __restrict__ y) {
    __shared__ unsigned short xs[11096];
    int tid = threadIdx.x;
    int blk = blockIdx.x;
    int n = blk >> 1, hb = blk & 1;

    const float4* xb4 = reinterpret_cast<const float4*>(x + (size_t)n * 21168 + hb * 40 * 252);
#pragma unroll
    for (int it = 0; it < 11; ++it) {
        int i = it * 256 + tid;
        if (i < 2772) {
            float4 v = xb4[i];
            ushort4 h;
            h.x = f2bf(v.x); h.y = f2bf(v.y); h.z = f2bf(v.z); h.w = f2bf(v.w);
            *reinterpret_cast<ushort4*>(&xs[i * 4]) = h;
        }
    }
    if (tid < 8) xs[11088 + tid] = 0;
    __syncthreads();

    int lane = tid & 63;
    int wv = tid >> 6;
    int row = lane & 15;
    int seg = lane >> 4;
    const uint4* wm = reinterpret_cast<const uint4*>(wmf);
    float b0 = b[row];
    float b1 = b[16 + row];
    int pbase = n * 400 + hb * 200;

    for (int tile = wv; tile < 13; tile += 4) {
        int p = tile * 16 + row; if (p > 199) p = 199;
        int eb = (p / 20) * 1008 + (p % 20) * 12 + seg * 8;
        f32x4 acc0 = {0.f, 0.f, 0.f, 0.f};
        f32x4 acc1 = {0.f, 0.f, 0.f, 0.f};
#pragma unroll
        for (int ky = 0; ky < 8; ++ky) {
            int ea = eb + ky * 252;
            ushort4 lo = *reinterpret_cast<const ushort4*>(&xs[ea]);
            ushort4 hi = *reinterpret_cast<const ushort4*>(&xs[ea + 4]);
            bf16x8 a = {(short)lo.x, (short)lo.y, (short)lo.z, (short)lo.w,
                        (short)hi.x, (short)hi.y, (short)hi.z, (short)hi.w};
            bf16x8 w0 = __builtin_bit_cast(bf16x8, wm[(ky * 2 + 0) * 64 + lane]);
            bf16x8 w1 = __builtin_bit_cast(bf16x8, wm[(ky * 2 + 1) * 64 + lane]);
            acc0 = __builtin_amdgcn_mfma_f32_16x16x32_bf16(a, w0, acc0, 0, 0, 0);
            acc1 = __builtin_amdgcn_mfma_f32_16x16x32_bf16(a, w1, acc1, 0, 0, 0);
        }
#pragma unroll
        for (int r = 0; r < 4; ++r) {
            int pl = tile * 16 + seg * 4 + r;
            if (pl < 200) {
                float* yp = y + ((size_t)(pbase + pl)) * 32 + row;
                yp[0]  = fmaxf(acc0[r] + b0, 0.f);
                yp[16] = fmaxf(acc1[r] + b1, 0.f);
            }
        }
    }
}

// ---------------- conv2 v3 (unchanged) ----------------
__global__ __launch_bounds__(256, 3) void conv2_kernel(const float* __restrict__ y1,
                                                       const float* __restrict__ w,
                                                       const float* __restrict__ b,
                                                       float* __restrict__ y2) {
    __shared__ float xs[12800];
    int tid = threadIdx.x;
    int n = blockIdx.x;
    const float4* xg = reinterpret_cast<const float4*>(y1 + (size_t)n * 12800);
#pragma unroll
    for (int q = 0; q < 13; ++q) {
        int i = q * 256 + tid;
        if (i < 3200) {
            int px = i >> 3, qq = i & 7;
            float4 v = xg[i];
            *reinterpret_cast<float4*>(&xs[px * 32 + ((qq * 4) ^ ((px & 3) << 3))]) = v;
        }
    }
    __syncthreads();

    int ocg = tid & 15;
    int pg = tid >> 4;
    int ibase[6];
    bool valid[6];
#pragma unroll
    for (int j = 0; j < 6; ++j) {
        int p = pg + 16 * j;
        valid[j] = p < 81;
        int pp = valid[j] ? p : 0;
        ibase[j] = (pp / 9) * 40 + (pp % 9) * 2;
    }
    const float4* wg4 = reinterpret_cast<const float4*>(w);
    float acc[6][4] = {};
#pragma unroll 1
    for (int kk = 0; kk < 16; ++kk) {
        int ky = kk >> 2, kx = kk & 3;
        int koff = ky * 20 + kx;
        int ib[6], sz[6];
#pragma unroll
        for (int j = 0; j < 6; ++j) {
            int ipx = ibase[j] + koff;
            ib[j] = ipx * 32;
            sz[j] = (ipx & 3) << 3;
        }
        const float4* wkk = wg4 + kk * 512 + ocg;
#pragma unroll 2
        for (int icv = 0; icv < 8; ++icv) {
            float4 wv[4];
#pragma unroll
            for (int i = 0; i < 4; ++i) wv[i] = wkk[(icv * 4 + i) * 16];
#pragma unroll
            for (int j = 0; j < 6; ++j) {
                float4 xv = *reinterpret_cast<const float4*>(&xs[ib[j] + ((icv * 4) ^ sz[j])]);
                FMA16(xv)
            }
        }
    }
    float4 bv = reinterpret_cast<const float4*>(b)[ocg];
#pragma unroll
    for (int j = 0; j < 6; ++j) {
        if (valid[j]) {
            int p = pg + 16 * j;
            float4 o;
            o.x = fmaxf(acc[j][0] + bv.x, 0.f);
            o.y = fmaxf(acc[j][1] + bv.y, 0.f);
            o.z = fmaxf(acc[j][2] + bv.z, 0.f);
            o.w = fmaxf(acc[j][3] + bv.w, 0.f);
            *reinterpret_cast<float4*>(&y2[((size_t)n * 81 + p) * 64 + ocg * 4]) = o;
        }
    }
}

// ---------------- conv3 v4: writes y3 as bf16 (fc consumes via MFMA) ----------------
__global__ __launch_bounds__(256, 4) void conv3_kernel(const float* __restrict__ y2,
                                                       const float* __restrict__ w,
                                                       const float* __restrict__ b,
                                                       unsigned short* __restrict__ y3) {
    __shared__ float xs[5184];
    int tid = threadIdx.x;
    int n = blockIdx.x;
    const float4* xg = reinterpret_cast<const float4*>(y2 + (size_t)n * 5184);
#pragma unroll
    for (int q = 0; q < 6; ++q) {
        int i = q * 256 + tid;
        if (i < 1296) {
            int px = i >> 4, qq = i & 15;
            float4 v = xg[i];
            *reinterpret_cast<float4*>(&xs[px * 64 + ((qq * 4) ^ ((px & 7) << 3))]) = v;
        }
    }
    __syncthreads();

    int ocg = tid & 15;
    int pg = tid >> 4;
    int ibase[4];
    bool valid[4];
#pragma unroll
    for (int j = 0; j < 4; ++j) {
        int p = pg + 16 * j;
        valid[j] = p < 49;
        int pp = valid[j] ? p : 0;
        ibase[j] = (pp / 7) * 9 + (pp % 7);
    }
    const float4* wg4 = reinterpret_cast<const float4*>(w);
    float acc[4][4] = {};
#pragma unroll 1
    for (int kk = 0; kk < 9; ++kk) {
        int ky = kk / 3, kx = kk % 3;
        int koff = ky * 9 + kx;
        int ib[4], sz[4];
#pragma unroll
        for (int j = 0; j < 4; ++j) {
            int ipx = ibase[j] + koff;
            ib[j] = ipx * 64;
            sz[j] = (ipx & 7) << 3;
        }
        const float4* wkk = wg4 + kk * 1024 + ocg;
#pragma unroll 2
        for (int icv = 0; icv < 16; ++icv) {
            float4 wv[4];
#pragma unroll
            for (int i = 0; i < 4; ++i) wv[i] = wkk[(icv * 4 + i) * 16];
#pragma unroll
            for (int j = 0; j < 4; ++j) {
                float4 xv = *reinterpret_cast<const float4*>(&xs[ib[j] + ((icv * 4) ^ sz[j])]);
                FMA16(xv)
            }
        }
    }
    float4 bv = reinterpret_cast<const float4*>(b)[ocg];
#pragma unroll
    for (int j = 0; j < 4; ++j) {
        if (valid[j]) {
            int p = pg + 16 * j;
            ushort4 o;
            o.x = f2bf(fmaxf(acc[j][0] + bv.x, 0.f));
            o.y = f2bf(fmaxf(acc[j][1] + bv.y, 0.f));
            o.z = f2bf(fmaxf(acc[j][2] + bv.z, 0.f));
            o.w = f2bf(fmaxf(acc[j][3] + bv.w, 0.f));
            *reinterpret_cast<ushort4*>(&y3[(size_t)n * 3136 + p * 64 + ocg * 4]) = o;
        }
    }
}

// ---------------- FC v2: bf16 MFMA, K-split across 4 waves ----------------
// grid: 32 M-tiles(64) x 8 N-tiles(64) = 256 blocks. Wave w handles kk = w, w+4, ... (<100).
// A-frags from global y3 bf16 (L2); B-frags from pre-permuted table (L2). No LDS in main loop.
__global__ __launch_bounds__(256) void fc_kernel(const unsigned short* __restrict__ A,
                                                 const unsigned short* __restrict__ Bt,
                                                 const float* __restrict__ bias,
                                                 float* __restrict__ C) {
    __shared__ float Cs[64][65];
    int tid = threadIdx.x;
    int lane = tid & 63;
    int wv = tid >> 6;
    int bm = blockIdx.x & 31;
    int bn = blockIdx.x >> 5;
    int row = lane & 15, seg = lane >> 4;

    const uint4* B4 = reinterpret_cast<const uint4*>(Bt);
    f32x4 acc[4][4];
#pragma unroll
    for (int mf = 0; mf < 4; ++mf)
#pragma unroll
        for (int nf = 0; nf < 4; ++nf) acc[mf][nf] = (f32x4){0.f, 0.f, 0.f, 0.f};

    const unsigned short* Abase = A + (size_t)(bm * 64 + row) * 3136 + seg * 8;

#pragma unroll 1
    for (int kk = wv; kk < 100; kk += 4) {
        bf16x8 a[4], bb[4];
#pragma unroll
        for (int mf = 0; mf < 4; ++mf)
            a[mf] = __builtin_bit_cast(bf16x8,
                *reinterpret_cast<const uint4*>(Abase + (size_t)mf * 16 * 3136 + kk * 32));
#pragma unroll
        for (int nf = 0; nf < 4; ++nf)
            bb[nf] = __builtin_bit_cast(bf16x8, B4[(kk * 32 + bn * 4 + nf) * 64 + lane]);
#pragma unroll
        for (int mf = 0; mf < 4; ++mf)
#pragma unroll
            for (int nf = 0; nf < 4; ++nf)
                acc[mf][nf] = __builtin_amdgcn_mfma_f32_16x16x32_bf16(a[mf], bb[nf], acc[mf][nf], 0, 0, 0);
    }

    // serialized K-split reduction into LDS
#pragma unroll 1
    for (int w = 0; w < 4; ++w) {
        if (wv == w) {
#pragma unroll
            for (int mf = 0; mf < 4; ++mf)
#pragma unroll
                for (int nf = 0; nf < 4; ++nf)
#pragma unroll
                    for (int r = 0; r < 4; ++r) {
                        int rr = mf * 16 + seg * 4 + r;
                        int cc = nf * 16 + row;
                        if (w == 0) Cs[rr][cc] = acc[mf][nf][r];
                        else        Cs[rr][cc] += acc[mf][nf][r];
                    }
        }
        __syncthreads();
    }

    // bias + relu + store (f32 h)
    int r = tid >> 2, cq = (tid & 3) * 16;
#pragma unroll
    for (int q = 0; q < 4; ++q) {
        int c0 = cq + q * 4;
        float4 v = *reinterpret_cast<float4*>(&Cs[r][c0]);
        float4 bv = *reinterpret_cast<const float4*>(&bias[bn * 64 + c0]);
        v.x = fmaxf(v.x + bv.x, 0.f);
        v.y = fmaxf(v.y + bv.y, 0.f);
        v.z = fmaxf(v.z + bv.z, 0.f);
        v.w = fmaxf(v.w + bv.w, 0.f);
        *reinterpret_cast<float4*>(&C[(size_t)(bm * 64 + r) * 512 + bn * 64 + c0]) = v;
    }
}

// ---------------- proj (unchanged) ----------------
__global__ __launch_bounds__(256) void proj_kernel(const float* __restrict__ h,
                                                   const float* __restrict__ winr,
                                                   const float* __restrict__ wini,
                                                   float* __restrict__ pr,
                                                   float* __restrict__ pi) {
    int idx = blockIdx.x * 256 + threadIdx.x;
    int u = idx & 127;
    int n0 = (idx >> 7) * 8;
    float ar[8] = {}, ai[8] = {};
    for (int k = 0; k < 512; ++k) {
        float wrv = winr[k * 128 + u], wiv = wini[k * 128 + u];
#pragma unroll
        for (int g = 0; g < 8; ++g) {
            float hv = h[(size_t)(n0 + g) * 512 + k];
            ar[g] = fmaf(hv, wrv, ar[g]);
            ai[g] = fmaf(hv, wiv, ai[g]);
        }
    }
#pragma unroll
    for (int g = 0; g < 8; ++g) {
        pr[(size_t)(n0 + g) * 128 + u] = ar[g];
        pi[(size_t)(n0 + g) * 128 + u] = ai[g];
    }
}

// ---------------- RNN scan v2 (unchanged) ----------------
__global__ __launch_bounds__(512) void scan_kernel(const float* __restrict__ done,
                                                   const float* __restrict__ sr0,
                                                   const float* __restrict__ si0,
                                                   const float* __restrict__ wrtR,
                                                   const float* __restrict__ wrtI,
                                                   const float* __restrict__ pr,
                                                   const float* __restrict__ pi,
                                                   float* __restrict__ hsr,
                                                   float* __restrict__ hsi) {
    int b = blockIdx.x;
    int tid = threadIdx.x;
    int u = tid & 127;
    int s = tid >> 7;
    int w = tid >> 6;

    const float4* wr4 = reinterpret_cast<const float4*>(wrtR + u * 128 + s * 32);
    const float4* wi4 = reinterpret_cast<const float4*>(wrtI + u * 128 + s * 32);
    float4 WR[8], WI[8];
#pragma unroll
    for (int q = 0; q < 8; ++q) { WR[q] = wr4[q]; WI[q] = wi4[q]; }

    __shared__ __align__(16) float stR[128], stI[128];
    __shared__ float parR[4][128], parI[4][128];
    __shared__ float redw[8];

    if (s == 0) { stR[u] = sr0[b * 128 + u]; stI[u] = si0[b * 128 + u]; }
    float cr = 0.f, ci = 0.f;
#pragma unroll
    for (int q = 0; q < 8; ++q) {
        cr += WR[q].x + WR[q].y + WR[q].z + WR[q].w;
        ci += WI[q].x + WI[q].y + WI[q].z + WI[q].w;
    }
    parR[s][u] = cr; parI[s][u] = ci;
    __syncthreads();
    float SWr = parR[0][u] + parR[1][u] + parR[2][u] + parR[3][u];
    float SWi = parI[0][u] + parI[1][u] + parI[2][u] + parI[3][u];
    __syncthreads();

    for (int t = 0; t < T_STEPS; ++t) {
        int np = (t * BATCH + b) * 128 + u;
        float prr = pr[np];
        float pri = pi[np];
        float d = done[t * BATCH + b];
        float r = 1.f - d;

        const float4* sR4 = reinterpret_cast<const float4*>(&stR[s * 32]);
        const float4* sI4 = reinterpret_cast<const float4*>(&stI[s * 32]);
        float ar0 = 0.f, ar1 = 0.f, ai0 = 0.f, ai1 = 0.f;
#pragma unroll
        for (int q = 0; q < 8; ++q) {
            float4 sr = sR4[q], si = sI4[q];
            float4 wrv = WR[q], wiv = WI[q];
            if (q & 1) {
                ar1 = fmaf(sr.x, wrv.x, ar1); ar1 = fmaf(-si.x, wiv.x, ar1);
                ai1 = fmaf(sr.x, wiv.x, ai1); ai1 = fmaf(si.x, wrv.x, ai1);
                ar1 = fmaf(sr.y, wrv.y, ar1); ar1 = fmaf(-si.y, wiv.y, ar1);
                ai1 = fmaf(sr.y, wiv.y, ai1); ai1 = fmaf(si.y, wrv.y, ai1);
                ar1 = fmaf(sr.z, wrv.z, ar1); ar1 = fmaf(-si.z, wiv.z, ar1);
                ai1 = fmaf(sr.z, wiv.z, ai1); ai1 = fmaf(si.z, wrv.z, ai1);
                ar1 = fmaf(sr.w, wrv.w, ar1); ar1 = fmaf(-si.w, wiv.w, ar1);
                ai1 = fmaf(sr.w, wiv.w, ai1); ai1 = fmaf(si.w, wrv.w, ai1);
            } else {
                ar0 = fmaf(sr.x, wrv.x, ar0); ar0 = fmaf(-si.x, wiv.x, ar0);
                ai0 = fmaf(sr.x, wiv.x, ai0); ai0 = fmaf(si.x, wrv.x, ai0);
                ar0 = fmaf(sr.y, wrv.y, ar0); ar0 = fmaf(-si.y, wiv.y, ar0);
                ai0 = fmaf(sr.y, wiv.y, ai0); ai0 = fmaf(si.y, wrv.y, ai0);
                ar0 = fmaf(sr.z, wrv.z, ar0); ar0 = fmaf(-si.z, wiv.z, ar0);
                ai0 = fmaf(sr.z, wiv.z, ai0); ai0 = fmaf(si.z, wrv.z, ai0);
                ar0 = fmaf(sr.w, wrv.w, ar0); ar0 = fmaf(-si.w, wiv.w, ar0);
                ai0 = fmaf(sr.w, wiv.w, ai0); ai0 = fmaf(si.w, wrv.w, ai0);
            }
        }
        parR[s][u] = ar0 + ar1;
        parI[s][u] = ai0 + ai1;
        __syncthreads();

        float tr_ = (parR[0][u] + parR[1][u]) + (parR[2][u] + parR[3][u]);
        float ti_ = (parI[0][u] + parI[1][u]) + (parI[2][u] + parI[3][u]);
        float pre_r = fmaf(r, tr_, fmaf(d, SWr, prr));
        float pre_i = fmaf(r, ti_, fmaf(d, SWi, pri));
        float sq = fmaf(pre_r, pre_r, pre_i * pre_i);
#pragma unroll
        for (int off = 32; off; off >>= 1) sq += __shfl_xor(sq, off);
        if ((tid & 63) == 0) redw[w] = sq;
        __syncthreads();

        float norm = redw[s * 2] + redw[s * 2 + 1];
        float scale = NORM_SCALE / sqrtf(norm);
        float nr = pre_r * scale, ni = pre_i * scale;
        if (s == 0) {
            stR[u] = nr; stI[u] = ni;
            hsr[np] = nr; hsi[np] = ni;
        }
        __syncthreads();
    }
}

// ---------------- heads (unchanged) ----------------
__global__ void heads_kernel(const float* __restrict__ hsr, const float* __restrict__ hsi,
                             const float* __restrict__ aw, const float* __restrict__ ab,
                             const float* __restrict__ cw, const float* __restrict__ cb,
                             float* __restrict__ out) {
    int idx = blockIdx.x * 256 + threadIdx.x;
    if (idx >= N_FRAMES * 7) return;
    int j = idx % 7;
    int n = idx / 7;
    float acc;
    if (j < 6) {
        acc = ab[j];
        for (int k = 0; k < 128; ++k) acc = fmaf(hsr[n * 128 + k], aw[k * 6 + j], acc);
        for (int k = 0; k < 128; ++k) acc = fmaf(hsi[n * 128 + k], aw[(128 + k) * 6 + j], acc);
    } else {
        acc = cb[0];
        for (int k = 0; k < 128; ++k) acc = fmaf(hsr[n * 128 + k], cw[k], acc);
        for (int k = 0; k < 128; ++k) acc = fmaf(hsi[n * 128 + k], cw[128 + k], acc);
    }
    out[idx] = acc;
}

// ---------------- launch ----------------
extern "C" void kernel_launch(void* const* d_in, const int* in_sizes, int n_in,
                              void* d_out, int out_size, void* d_ws, size_t ws_size,
                              hipStream_t stream) {
    const float* x        = (const float*)d_in[0];
    const float* done     = (const float*)d_in[1];
    const float* sr0      = (const float*)d_in[2];
    const float* si0      = (const float*)d_in[3];
    const float* conv1_w  = (const float*)d_in[4];
    const float* conv1_b  = (const float*)d_in[5];
    const float* conv2_w  = (const float*)d_in[6];
    const float* conv2_b  = (const float*)d_in[7];
    const float* conv3_w  = (const float*)d_in[8];
    const float* conv3_b  = (const float*)d_in[9];
    const float* fc_w     = (const float*)d_in[10];
    const float* fc_b     = (const float*)d_in[11];
    const float* win_r    = (const float*)d_in[12];
    const float* win_i    = (const float*)d_in[13];
    const float* wrec_r   = (const float*)d_in[14];
    const float* wrec_i   = (const float*)d_in[15];
    const float* actor_w  = (const float*)d_in[16];
    const float* actor_b  = (const float*)d_in[17];
    const float* critic_w = (const float*)d_in[18];
    const float* critic_b = (const float*)d_in[19];

    float* ws = (float*)d_ws;
    unsigned short* w1mf = (unsigned short*)(ws + OFF_W1P);
    float* w2p  = ws + OFF_W2P;
    float* w3p  = ws + OFF_W3P;
    unsigned short* fcb = (unsigned short*)(ws + OFF_FCWP);
    float* hsr  = ws + OFF_HSR;
    float* hsi  = ws + OFF_HSI;
    float* prj  = ws + OFF_PROJR;
    float* pij  = ws + OFF_PROJI;
    float* h    = ws + OFF_H;
    float* y2   = ws + OFF_Y2;
    float* wrtR = ws + OFF_WRTR;
    float* wrtI = ws + OFF_WRTI;
    float* y1   = ws + OFF_Y1;
    unsigned short* y3b = (unsigned short*)(ws + OFF_Y3);
    float* outp = (float*)d_out;

    hipLaunchKernelGGL(permute_w1mf, dim3(32), dim3(256), 0, stream, conv1_w, w1mf);
    hipLaunchKernelGGL(permute_w2, dim3(128), dim3(256), 0, stream, conv2_w, w2p);
    hipLaunchKernelGGL(permute_w3, dim3(144), dim3(256), 0, stream, conv3_w, w3p);
    hipLaunchKernelGGL(permute_fcwmf, dim3(6400), dim3(256), 0, stream, fc_w, fcb);

    hipLaunchKernelGGL(conv1_kernel, dim3(4096), dim3(256), 0, stream, x, w1mf, conv1_b, y1);
    hipLaunchKernelGGL(conv2_kernel, dim3(2048), dim3(256), 0, stream, y1, w2p, conv2_b, y2);
    hipLaunchKernelGGL(conv3_kernel, dim3(2048), dim3(256), 0, stream, y2, w3p, conv3_b, y3b);
    // y2 consumed; its space now holds the transposed recurrent weights
    hipLaunchKernelGGL(permute_wrt, dim3(64), dim3(256), 0, stream, wrec_r, wrec_i, wrtR, wrtI);
    hipLaunchKernelGGL(fc_kernel, dim3(256), dim3(256), 0, stream, y3b, fcb, fc_b, h);
    hipLaunchKernelGGL(proj_kernel, dim3(128), dim3(256), 0, stream, h, win_r, win_i, prj, pij);
    hipLaunchKernelGGL(scan_kernel, dim3(16), dim3(512), 0, stream,
                       done, sr0, si0, wrtR, wrtI, prj, pij, hsr, hsi);
    hipLaunchKernelGGL(heads_kernel, dim3(56), dim3(256), 0, stream,
                       hsr, hsi, actor_w, actor_b, critic_w, critic_b, outp);
}

// Round 10
// 521.402 us; speedup vs baseline: 3.7507x; 1.3349x over previous
//
#include <hip/hip_runtime.h>
#include <hip/hip_bf16.h>

// ---------------- problem constants ----------------
#define N_FRAMES 2048          // T*B
#define T_STEPS  128
#define BATCH    16
#define UNITS    128
#define NORM_SCALE 11.313708498984760390f  // sqrt(128)

typedef short bf16x8 __attribute__((ext_vector_type(8)));
typedef float f32x4 __attribute__((ext_vector_type(4)));

static __device__ inline unsigned short f2bf(float f) {
    __hip_bfloat16 h = __float2bfloat16(f);
    return __builtin_bit_cast(unsigned short, h);
}

// ---------------- workspace layout (float elements) ----------------
static const size_t OFF_W1P   = 0;            // 16KB ush: conv1 MFMA weights [ky][nt][lane][8]
static const size_t OFF_W2P   = 6144;         // 64KB ush: conv2 MFMA B-frags [16][4][64][8]
static const size_t OFF_W3P   = 38912;        // 36864 f32: conv3 w [kk][ic][oc]
static const size_t OFF_FCWP  = 75776;        // ush: fc MFMA B-frags [100][32][64][8]
static const size_t OFF_HSR   = 1681408;      // 262144
static const size_t OFF_HSI   = 1943552;      // 262144
static const size_t OFF_PROJR = 2205696;      // 262144
static const size_t OFF_PROJI = 2467840;      // 262144
static const size_t OFF_H     = 2729984;      // 1048576 : fc output [2048][512] f32
static const size_t OFF_Y2    = 3778560;      // 10616832: [2048][9][9][64] f32
static const size_t OFF_WRTR  = OFF_Y2;       // 16384 : wrec_r transposed (after conv3 consumed y2)
static const size_t OFF_WRTI  = OFF_Y2 + 16384; // 16384 : wrec_i transposed
static const size_t OFF_Y1    = 14395392;     // ush: y1 bf16 [2048][20][20][32]
static const size_t OFF_Y3    = OFF_Y1;       // ush: y3 bf16 [2048][3136] (reuses y1 after conv2)

// ---------------- weight permutes ----------------
__global__ void permute_w1mf(const float* __restrict__ w, unsigned short* __restrict__ o) {
    int i = blockIdx.x * 256 + threadIdx.x;      // 8192
    if (i >= 8192) return;
    int j = i & 7; int lane = (i >> 3) & 63; int nt = (i >> 9) & 1; int ky = i >> 10;
    int t = (lane >> 4) * 8 + j;
    int oc = nt * 16 + (lane & 15);
    float v = 0.f;
    if (t < 24) {
        int kx = t / 3, ic = t % 3;
        v = w[((oc * 3 + ic) * 8 + ky) * 8 + kx] * (1.0f / 255.0f);
    }
    o[i] = f2bf(v);
}
// conv2 MFMA B-frags: o[((kk*4+nt)*64+lane)*8+j] = w2[oc=nt*16+(lane&15)][ic=(lane>>4)*8+j][ky=kk>>2][kx=kk&3]
__global__ void permute_w2mf(const float* __restrict__ w, unsigned short* __restrict__ o) {
    int i = blockIdx.x * 256 + threadIdx.x;      // 32768
    if (i >= 32768) return;
    int j = i & 7; int lane = (i >> 3) & 63; int nt = (i >> 9) & 3; int kk = i >> 11;
    int ic = (lane >> 4) * 8 + j;
    int oc = nt * 16 + (lane & 15);
    int ky = kk >> 2, kx = kk & 3;
    o[i] = f2bf(w[((oc * 32 + ic) * 4 + ky) * 4 + kx]);
}
__global__ void permute_w3(const float* __restrict__ w, float* __restrict__ o) {
    int i = blockIdx.x * 256 + threadIdx.x;      // 36864
    if (i >= 64 * 64 * 9) return;
    int oc = i & 63; int r = i >> 6; int ic = r & 63; int kk = r >> 6;
    int kx = kk % 3, ky = kk / 3;
    o[i] = w[((oc * 64 + ic) * 3 + ky) * 3 + kx];
}
__global__ void permute_fcwmf(const float* __restrict__ w, unsigned short* __restrict__ o) {
    int i = blockIdx.x * 256 + threadIdx.x;      // 1638400
    if (i >= 1638400) return;
    int jj = i & 7; int lane = (i >> 3) & 63; int ntg = (i >> 9) & 31; int kk = i >> 14;
    int k = kk * 32 + (lane >> 4) * 8 + jj;
    int n = ntg * 16 + (lane & 15);
    float v = 0.f;
    if (k < 3136) {
        int p = k >> 6, c = k & 63;
        v = w[(size_t)(c * 49 + p) * 512 + n];
    }
    o[i] = f2bf(v);
}
__global__ void permute_wrt(const float* __restrict__ wr, const float* __restrict__ wi,
                            float* __restrict__ otr, float* __restrict__ oti) {
    int i = blockIdx.x * 256 + threadIdx.x;      // 16384
    if (i >= 16384) return;
    int k = i & 127, u = i >> 7;
    otr[i] = wr[k * 128 + u];
    oti[i] = wi[k * 128 + u];
}

#define FMA16(xv)                                              \
    acc[j][0] = fmaf(xv.x, wv[0].x, acc[j][0]);                \
    acc[j][1] = fmaf(xv.x, wv[0].y, acc[j][1]);                \
    acc[j][2] = fmaf(xv.x, wv[0].z, acc[j][2]);                \
    acc[j][3] = fmaf(xv.x, wv[0].w, acc[j][3]);                \
    acc[j][0] = fmaf(xv.y, wv[1].x, acc[j][0]);                \
    acc[j][1] = fmaf(xv.y, wv[1].y, acc[j][1]);                \
    acc[j][2] = fmaf(xv.y, wv[1].z, acc[j][2]);                \
    acc[j][3] = fmaf(xv.y, wv[1].w, acc[j][3]);                \
    acc[j][0] = fmaf(xv.z, wv[2].x, acc[j][0]);                \
    acc[j][1] = fmaf(xv.z, wv[2].y, acc[j][1]);                \
    acc[j][2] = fmaf(xv.z, wv[2].z, acc[j][2]);                \
    acc[j][3] = fmaf(xv.z, wv[2].w, acc[j][3]);                \
    acc[j][0] = fmaf(xv.w, wv[3].x, acc[j][0]);                \
    acc[j][1] = fmaf(xv.w, wv[3].y, acc[j][1]);                \
    acc[j][2] = fmaf(xv.w, wv[3].z, acc[j][2]);                \
    acc[j][3] = fmaf(xv.w, wv[3].w, acc[j][3]);

// ---------------- conv1 v6: MFMA implicit GEMM, bf16 output ----------------
__global__ __launch_bounds__(256) void conv1_kernel(const float* __restrict__ x,
                                                    const unsigned short* __restrict__ wmf,
                                                    const float* __restrict__ b,
                                                    unsigned short* __restrict__ y) {
    __shared__ unsigned short xs[11096];
    int tid = threadIdx.x;
    int blk = blockIdx.x;
    int n = blk >> 1, hb = blk & 1;

    const float4* xb4 = reinterpret_cast<const float4*>(x + (size_t)n * 21168 + hb * 40 * 252);
#pragma unroll
    for (int it = 0; it < 11; ++it) {
        int i = it * 256 + tid;
        if (i < 2772) {
            float4 v = xb4[i];
            ushort4 h;
            h.x = f2bf(v.x); h.y = f2bf(v.y); h.z = f2bf(v.z); h.w = f2bf(v.w);
            *reinterpret_cast<ushort4*>(&xs[i * 4]) = h;
        }
    }
    if (tid < 8) xs[11088 + tid] = 0;
    __syncthreads();

    int lane = tid & 63;
    int wv = tid >> 6;
    int row = lane & 15;
    int seg = lane >> 4;
    const uint4* wm = reinterpret_cast<const uint4*>(wmf);
    float b0 = b[row];
    float b1 = b[16 + row];
    int pbase = n * 400 + hb * 200;

    for (int tile = wv; tile < 13; tile += 4) {
        int p = tile * 16 + row; if (p > 199) p = 199;
        int eb = (p / 20) * 1008 + (p % 20) * 12 + seg * 8;
        f32x4 acc0 = {0.f, 0.f, 0.f, 0.f};
        f32x4 acc1 = {0.f, 0.f, 0.f, 0.f};
#pragma unroll
        for (int ky = 0; ky < 8; ++ky) {
            int ea = eb + ky * 252;
            ushort4 lo = *reinterpret_cast<const ushort4*>(&xs[ea]);
            ushort4 hi = *reinterpret_cast<const ushort4*>(&xs[ea + 4]);
            bf16x8 a = {(short)lo.x, (short)lo.y, (short)lo.z, (short)lo.w,
                        (short)hi.x, (short)hi.y, (short)hi.z, (short)hi.w};
            bf16x8 w0 = __builtin_bit_cast(bf16x8, wm[(ky * 2 + 0) * 64 + lane]);
            bf16x8 w1 = __builtin_bit_cast(bf16x8, wm[(ky * 2 + 1) * 64 + lane]);
            acc0 = __builtin_amdgcn_mfma_f32_16x16x32_bf16(a, w0, acc0, 0, 0, 0);
            acc1 = __builtin_amdgcn_mfma_f32_16x16x32_bf16(a, w1, acc1, 0, 0, 0);
        }
#pragma unroll
        for (int r = 0; r < 4; ++r) {
            int pl = tile * 16 + seg * 4 + r;
            if (pl < 200) {
                unsigned short* yp = y + ((size_t)(pbase + pl)) * 32 + row;
                yp[0]  = f2bf(fmaxf(acc0[r] + b0, 0.f));
                yp[16] = f2bf(fmaxf(acc1[r] + b1, 0.f));
            }
        }
    }
}

// ---------------- conv2 v4: MFMA implicit GEMM ----------------
// block = 2 images; LDS = 2*12800 bf16 = 51.2 KB, XOR-swizzled 16B units (u ^ ((u>>3)&3) on low-2).
// 4 waves: wave -> (img = wv>>1, tiles (wv&1)*3 .. +2). Per kk: 3 A ds_reads + 4 B global + 12 MFMA.
__global__ __launch_bounds__(256) void conv2_kernel(const unsigned short* __restrict__ y1b,
                                                    const unsigned short* __restrict__ wt,
                                                    const float* __restrict__ b,
                                                    float* __restrict__ y2) {
    __shared__ unsigned short xs[2 * 12800];
    int tid = threadIdx.x;
    int n0 = blockIdx.x * 2;
    const uint4* xg = reinterpret_cast<const uint4*>(y1b + (size_t)n0 * 12800);
    uint4* xs4 = reinterpret_cast<uint4*>(xs);
#pragma unroll
    for (int q = 0; q < 13; ++q) {
        int i = q * 256 + tid;
        if (i < 3200) {
            uint4 v = xg[i];
            int swz = (i & ~3) | ((i & 3) ^ ((i >> 3) & 3));   // 1600%8==0 so img offset preserved
            xs4[swz] = v;
        }
    }
    __syncthreads();

    int lane = tid & 63;
    int wv = tid >> 6;
    int img = wv >> 1;
    int tbase = (wv & 1) * 3;
    int row = lane & 15, seg = lane >> 4;
    int imgb = img * 1600;                      // 16B units

    int ibase[3];
#pragma unroll
    for (int t = 0; t < 3; ++t) {
        int p = (tbase + t) * 16 + row; if (p > 80) p = 80;
        ibase[t] = (p / 9) * 40 + (p % 9) * 2;  // input pixel index (row stride 20)
    }
    const uint4* B4 = reinterpret_cast<const uint4*>(wt);
    f32x4 acc[3][4];
#pragma unroll
    for (int t = 0; t < 3; ++t)
#pragma unroll
        for (int nt = 0; nt < 4; ++nt) acc[t][nt] = (f32x4){0.f, 0.f, 0.f, 0.f};

#pragma unroll 1
    for (int kk = 0; kk < 16; ++kk) {
        int ky = kk >> 2, kx = kk & 3;
        int koff = ky * 20 + kx;
        bf16x8 bb[4];
#pragma unroll
        for (int nt = 0; nt < 4; ++nt)
            bb[nt] = __builtin_bit_cast(bf16x8, B4[(kk * 4 + nt) * 64 + lane]);
        bf16x8 a[3];
#pragma unroll
        for (int t = 0; t < 3; ++t) {
            int ipx = ibase[t] + koff;
            int a16 = imgb + ipx * 4 + (seg ^ ((ipx >> 1) & 3));
            a[t] = __builtin_bit_cast(bf16x8, *reinterpret_cast<const uint4*>(&xs[a16 * 8]));
        }
#pragma unroll
        for (int t = 0; t < 3; ++t)
#pragma unroll
            for (int nt = 0; nt < 4; ++nt)
                acc[t][nt] = __builtin_amdgcn_mfma_f32_16x16x32_bf16(a[t], bb[nt], acc[t][nt], 0, 0, 0);
    }

#pragma unroll
    for (int nt = 0; nt < 4; ++nt) {
        int c = nt * 16 + row;
        float bc = b[c];
#pragma unroll
        for (int t = 0; t < 3; ++t)
#pragma unroll
            for (int r = 0; r < 4; ++r) {
                int p = (tbase + t) * 16 + seg * 4 + r;
                if (p < 81)
                    y2[((size_t)(n0 + img) * 81 + p) * 64 + c] = fmaxf(acc[t][nt][r] + bc, 0.f);
            }
    }
}

// ---------------- conv3 v4: writes y3 as bf16 (unchanged) ----------------
__global__ __launch_bounds__(256, 4) void conv3_kernel(const float* __restrict__ y2,
                                                       const float* __restrict__ w,
                                                       const float* __restrict__ b,
                                                       unsigned short* __restrict__ y3) {
    __shared__ float xs[5184];
    int tid = threadIdx.x;
    int n = blockIdx.x;
    const float4* xg = reinterpret_cast<const float4*>(y2 + (size_t)n * 5184);
#pragma unroll
    for (int q = 0; q < 6; ++q) {
        int i = q * 256 + tid;
        if (i < 1296) {
            int px = i >> 4, qq = i & 15;
            float4 v = xg[i];
            *reinterpret_cast<float4*>(&xs[px * 64 + ((qq * 4) ^ ((px & 7) << 3))]) = v;
        }
    }
    __syncthreads();

    int ocg = tid & 15;
    int pg = tid >> 4;
    int ibase[4];
    bool valid[4];
#pragma unroll
    for (int j = 0; j < 4; ++j) {
        int p = pg + 16 * j;
        valid[j] = p < 49;
        int pp = valid[j] ? p : 0;
        ibase[j] = (pp / 7) * 9 + (pp % 7);
    }
    const float4* wg4 = reinterpret_cast<const float4*>(w);
    float acc[4][4] = {};
#pragma unroll 1
    for (int kk = 0; kk < 9; ++kk) {
        int ky = kk / 3, kx = kk % 3;
        int koff = ky * 9 + kx;
        int ib[4], sz[4];
#pragma unroll
        for (int j = 0; j < 4; ++j) {
            int ipx = ibase[j] + koff;
            ib[j] = ipx * 64;
            sz[j] = (ipx & 7) << 3;
        }
        const float4* wkk = wg4 + kk * 1024 + ocg;
#pragma unroll 2
        for (int icv = 0; icv < 16; ++icv) {
            float4 wv[4];
#pragma unroll
            for (int i = 0; i < 4; ++i) wv[i] = wkk[(icv * 4 + i) * 16];
#pragma unroll
            for (int j = 0; j < 4; ++j) {
                float4 xv = *reinterpret_cast<const float4*>(&xs[ib[j] + ((icv * 4) ^ sz[j])]);
                FMA16(xv)
            }
        }
    }
    float4 bv = reinterpret_cast<const float4*>(b)[ocg];
#pragma unroll
    for (int j = 0; j < 4; ++j) {
        if (valid[j]) {
            int p = pg + 16 * j;
            ushort4 o;
            o.x = f2bf(fmaxf(acc[j][0] + bv.x, 0.f));
            o.y = f2bf(fmaxf(acc[j][1] + bv.y, 0.f));
            o.z = f2bf(fmaxf(acc[j][2] + bv.z, 0.f));
            o.w = f2bf(fmaxf(acc[j][3] + bv.w, 0.f));
            *reinterpret_cast<ushort4*>(&y3[(size_t)n * 3136 + p * 64 + ocg * 4]) = o;
        }
    }
}

// ---------------- FC v2: bf16 MFMA (unchanged) ----------------
__global__ __launch_bounds__(256) void fc_kernel(const unsigned short* __restrict__ A,
                                                 const unsigned short* __restrict__ Bt,
                                                 const float* __restrict__ bias,
                                                 float* __restrict__ C) {
    __shared__ float Cs[64][65];
    int tid = threadIdx.x;
    int lane = tid & 63;
    int wv = tid >> 6;
    int bm = blockIdx.x & 31;
    int bn = blockIdx.x >> 5;
    int row = lane & 15, seg = lane >> 4;

    const uint4* B4 = reinterpret_cast<const uint4*>(Bt);
    f32x4 acc[4][4];
#pragma unroll
    for (int mf = 0; mf < 4; ++mf)
#pragma unroll
        for (int nf = 0; nf < 4; ++nf) acc[mf][nf] = (f32x4){0.f, 0.f, 0.f, 0.f};

    const unsigned short* Abase = A + (size_t)(bm * 64 + row) * 3136 + seg * 8;

#pragma unroll 1
    for (int kk = wv; kk < 100; kk += 4) {
        bf16x8 a[4], bb[4];
#pragma unroll
        for (int mf = 0; mf < 4; ++mf)
            a[mf] = __builtin_bit_cast(bf16x8,
                *reinterpret_cast<const uint4*>(Abase + (size_t)mf * 16 * 3136 + kk * 32));
#pragma unroll
        for (int nf = 0; nf < 4; ++nf)
            bb[nf] = __builtin_bit_cast(bf16x8, B4[(kk * 32 + bn * 4 + nf) * 64 + lane]);
#pragma unroll
        for (int mf = 0; mf < 4; ++mf)
#pragma unroll
            for (int nf = 0; nf < 4; ++nf)
                acc[mf][nf] = __builtin_amdgcn_mfma_f32_16x16x32_bf16(a[mf], bb[nf], acc[mf][nf], 0, 0, 0);
    }

#pragma unroll 1
    for (int w = 0; w < 4; ++w) {
        if (wv == w) {
#pragma unroll
            for (int mf = 0; mf < 4; ++mf)
#pragma unroll
                for (int nf = 0; nf < 4; ++nf)
#pragma unroll
                    for (int r = 0; r < 4; ++r) {
                        int rr = mf * 16 + seg * 4 + r;
                        int cc = nf * 16 + row;
                        if (w == 0) Cs[rr][cc] = acc[mf][nf][r];
                        else        Cs[rr][cc] += acc[mf][nf][r];
                    }
        }
        __syncthreads();
    }

    int r = tid >> 2, cq = (tid & 3) * 16;
#pragma unroll
    for (int q = 0; q < 4; ++q) {
        int c0 = cq + q * 4;
        float4 v = *reinterpret_cast<float4*>(&Cs[r][c0]);
        float4 bv = *reinterpret_cast<const float4*>(&bias[bn * 64 + c0]);
        v.x = fmaxf(v.x + bv.x, 0.f);
        v.y = fmaxf(v.y + bv.y, 0.f);
        v.z = fmaxf(v.z + bv.z, 0.f);
        v.w = fmaxf(v.w + bv.w, 0.f);
        *reinterpret_cast<float4*>(&C[(size_t)(bm * 64 + r) * 512 + bn * 64 + c0]) = v;
    }
}

// ---------------- proj (unchanged) ----------------
__global__ __launch_bounds__(256) void proj_kernel(const float* __restrict__ h,
                                                   const float* __restrict__ winr,
                                                   const float* __restrict__ wini,
                                                   float* __restrict__ pr,
                                                   float* __restrict__ pi) {
    int idx = blockIdx.x * 256 + threadIdx.x;
    int u = idx & 127;
    int n0 = (idx >> 7) * 8;
    float ar[8] = {}, ai[8] = {};
    for (int k = 0; k < 512; ++k) {
        float wrv = winr[k * 128 + u], wiv = wini[k * 128 + u];
#pragma unroll
        for (int g = 0; g < 8; ++g) {
            float hv = h[(size_t)(n0 + g) * 512 + k];
            ar[g] = fmaf(hv, wrv, ar[g]);
            ai[g] = fmaf(hv, wiv, ai[g]);
        }
    }
#pragma unroll
    for (int g = 0; g < 8; ++g) {
        pr[(size_t)(n0 + g) * 128 + u] = ar[g];
        pi[(size_t)(n0 + g) * 128 + u] = ai[g];
    }
}

// ---------------- RNN scan v2 (unchanged) ----------------
__global__ __launch_bounds__(512) void scan_kernel(const float* __restrict__ done,
                                                   const float* __restrict__ sr0,
                                                   const float* __restrict__ si0,
                                                   const float* __restrict__ wrtR,
                                                   const float* __restrict__ wrtI,
                                                   const float* __restrict__ pr,
                                                   const float* __restrict__ pi,
                                                   float* __restrict__ hsr,
                                                   float* __restrict__ hsi) {
    int b = blockIdx.x;
    int tid = threadIdx.x;
    int u = tid & 127;
    int s = tid >> 7;
    int w = tid >> 6;

    const float4* wr4 = reinterpret_cast<const float4*>(wrtR + u * 128 + s * 32);
    const float4* wi4 = reinterpret_cast<const float4*>(wrtI + u * 128 + s * 32);
    float4 WR[8], WI[8];
#pragma unroll
    for (int q = 0; q < 8; ++q) { WR[q] = wr4[q]; WI[q] = wi4[q]; }

    __shared__ __align__(16) float stR[128], stI[128];
    __shared__ float parR[4][128], parI[4][128];
    __shared__ float redw[8];

    if (s == 0) { stR[u] = sr0[b * 128 + u]; stI[u] = si0[b * 128 + u]; }
    float cr = 0.f, ci = 0.f;
#pragma unroll
    for (int q = 0; q < 8; ++q) {
        cr += WR[q].x + WR[q].y + WR[q].z + WR[q].w;
        ci += WI[q].x + WI[q].y + WI[q].z + WI[q].w;
    }
    parR[s][u] = cr; parI[s][u] = ci;
    __syncthreads();
    float SWr = parR[0][u] + parR[1][u] + parR[2][u] + parR[3][u];
    float SWi = parI[0][u] + parI[1][u] + parI[2][u] + parI[3][u];
    __syncthreads();

    for (int t = 0; t < T_STEPS; ++t) {
        int np = (t * BATCH + b) * 128 + u;
        float prr = pr[np];
        float pri = pi[np];
        float d = done[t * BATCH + b];
        float r = 1.f - d;

        const float4* sR4 = reinterpret_cast<const float4*>(&stR[s * 32]);
        const float4* sI4 = reinterpret_cast<const float4*>(&stI[s * 32]);
        float ar0 = 0.f, ar1 = 0.f, ai0 = 0.f, ai1 = 0.f;
#pragma unroll
        for (int q = 0; q < 8; ++q) {
            float4 sr = sR4[q], si = sI4[q];
            float4 wrv = WR[q], wiv = WI[q];
            if (q & 1) {
                ar1 = fmaf(sr.x, wrv.x, ar1); ar1 = fmaf(-si.x, wiv.x, ar1);
                ai1 = fmaf(sr.x, wiv.x, ai1); ai1 = fmaf(si.x, wrv.x, ai1);
                ar1 = fmaf(sr.y, wrv.y, ar1); ar1 = fmaf(-si.y, wiv.y, ar1);
                ai1 = fmaf(sr.y, wiv.y, ai1); ai1 = fmaf(si.y, wrv.y, ai1);
                ar1 = fmaf(sr.z, wrv.z, ar1); ar1 = fmaf(-si.z, wiv.z, ar1);
                ai1 = fmaf(sr.z, wiv.z, ai1); ai1 = fmaf(si.z, wrv.z, ai1);
                ar1 = fmaf(sr.w, wrv.w, ar1); ar1 = fmaf(-si.w, wiv.w, ar1);
                ai1 = fmaf(sr.w, wiv.w, ai1); ai1 = fmaf(si.w, wrv.w, ai1);
            } else {
                ar0 = fmaf(sr.x, wrv.x, ar0); ar0 = fmaf(-si.x, wiv.x, ar0);
                ai0 = fmaf(sr.x, wiv.x, ai0); ai0 = fmaf(si.x, wrv.x, ai0);
                ar0 = fmaf(sr.y, wrv.y, ar0); ar0 = fmaf(-si.y, wiv.y, ar0);
                ai0 = fmaf(sr.y, wiv.y, ai0); ai0 = fmaf(si.y, wrv.y, ai0);
                ar0 = fmaf(sr.z, wrv.z, ar0); ar0 = fmaf(-si.z, wiv.z, ar0);
                ai0 = fmaf(sr.z, wiv.z, ai0); ai0 = fmaf(si.z, wrv.z, ai0);
                ar0 = fmaf(sr.w, wrv.w, ar0); ar0 = fmaf(-si.w, wiv.w, ar0);
                ai0 = fmaf(sr.w, wiv.w, ai0); ai0 = fmaf(si.w, wrv.w, ai0);
            }
        }
        parR[s][u] = ar0 + ar1;
        parI[s][u] = ai0 + ai1;
        __syncthreads();

        float tr_ = (parR[0][u] + parR[1][u]) + (parR[2][u] + parR[3][u]);
        float ti_ = (parI[0][u] + parI[1][u]) + (parI[2][u] + parI[3][u]);
        float pre_r = fmaf(r, tr_, fmaf(d, SWr, prr));
        float pre_i = fmaf(r, ti_, fmaf(d, SWi, pri));
        float sq = fmaf(pre_r, pre_r, pre_i * pre_i);
#pragma unroll
        for (int off = 32; off; off >>= 1) sq += __shfl_xor(sq, off);
        if ((tid & 63) == 0) redw[w] = sq;
        __syncthreads();

        float norm = redw[s * 2] + redw[s * 2 + 1];
        float scale = NORM_SCALE / sqrtf(norm);
        float nr = pre_r * scale, ni = pre_i * scale;
        if (s == 0) {
            stR[u] = nr; stI[u] = ni;
            hsr[np] = nr; hsi[np] = ni;
        }
        __syncthreads();
    }
}

// ---------------- heads (unchanged) ----------------
__global__ void heads_kernel(const float* __restrict__ hsr, const float* __restrict__ hsi,
                             const float* __restrict__ aw, const float* __restrict__ ab,
                             const float* __restrict__ cw, const float* __restrict__ cb,
                             float* __restrict__ out) {
    int idx = blockIdx.x * 256 + threadIdx.x;
    if (idx >= N_FRAMES * 7) return;
    int j = idx % 7;
    int n = idx / 7;
    float acc;
    if (j < 6) {
        acc = ab[j];
        for (int k = 0; k < 128; ++k) acc = fmaf(hsr[n * 128 + k], aw[k * 6 + j], acc);
        for (int k = 0; k < 128; ++k) acc = fmaf(hsi[n * 128 + k], aw[(128 + k) * 6 + j], acc);
    } else {
        acc = cb[0];
        for (int k = 0; k < 128; ++k) acc = fmaf(hsr[n * 128 + k], cw[k], acc);
        for (int k = 0; k < 128; ++k) acc = fmaf(hsi[n * 128 + k], cw[128 + k], acc);
    }
    out[idx] = acc;
}

// ---------------- launch ----------------
extern "C" void kernel_launch(void* const* d_in, const int* in_sizes, int n_in,
                              void* d_out, int out_size, void* d_ws, size_t ws_size,
                              hipStream_t stream) {
    const float* x        = (const float*)d_in[0];
    const float* done     = (const float*)d_in[1];
    const float* sr0      = (const float*)d_in[2];
    const float* si0      = (const float*)d_in[3];
    const float* conv1_w  = (const float*)d_in[4];
    const float* conv1_b  = (const float*)d_in[5];
    const float* conv2_w  = (const float*)d_in[6];
    const float* conv2_b  = (const float*)d_in[7];
    const float* conv3_w  = (const float*)d_in[8];
    const float* conv3_b  = (const float*)d_in[9];
    const float* fc_w     = (const float*)d_in[10];
    const float* fc_b     = (const float*)d_in[11];
    const float* win_r    = (const float*)d_in[12];
    const float* win_i    = (const float*)d_in[13];
    const float* wrec_r   = (const float*)d_in[14];
    const float* wrec_i   = (const float*)d_in[15];
    const float* actor_w  = (const float*)d_in[16];
    const float* actor_b  = (const float*)d_in[17];
    const float* critic_w = (const float*)d_in[18];
    const float* critic_b = (const float*)d_in[19];

    float* ws = (float*)d_ws;
    unsigned short* w1mf = (unsigned short*)(ws + OFF_W1P);
    unsigned short* w2mf = (unsigned short*)(ws + OFF_W2P);
    float* w3p  = ws + OFF_W3P;
    unsigned short* fcb = (unsigned short*)(ws + OFF_FCWP);
    float* hsr  = ws + OFF_HSR;
    float* hsi  = ws + OFF_HSI;
    float* prj  = ws + OFF_PROJR;
    float* pij  = ws + OFF_PROJI;
    float* h    = ws + OFF_H;
    float* y2   = ws + OFF_Y2;
    float* wrtR = ws + OFF_WRTR;
    float* wrtI = ws + OFF_WRTI;
    unsigned short* y1b = (unsigned short*)(ws + OFF_Y1);
    unsigned short* y3b = (unsigned short*)(ws + OFF_Y3);
    float* outp = (float*)d_out;

    hipLaunchKernelGGL(permute_w1mf, dim3(32), dim3(256), 0, stream, conv1_w, w1mf);
    hipLaunchKernelGGL(permute_w2mf, dim3(128), dim3(256), 0, stream, conv2_w, w2mf);
    hipLaunchKernelGGL(permute_w3, dim3(144), dim3(256), 0, stream, conv3_w, w3p);
    hipLaunchKernelGGL(permute_fcwmf, dim3(6400), dim3(256), 0, stream, fc_w, fcb);

    hipLaunchKernelGGL(conv1_kernel, dim3(4096), dim3(256), 0, stream, x, w1mf, conv1_b, y1b);
    hipLaunchKernelGGL(conv2_kernel, dim3(1024), dim3(256), 0, stream, y1b, w2mf, conv2_b, y2);
    hipLaunchKernelGGL(conv3_kernel, dim3(2048), dim3(256), 0, stream, y2, w3p, conv3_b, y3b);
    // y2 consumed; its space now holds the transposed recurrent weights
    hipLaunchKernelGGL(permute_wrt, dim3(64), dim3(256), 0, stream, wrec_r, wrec_i, wrtR, wrtI);
    hipLaunchKernelGGL(fc_kernel, dim3(256), dim3(256), 0, stream, y3b, fcb, fc_b, h);
    hipLaunchKernelGGL(proj_kernel, dim3(128), dim3(256), 0, stream, h, win_r, win_i, prj, pij);
    hipLaunchKernelGGL(scan_kernel, dim3(16), dim3(512), 0, stream,
                       done, sr0, si0, wrtR, wrtI, prj, pij, hsr, hsi);
    hipLaunchKernelGGL(heads_kernel, dim3(56), dim3(256), 0, stream,
                       hsr, hsi, actor_w, actor_b, critic_w, critic_b, outp);
}

// Round 11
// 374.283 us; speedup vs baseline: 5.2250x; 1.3931x over previous
//
#include <hip/hip_runtime.h>
#include <hip/hip_bf16.h>

// ---------------- problem constants ----------------
#define N_FRAMES 2048          // T*B
#define T_STEPS  128
#define BATCH    16
#define UNITS    128
#define NORM_SCALE 11.313708498984760390f  // sqrt(128)

typedef short bf16x8 __attribute__((ext_vector_type(8)));
typedef float f32x4 __attribute__((ext_vector_type(4)));

static __device__ inline unsigned short f2bf(float f) {
    __hip_bfloat16 h = __float2bfloat16(f);
    return __builtin_bit_cast(unsigned short, h);
}

// ---------------- workspace layout (float elements) ----------------
static const size_t OFF_W1P   = 0;            // 16KB ush: conv1 MFMA weights [ky][nt][lane][8]
static const size_t OFF_W2P   = 6144;         // 64KB ush: conv2 MFMA B-frags [16][4][64][8]
static const size_t OFF_W3P   = 38912;        // 72KB ush: conv3 MFMA B-frags [9][2][4][64][8]
static const size_t OFF_FCWP  = 75776;        // ush: fc MFMA B-frags [100][32][64][8]
static const size_t OFF_HSR   = 1681408;      // 262144
static const size_t OFF_HSI   = 1943552;      // 262144
static const size_t OFF_PROJR = 2205696;      // 262144
static const size_t OFF_PROJI = 2467840;      // 262144
static const size_t OFF_H     = 2729984;      // 1048576 : fc output [2048][512] f32
static const size_t OFF_Y2    = 3778560;      // ush: y2 bf16 [2048][9][9][64]
static const size_t OFF_WRTR  = OFF_Y2;       // 16384 f32: wrec_r transposed (after conv3 consumed y2)
static const size_t OFF_WRTI  = OFF_Y2 + 16384; // 16384 f32: wrec_i transposed
static const size_t OFF_Y1    = 14395392;     // ush: y1 bf16 [2048][20][20][32]
static const size_t OFF_Y3    = OFF_Y1;       // ush: y3 bf16 [2048][3136] (reuses y1 after conv2)

// ---------------- weight permutes ----------------
__global__ void permute_w1mf(const float* __restrict__ w, unsigned short* __restrict__ o) {
    int i = blockIdx.x * 256 + threadIdx.x;      // 8192
    if (i >= 8192) return;
    int j = i & 7; int lane = (i >> 3) & 63; int nt = (i >> 9) & 1; int ky = i >> 10;
    int t = (lane >> 4) * 8 + j;
    int oc = nt * 16 + (lane & 15);
    float v = 0.f;
    if (t < 24) {
        int kx = t / 3, ic = t % 3;
        v = w[((oc * 3 + ic) * 8 + ky) * 8 + kx] * (1.0f / 255.0f);
    }
    o[i] = f2bf(v);
}
// conv2 MFMA B-frags: o[((kk*4+nt)*64+lane)*8+j] = w2[oc=nt*16+(lane&15)][ic=(lane>>4)*8+j][ky=kk>>2][kx=kk&3]
__global__ void permute_w2mf(const float* __restrict__ w, unsigned short* __restrict__ o) {
    int i = blockIdx.x * 256 + threadIdx.x;      // 32768
    if (i >= 32768) return;
    int j = i & 7; int lane = (i >> 3) & 63; int nt = (i >> 9) & 3; int kk = i >> 11;
    int ic = (lane >> 4) * 8 + j;
    int oc = nt * 16 + (lane & 15);
    int ky = kk >> 2, kx = kk & 3;
    o[i] = f2bf(w[((oc * 32 + ic) * 4 + ky) * 4 + kx]);
}
// conv3 MFMA B-frags: o[(((kk*2+c)*4+nt)*64+lane)*8+j] = w3[oc=nt*16+(lane&15)][ic=c*32+(lane>>4)*8+j][ky=kk/3][kx=kk%3]
__global__ void permute_w3mf(const float* __restrict__ w, unsigned short* __restrict__ o) {
    int i = blockIdx.x * 256 + threadIdx.x;      // 9*2*4*64*8 = 36864
    if (i >= 36864) return;
    int j = i & 7; int lane = (i >> 3) & 63; int nt = (i >> 9) & 3; int c = (i >> 11) & 1; int kk = i >> 12;
    int ic = c * 32 + (lane >> 4) * 8 + j;
    int oc = nt * 16 + (lane & 15);
    int ky = kk / 3, kx = kk % 3;
    o[i] = f2bf(w[((oc * 64 + ic) * 3 + ky) * 3 + kx]);
}
__global__ void permute_fcwmf(const float* __restrict__ w, unsigned short* __restrict__ o) {
    int i = blockIdx.x * 256 + threadIdx.x;      // 1638400
    if (i >= 1638400) return;
    int jj = i & 7; int lane = (i >> 3) & 63; int ntg = (i >> 9) & 31; int kk = i >> 14;
    int k = kk * 32 + (lane >> 4) * 8 + jj;
    int n = ntg * 16 + (lane & 15);
    float v = 0.f;
    if (k < 3136) {
        int p = k >> 6, c = k & 63;
        v = w[(size_t)(c * 49 + p) * 512 + n];
    }
    o[i] = f2bf(v);
}
__global__ void permute_wrt(const float* __restrict__ wr, const float* __restrict__ wi,
                            float* __restrict__ otr, float* __restrict__ oti) {
    int i = blockIdx.x * 256 + threadIdx.x;      // 16384
    if (i >= 16384) return;
    int k = i & 127, u = i >> 7;
    otr[i] = wr[k * 128 + u];
    oti[i] = wi[k * 128 + u];
}

// ---------------- conv1 v6: MFMA implicit GEMM, bf16 output (unchanged) ----------------
__global__ __launch_bounds__(256) void conv1_kernel(const float* __restrict__ x,
                                                    const unsigned short* __restrict__ wmf,
                                                    const float* __restrict__ b,
                                                    unsigned short* __restrict__ y) {
    __shared__ unsigned short xs[11096];
    int tid = threadIdx.x;
    int blk = blockIdx.x;
    int n = blk >> 1, hb = blk & 1;

    const float4* xb4 = reinterpret_cast<const float4*>(x + (size_t)n * 21168 + hb * 40 * 252);
#pragma unroll
    for (int it = 0; it < 11; ++it) {
        int i = it * 256 + tid;
        if (i < 2772) {
            float4 v = xb4[i];
            ushort4 h;
            h.x = f2bf(v.x); h.y = f2bf(v.y); h.z = f2bf(v.z); h.w = f2bf(v.w);
            *reinterpret_cast<ushort4*>(&xs[i * 4]) = h;
        }
    }
    if (tid < 8) xs[11088 + tid] = 0;
    __syncthreads();

    int lane = tid & 63;
    int wv = tid >> 6;
    int row = lane & 15;
    int seg = lane >> 4;
    const uint4* wm = reinterpret_cast<const uint4*>(wmf);
    float b0 = b[row];
    float b1 = b[16 + row];
    int pbase = n * 400 + hb * 200;

    for (int tile = wv; tile < 13; tile += 4) {
        int p = tile * 16 + row; if (p > 199) p = 199;
        int eb = (p / 20) * 1008 + (p % 20) * 12 + seg * 8;
        f32x4 acc0 = {0.f, 0.f, 0.f, 0.f};
        f32x4 acc1 = {0.f, 0.f, 0.f, 0.f};
#pragma unroll
        for (int ky = 0; ky < 8; ++ky) {
            int ea = eb + ky * 252;
            ushort4 lo = *reinterpret_cast<const ushort4*>(&xs[ea]);
            ushort4 hi = *reinterpret_cast<const ushort4*>(&xs[ea + 4]);
            bf16x8 a = {(short)lo.x, (short)lo.y, (short)lo.z, (short)lo.w,
                        (short)hi.x, (short)hi.y, (short)hi.z, (short)hi.w};
            bf16x8 w0 = __builtin_bit_cast(bf16x8, wm[(ky * 2 + 0) * 64 + lane]);
            bf16x8 w1 = __builtin_bit_cast(bf16x8, wm[(ky * 2 + 1) * 64 + lane]);
            acc0 = __builtin_amdgcn_mfma_f32_16x16x32_bf16(a, w0, acc0, 0, 0, 0);
            acc1 = __builtin_amdgcn_mfma_f32_16x16x32_bf16(a, w1, acc1, 0, 0, 0);
        }
#pragma unroll
        for (int r = 0; r < 4; ++r) {
            int pl = tile * 16 + seg * 4 + r;
            if (pl < 200) {
                unsigned short* yp = y + ((size_t)(pbase + pl)) * 32 + row;
                yp[0]  = f2bf(fmaxf(acc0[r] + b0, 0.f));
                yp[16] = f2bf(fmaxf(acc1[r] + b1, 0.f));
            }
        }
    }
}

// ---------------- conv2 v5: MFMA implicit GEMM, bf16 output ----------------
__global__ __launch_bounds__(256) void conv2_kernel(const unsigned short* __restrict__ y1b,
                                                    const unsigned short* __restrict__ wt,
                                                    const float* __restrict__ b,
                                                    unsigned short* __restrict__ y2) {
    __shared__ unsigned short xs[2 * 12800];
    int tid = threadIdx.x;
    int n0 = blockIdx.x * 2;
    const uint4* xg = reinterpret_cast<const uint4*>(y1b + (size_t)n0 * 12800);
    uint4* xs4 = reinterpret_cast<uint4*>(xs);
#pragma unroll
    for (int q = 0; q < 13; ++q) {
        int i = q * 256 + tid;
        if (i < 3200) {
            uint4 v = xg[i];
            int swz = (i & ~3) | ((i & 3) ^ ((i >> 3) & 3));
            xs4[swz] = v;
        }
    }
    __syncthreads();

    int lane = tid & 63;
    int wv = tid >> 6;
    int img = wv >> 1;
    int tbase = (wv & 1) * 3;
    int row = lane & 15, seg = lane >> 4;
    int imgb = img * 1600;

    int ibase[3];
#pragma unroll
    for (int t = 0; t < 3; ++t) {
        int p = (tbase + t) * 16 + row; if (p > 80) p = 80;
        ibase[t] = (p / 9) * 40 + (p % 9) * 2;
    }
    const uint4* B4 = reinterpret_cast<const uint4*>(wt);
    f32x4 acc[3][4];
#pragma unroll
    for (int t = 0; t < 3; ++t)
#pragma unroll
        for (int nt = 0; nt < 4; ++nt) acc[t][nt] = (f32x4){0.f, 0.f, 0.f, 0.f};

#pragma unroll 1
    for (int kk = 0; kk < 16; ++kk) {
        int ky = kk >> 2, kx = kk & 3;
        int koff = ky * 20 + kx;
        bf16x8 bb[4];
#pragma unroll
        for (int nt = 0; nt < 4; ++nt)
            bb[nt] = __builtin_bit_cast(bf16x8, B4[(kk * 4 + nt) * 64 + lane]);
        bf16x8 a[3];
#pragma unroll
        for (int t = 0; t < 3; ++t) {
            int ipx = ibase[t] + koff;
            int a16 = imgb + ipx * 4 + (seg ^ ((ipx >> 1) & 3));
            a[t] = __builtin_bit_cast(bf16x8, *reinterpret_cast<const uint4*>(&xs[a16 * 8]));
        }
#pragma unroll
        for (int t = 0; t < 3; ++t)
#pragma unroll
            for (int nt = 0; nt < 4; ++nt)
                acc[t][nt] = __builtin_amdgcn_mfma_f32_16x16x32_bf16(a[t], bb[nt], acc[t][nt], 0, 0, 0);
    }

#pragma unroll
    for (int nt = 0; nt < 4; ++nt) {
        int c = nt * 16 + row;
        float bc = b[c];
#pragma unroll
        for (int t = 0; t < 3; ++t)
#pragma unroll
            for (int r = 0; r < 4; ++r) {
                int p = (tbase + t) * 16 + seg * 4 + r;
                if (p < 81)
                    y2[((size_t)(n0 + img) * 81 + p) * 64 + c] = f2bf(fmaxf(acc[t][nt][r] + bc, 0.f));
            }
    }
}

// ---------------- conv3 v5: MFMA implicit GEMM ----------------
// block = 2 images; LDS = 2*5184 bf16 = 20.7 KB, 16B-unit swizzle q ^ (px&7).
// 4 waves: (img = wv>>1, tiles (wv&1)*2..+1). K = 9 taps x 2 ic-chunks of 32.
__global__ __launch_bounds__(256) void conv3_kernel(const unsigned short* __restrict__ y2b,
                                                    const unsigned short* __restrict__ wt,
                                                    const float* __restrict__ b,
                                                    unsigned short* __restrict__ y3) {
    __shared__ unsigned short xs[2 * 5184];
    int tid = threadIdx.x;
    int n0 = blockIdx.x * 2;
    const uint4* xg = reinterpret_cast<const uint4*>(y2b + (size_t)n0 * 5184);
    uint4* xs4 = reinterpret_cast<uint4*>(xs);
#pragma unroll
    for (int q = 0; q < 6; ++q) {
        int i = q * 256 + tid;
        if (i < 1296) {
            uint4 v = xg[i];
            int px = i >> 3, qq = i & 7;
            xs4[px * 8 + (qq ^ (px & 7))] = v;
        }
    }
    __syncthreads();

    int lane = tid & 63;
    int wv = tid >> 6;
    int img = wv >> 1;
    int tbase = (wv & 1) * 2;
    int row = lane & 15, seg = lane >> 4;

    int ibase[2];
#pragma unroll
    for (int t = 0; t < 2; ++t) {
        int p = (tbase + t) * 16 + row; if (p > 48) p = 48;
        ibase[t] = img * 81 + (p / 7) * 9 + (p % 7);   // global pixel idx (incl. image)
    }
    const uint4* B4 = reinterpret_cast<const uint4*>(wt);
    f32x4 acc[2][4];
#pragma unroll
    for (int t = 0; t < 2; ++t)
#pragma unroll
        for (int nt = 0; nt < 4; ++nt) acc[t][nt] = (f32x4){0.f, 0.f, 0.f, 0.f};

#pragma unroll 1
    for (int kk = 0; kk < 9; ++kk) {
        int ky = kk / 3, kx = kk % 3;
        int koff = ky * 9 + kx;
#pragma unroll
        for (int c = 0; c < 2; ++c) {
            bf16x8 bb[4];
#pragma unroll
            for (int nt = 0; nt < 4; ++nt)
                bb[nt] = __builtin_bit_cast(bf16x8, B4[((kk * 2 + c) * 4 + nt) * 64 + lane]);
            bf16x8 a[2];
#pragma unroll
            for (int t = 0; t < 2; ++t) {
                int px = ibase[t] + koff;
                int u16 = px * 8 + ((c * 4 + seg) ^ (px & 7));
                a[t] = __builtin_bit_cast(bf16x8, *reinterpret_cast<const uint4*>(&xs[u16 * 8]));
            }
#pragma unroll
            for (int t = 0; t < 2; ++t)
#pragma unroll
                for (int nt = 0; nt < 4; ++nt)
                    acc[t][nt] = __builtin_amdgcn_mfma_f32_16x16x32_bf16(a[t], bb[nt], acc[t][nt], 0, 0, 0);
        }
    }

#pragma unroll
    for (int nt = 0; nt < 4; ++nt) {
        int c = nt * 16 + row;
        float bc = b[c];
#pragma unroll
        for (int t = 0; t < 2; ++t)
#pragma unroll
            for (int r = 0; r < 4; ++r) {
                int p = (tbase + t) * 16 + seg * 4 + r;
                if (p < 49)
                    y3[(size_t)(n0 + img) * 3136 + p * 64 + c] = f2bf(fmaxf(acc[t][nt][r] + bc, 0.f));
            }
    }
}

// ---------------- FC v2: bf16 MFMA (unchanged) ----------------
__global__ __launch_bounds__(256) void fc_kernel(const unsigned short* __restrict__ A,
                                                 const unsigned short* __restrict__ Bt,
                                                 const float* __restrict__ bias,
                                                 float* __restrict__ C) {
    __shared__ float Cs[64][65];
    int tid = threadIdx.x;
    int lane = tid & 63;
    int wv = tid >> 6;
    int bm = blockIdx.x & 31;
    int bn = blockIdx.x >> 5;
    int row = lane & 15, seg = lane >> 4;

    const uint4* B4 = reinterpret_cast<const uint4*>(Bt);
    f32x4 acc[4][4];
#pragma unroll
    for (int mf = 0; mf < 4; ++mf)
#pragma unroll
        for (int nf = 0; nf < 4; ++nf) acc[mf][nf] = (f32x4){0.f, 0.f, 0.f, 0.f};

    const unsigned short* Abase = A + (size_t)(bm * 64 + row) * 3136 + seg * 8;

#pragma unroll 1
    for (int kk = wv; kk < 100; kk += 4) {
        bf16x8 a[4], bb[4];
#pragma unroll
        for (int mf = 0; mf < 4; ++mf)
            a[mf] = __builtin_bit_cast(bf16x8,
                *reinterpret_cast<const uint4*>(Abase + (size_t)mf * 16 * 3136 + kk * 32));
#pragma unroll
        for (int nf = 0; nf < 4; ++nf)
            bb[nf] = __builtin_bit_cast(bf16x8, B4[(kk * 32 + bn * 4 + nf) * 64 + lane]);
#pragma unroll
        for (int mf = 0; mf < 4; ++mf)
#pragma unroll
            for (int nf = 0; nf < 4; ++nf)
                acc[mf][nf] = __builtin_amdgcn_mfma_f32_16x16x32_bf16(a[mf], bb[nf], acc[mf][nf], 0, 0, 0);
    }

#pragma unroll 1
    for (int w = 0; w < 4; ++w) {
        if (wv == w) {
#pragma unroll
            for (int mf = 0; mf < 4; ++mf)
#pragma unroll
                for (int nf = 0; nf < 4; ++nf)
#pragma unroll
                    for (int r = 0; r < 4; ++r) {
                        int rr = mf * 16 + seg * 4 + r;
                        int cc = nf * 16 + row;
                        if (w == 0) Cs[rr][cc] = acc[mf][nf][r];
                        else        Cs[rr][cc] += acc[mf][nf][r];
                    }
        }
        __syncthreads();
    }

    int r = tid >> 2, cq = (tid & 3) * 16;
#pragma unroll
    for (int q = 0; q < 4; ++q) {
        int c0 = cq + q * 4;
        float4 v = *reinterpret_cast<float4*>(&Cs[r][c0]);
        float4 bv = *reinterpret_cast<const float4*>(&bias[bn * 64 + c0]);
        v.x = fmaxf(v.x + bv.x, 0.f);
        v.y = fmaxf(v.y + bv.y, 0.f);
        v.z = fmaxf(v.z + bv.z, 0.f);
        v.w = fmaxf(v.w + bv.w, 0.f);
        *reinterpret_cast<float4*>(&C[(size_t)(bm * 64 + r) * 512 + bn * 64 + c0]) = v;
    }
}

// ---------------- proj (unchanged) ----------------
__global__ __launch_bounds__(256) void proj_kernel(const float* __restrict__ h,
                                                   const float* __restrict__ winr,
                                                   const float* __restrict__ wini,
                                                   float* __restrict__ pr,
                                                   float* __restrict__ pi) {
    int idx = blockIdx.x * 256 + threadIdx.x;
    int u = idx & 127;
    int n0 = (idx >> 7) * 8;
    float ar[8] = {}, ai[8] = {};
    for (int k = 0; k < 512; ++k) {
        float wrv = winr[k * 128 + u], wiv = wini[k * 128 + u];
#pragma unroll
        for (int g = 0; g < 8; ++g) {
            float hv = h[(size_t)(n0 + g) * 512 + k];
            ar[g] = fmaf(hv, wrv, ar[g]);
            ai[g] = fmaf(hv, wiv, ai[g]);
        }
    }
#pragma unroll
    for (int g = 0; g < 8; ++g) {
        pr[(size_t)(n0 + g) * 128 + u] = ar[g];
        pi[(size_t)(n0 + g) * 128 + u] = ai[g];
    }
}

// ---------------- RNN scan v2 (unchanged) ----------------
__global__ __launch_bounds__(512) void scan_kernel(const float* __restrict__ done,
                                                   const float* __restrict__ sr0,
                                                   const float* __restrict__ si0,
                                                   const float* __restrict__ wrtR,
                                                   const float* __restrict__ wrtI,
                                                   const float* __restrict__ pr,
                                                   const float* __restrict__ pi,
                                                   float* __restrict__ hsr,
                                                   float* __restrict__ hsi) {
    int b = blockIdx.x;
    int tid = threadIdx.x;
    int u = tid & 127;
    int s = tid >> 7;
    int w = tid >> 6;

    const float4* wr4 = reinterpret_cast<const float4*>(wrtR + u * 128 + s * 32);
    const float4* wi4 = reinterpret_cast<const float4*>(wrtI + u * 128 + s * 32);
    float4 WR[8], WI[8];
#pragma unroll
    for (int q = 0; q < 8; ++q) { WR[q] = wr4[q]; WI[q] = wi4[q]; }

    __shared__ __align__(16) float stR[128], stI[128];
    __shared__ float parR[4][128], parI[4][128];
    __shared__ float redw[8];

    if (s == 0) { stR[u] = sr0[b * 128 + u]; stI[u] = si0[b * 128 + u]; }
    float cr = 0.f, ci = 0.f;
#pragma unroll
    for (int q = 0; q < 8; ++q) {
        cr += WR[q].x + WR[q].y + WR[q].z + WR[q].w;
        ci += WI[q].x + WI[q].y + WI[q].z + WI[q].w;
    }
    parR[s][u] = cr; parI[s][u] = ci;
    __syncthreads();
    float SWr = parR[0][u] + parR[1][u] + parR[2][u] + parR[3][u];
    float SWi = parI[0][u] + parI[1][u] + parI[2][u] + parI[3][u];
    __syncthreads();

    for (int t = 0; t < T_STEPS; ++t) {
        int np = (t * BATCH + b) * 128 + u;
        float prr = pr[np];
        float pri = pi[np];
        float d = done[t * BATCH + b];
        float r = 1.f - d;

        const float4* sR4 = reinterpret_cast<const float4*>(&stR[s * 32]);
        const float4* sI4 = reinterpret_cast<const float4*>(&stI[s * 32]);
        float ar0 = 0.f, ar1 = 0.f, ai0 = 0.f, ai1 = 0.f;
#pragma unroll
        for (int q = 0; q < 8; ++q) {
            float4 sr = sR4[q], si = sI4[q];
            float4 wrv = WR[q], wiv = WI[q];
            if (q & 1) {
                ar1 = fmaf(sr.x, wrv.x, ar1); ar1 = fmaf(-si.x, wiv.x, ar1);
                ai1 = fmaf(sr.x, wiv.x, ai1); ai1 = fmaf(si.x, wrv.x, ai1);
                ar1 = fmaf(sr.y, wrv.y, ar1); ar1 = fmaf(-si.y, wiv.y, ar1);
                ai1 = fmaf(sr.y, wiv.y, ai1); ai1 = fmaf(si.y, wrv.y, ai1);
                ar1 = fmaf(sr.z, wrv.z, ar1); ar1 = fmaf(-si.z, wiv.z, ar1);
                ai1 = fmaf(sr.z, wiv.z, ai1); ai1 = fmaf(si.z, wrv.z, ai1);
                ar1 = fmaf(sr.w, wrv.w, ar1); ar1 = fmaf(-si.w, wiv.w, ar1);
                ai1 = fmaf(sr.w, wiv.w, ai1); ai1 = fmaf(si.w, wrv.w, ai1);
            } else {
                ar0 = fmaf(sr.x, wrv.x, ar0); ar0 = fmaf(-si.x, wiv.x, ar0);
                ai0 = fmaf(sr.x, wiv.x, ai0); ai0 = fmaf(si.x, wrv.x, ai0);
                ar0 = fmaf(sr.y, wrv.y, ar0); ar0 = fmaf(-si.y, wiv.y, ar0);
                ai0 = fmaf(sr.y, wiv.y, ai0); ai0 = fmaf(si.y, wrv.y, ai0);
                ar0 = fmaf(sr.z, wrv.z, ar0); ar0 = fmaf(-si.z, wiv.z, ar0);
                ai0 = fmaf(sr.z, wiv.z, ai0); ai0 = fmaf(si.z, wrv.z, ai0);
                ar0 = fmaf(sr.w, wrv.w, ar0); ar0 = fmaf(-si.w, wiv.w, ar0);
                ai0 = fmaf(sr.w, wiv.w, ai0); ai0 = fmaf(si.w, wrv.w, ai0);
            }
        }
        parR[s][u] = ar0 + ar1;
        parI[s][u] = ai0 + ai1;
        __syncthreads();

        float tr_ = (parR[0][u] + parR[1][u]) + (parR[2][u] + parR[3][u]);
        float ti_ = (parI[0][u] + parI[1][u]) + (parI[2][u] + parI[3][u]);
        float pre_r = fmaf(r, tr_, fmaf(d, SWr, prr));
        float pre_i = fmaf(r, ti_, fmaf(d, SWi, pri));
        float sq = fmaf(pre_r, pre_r, pre_i * pre_i);
#pragma unroll
        for (int off = 32; off; off >>= 1) sq += __shfl_xor(sq, off);
        if ((tid & 63) == 0) redw[w] = sq;
        __syncthreads();

        float norm = redw[s * 2] + redw[s * 2 + 1];
        float scale = NORM_SCALE / sqrtf(norm);
        float nr = pre_r * scale, ni = pre_i * scale;
        if (s == 0) {
            stR[u] = nr; stI[u] = ni;
            hsr[np] = nr; hsi[np] = ni;
        }
        __syncthreads();
    }
}

// ---------------- heads (unchanged) ----------------
__global__ void heads_kernel(const float* __restrict__ hsr, const float* __restrict__ hsi,
                             const float* __restrict__ aw, const float* __restrict__ ab,
                             const float* __restrict__ cw, const float* __restrict__ cb,
                             float* __restrict__ out) {
    int idx = blockIdx.x * 256 + threadIdx.x;
    if (idx >= N_FRAMES * 7) return;
    int j = idx % 7;
    int n = idx / 7;
    float acc;
    if (j < 6) {
        acc = ab[j];
        for (int k = 0; k < 128; ++k) acc = fmaf(hsr[n * 128 + k], aw[k * 6 + j], acc);
        for (int k = 0; k < 128; ++k) acc = fmaf(hsi[n * 128 + k], aw[(128 + k) * 6 + j], acc);
    } else {
        acc = cb[0];
        for (int k = 0; k < 128; ++k) acc = fmaf(hsr[n * 128 + k], cw[k], acc);
        for (int k = 0; k < 128; ++k) acc = fmaf(hsi[n * 128 + k], cw[128 + k], acc);
    }
    out[idx] = acc;
}

// ---------------- launch ----------------
extern "C" void kernel_launch(void* const* d_in, const int* in_sizes, int n_in,
                              void* d_out, int out_size, void* d_ws, size_t ws_size,
                              hipStream_t stream) {
    const float* x        = (const float*)d_in[0];
    const float* done     = (const float*)d_in[1];
    const float* sr0      = (const float*)d_in[2];
    const float* si0      = (const float*)d_in[3];
    const float* conv1_w  = (const float*)d_in[4];
    const float* conv1_b  = (const float*)d_in[5];
    const float* conv2_w  = (const float*)d_in[6];
    const float* conv2_b  = (const float*)d_in[7];
    const float* conv3_w  = (const float*)d_in[8];
    const float* conv3_b  = (const float*)d_in[9];
    const float* fc_w     = (const float*)d_in[10];
    const float* fc_b     = (const float*)d_in[11];
    const float* win_r    = (const float*)d_in[12];
    const float* win_i    = (const float*)d_in[13];
    const float* wrec_r   = (const float*)d_in[14];
    const float* wrec_i   = (const float*)d_in[15];
    const float* actor_w  = (const float*)d_in[16];
    const float* actor_b  = (const float*)d_in[17];
    const float* critic_w = (const float*)d_in[18];
    const float* critic_b = (const float*)d_in[19];

    float* ws = (float*)d_ws;
    unsigned short* w1mf = (unsigned short*)(ws + OFF_W1P);
    unsigned short* w2mf = (unsigned short*)(ws + OFF_W2P);
    unsigned short* w3mf = (unsigned short*)(ws + OFF_W3P);
    unsigned short* fcb = (unsigned short*)(ws + OFF_FCWP);
    float* hsr  = ws + OFF_HSR;
    float* hsi  = ws + OFF_HSI;
    float* prj  = ws + OFF_PROJR;
    float* pij  = ws + OFF_PROJI;
    float* h    = ws + OFF_H;
    unsigned short* y2b = (unsigned short*)(ws + OFF_Y2);
    float* wrtR = ws + OFF_WRTR;
    float* wrtI = ws + OFF_WRTI;
    unsigned short* y1b = (unsigned short*)(ws + OFF_Y1);
    unsigned short* y3b = (unsigned short*)(ws + OFF_Y3);
    float* outp = (float*)d_out;

    hipLaunchKernelGGL(permute_w1mf, dim3(32), dim3(256), 0, stream, conv1_w, w1mf);
    hipLaunchKernelGGL(permute_w2mf, dim3(128), dim3(256), 0, stream, conv2_w, w2mf);
    hipLaunchKernelGGL(permute_w3mf, dim3(144), dim3(256), 0, stream, conv3_w, w3mf);
    hipLaunchKernelGGL(permute_fcwmf, dim3(6400), dim3(256), 0, stream, fc_w, fcb);

    hipLaunchKernelGGL(conv1_kernel, dim3(4096), dim3(256), 0, stream, x, w1mf, conv1_b, y1b);
    hipLaunchKernelGGL(conv2_kernel, dim3(1024), dim3(256), 0, stream, y1b, w2mf, conv2_b, y2b);
    hipLaunchKernelGGL(conv3_kernel, dim3(1024), dim3(256), 0, stream, y2b, w3mf, conv3_b, y3b);
    // y2 consumed; its space now holds the transposed recurrent weights
    hipLaunchKernelGGL(permute_wrt, dim3(64), dim3(256), 0, stream, wrec_r, wrec_i, wrtR, wrtI);
    hipLaunchKernelGGL(fc_kernel, dim3(256), dim3(256), 0, stream, y3b, fcb, fc_b, h);
    hipLaunchKernelGGL(proj_kernel, dim3(128), dim3(256), 0, stream, h, win_r, win_i, prj, pij);
    hipLaunchKernelGGL(scan_kernel, dim3(16), dim3(512), 0, stream,
                       done, sr0, si0, wrtR, wrtI, prj, pij, hsr, hsi);
    hipLaunchKernelGGL(heads_kernel, dim3(56), dim3(256), 0, stream,
                       hsr, hsi, actor_w, actor_b, critic_w, critic_b, outp);
}